// Round 2
// baseline (1157.379 us; speedup 1.0000x reference)
//
#include <hip/hip_runtime.h>
#include <stdint.h>

#define D_MODEL 2048
#define S_LEN   2048
#define NTOK    4096
#define QKV_N   3072
#define DFF     8192

typedef float  f32x4  __attribute__((ext_vector_type(4)));
typedef __bf16 bf16x8 __attribute__((ext_vector_type(8)));
typedef unsigned short u16;
typedef unsigned short u16x8 __attribute__((ext_vector_type(8)));

__device__ __forceinline__ float b2f(u16 u){ union{float f; uint32_t i;} v; v.i = ((uint32_t)u) << 16; return v.f; }
__device__ __forceinline__ u16 f2b(float f){
  union{float f; uint32_t i;} v; v.f = f;
  uint32_t r = v.i + 0x7FFFu + ((v.i >> 16) & 1u);
  return (u16)(r >> 16);
}

__device__ __forceinline__ void gload_lds16(const void* gsrc, void* ldst){
  __builtin_amdgcn_global_load_lds(
      (const __attribute__((address_space(1))) void*)gsrc,
      (__attribute__((address_space(3))) void*)ldst,
      16, 0, 0);
}

// ------- weight convert+transpose (sub-block): W[k0g+.. , n0g+..] f32 -> WT[Nt][Kt] bf16
__global__ __launch_bounds__(256) void wconv_kernel(const float* __restrict__ W, u16* __restrict__ WT,
                                                    int Nfull, int Kt, int Nt, int k0g, int n0g)
{
  __shared__ float tile[64][65];
  const int nTn = Nt >> 6;
  const int tk = blockIdx.x / nTn, tn = blockIdx.x % nTn;
  const int k0 = tk << 6, n0 = tn << 6;
  const int t  = threadIdx.x;
  const int c4 = (t & 15) << 2;
  const int r  = t >> 4;
#pragma unroll
  for (int i = 0; i < 4; ++i) {
    float4 v = *reinterpret_cast<const float4*>(&W[(size_t)(k0g + k0 + r + i*16) * Nfull + n0g + n0 + c4]);
    tile[r + i*16][c4+0] = v.x; tile[r + i*16][c4+1] = v.y;
    tile[r + i*16][c4+2] = v.z; tile[r + i*16][c4+3] = v.w;
  }
  __syncthreads();
#pragma unroll
  for (int i = 0; i < 4; ++i) {
    int n = r + i*16;
    ushort4 ov;
    ov.x = f2b(tile[c4+0][n]); ov.y = f2b(tile[c4+1][n]);
    ov.z = f2b(tile[c4+2][n]); ov.w = f2b(tile[c4+3][n]);
    *reinterpret_cast<ushort4*>(&WT[(size_t)(n0 + n) * Kt + k0 + c4]) = ov;
  }
}

// ------- rope cos/sin table (double precision) ---------------------------------------
__global__ void sincos_kernel(float* __restrict__ ct, float* __restrict__ st)
{
  int idx = blockIdx.x * 256 + threadIdx.x;
  if (idx >= S_LEN * 32) return;
  int p = idx >> 5, i = idx & 31;
  double freq = pow(10000.0, -((double)(2*i)) / 64.0);
  double ang  = (double)p * freq;
  ct[idx] = (float)cos(ang);
  st[idx] = (float)sin(ang);
}

// ------- RMSNorm: row (f32 or bf16) -> bf16 row --------------------------------------
template<bool BF16IN>
__global__ __launch_bounds__(256) void rmsnorm_kernel(const void* __restrict__ xin, const float* __restrict__ w, u16* __restrict__ out)
{
  const int row = blockIdx.x;
  const int t = threadIdx.x;
  float v[8];
  if (BF16IN) {
    const u16* xr = ((const u16*)xin) + (size_t)row * D_MODEL;
    u16x8 a = *reinterpret_cast<const u16x8*>(&xr[t*8]);
#pragma unroll
    for (int j = 0; j < 8; ++j) v[j] = b2f(a[j]);
  } else {
    const float* xr = ((const float*)xin) + (size_t)row * D_MODEL;
    float4 a = *reinterpret_cast<const float4*>(&xr[t*8]);
    float4 c = *reinterpret_cast<const float4*>(&xr[t*8+4]);
    v[0]=a.x; v[1]=a.y; v[2]=a.z; v[3]=a.w; v[4]=c.x; v[5]=c.y; v[6]=c.z; v[7]=c.w;
  }
  float ss = 0.f;
#pragma unroll
  for (int j = 0; j < 8; ++j) ss += v[j]*v[j];
#pragma unroll
  for (int d = 1; d < 64; d <<= 1) ss += __shfl_xor(ss, d);
  __shared__ float red[4];
  if ((t & 63) == 0) red[t >> 6] = ss;
  __syncthreads();
  ss = red[0] + red[1] + red[2] + red[3];
  const float sc = rsqrtf(ss * (1.0f / (float)D_MODEL) + 1e-5f);
  float4 w0 = *reinterpret_cast<const float4*>(&w[t*8]);
  float4 w1 = *reinterpret_cast<const float4*>(&w[t*8+4]);
  u16x8 o;
  o[0]=f2b(v[0]*sc*w0.x); o[1]=f2b(v[1]*sc*w0.y); o[2]=f2b(v[2]*sc*w0.z); o[3]=f2b(v[3]*sc*w0.w);
  o[4]=f2b(v[4]*sc*w1.x); o[5]=f2b(v[5]*sc*w1.y); o[6]=f2b(v[6]*sc*w1.z); o[7]=f2b(v[7]*sc*w1.w);
  *reinterpret_cast<u16x8*>(&out[(size_t)row * D_MODEL + t*8]) = o;
}

// ------- generic bf16 MFMA GEMM: A[M][lda] x WT[N][ldb] -------------------------------
// EPI: 2 silu->Cb; 3 Cb=v*other; 4 Cb=v; 5 Cf+=v; 6 Cb=f2b(v+resf); 7 Cf=v+b2f(resb)
template<int EPI>
__global__ __launch_bounds__(256) void gemm_kernel(
    const u16* __restrict__ A, const u16* __restrict__ BT,
    int K, int lda, int ldb, int ldc, int n_off,
    float* __restrict__ Cf, u16* __restrict__ Cb,
    const float* __restrict__ resf, const u16* __restrict__ resb, const u16* other)
{
  __shared__ u16 Alds[128 * 32];
  __shared__ u16 Blds[128 * 32];
  const int bn = blockIdx.x, bm = blockIdx.y;
  const int tid  = threadIdx.x;
  const int w    = tid >> 6, lane = tid & 63;
  const int g    = lane >> 4, lr = lane & 15;
  const int wr   = (w >> 1) * 64, wc = (w & 1) * 64;
  const int srow = lane >> 2;
  const int scol = (lane & 3) * 8;

  const f32x4 fz = {0.f, 0.f, 0.f, 0.f};
  f32x4 acc[4][4];
#pragma unroll
  for (int i = 0; i < 4; ++i)
#pragma unroll
    for (int j = 0; j < 4; ++j) acc[i][j] = fz;

  const size_t Abase = (size_t)(bm * 128) * lda;
  const size_t Bbase = (size_t)(bn * 128) * ldb;

  for (int k0 = 0; k0 < K; k0 += 32) {
    for (int li = w; li < 8; li += 4) {
      int row = li * 16 + srow;
      gload_lds16(A  + Abase + (size_t)row * lda + k0 + scol, &Alds[li * 512]);
      gload_lds16(BT + Bbase + (size_t)row * ldb + k0 + scol, &Blds[li * 512]);
    }
    __syncthreads();
    bf16x8 af[4], bfr[4];
#pragma unroll
    for (int mi = 0; mi < 4; ++mi) af[mi]  = *reinterpret_cast<const bf16x8*>(&Alds[(wr + mi*16 + lr) * 32 + g*8]);
#pragma unroll
    for (int ni = 0; ni < 4; ++ni) bfr[ni] = *reinterpret_cast<const bf16x8*>(&Blds[(wc + ni*16 + lr) * 32 + g*8]);
#pragma unroll
    for (int mi = 0; mi < 4; ++mi)
#pragma unroll
      for (int ni = 0; ni < 4; ++ni)
        acc[mi][ni] = __builtin_amdgcn_mfma_f32_16x16x32_bf16(af[mi], bfr[ni], acc[mi][ni], 0, 0, 0);
    __syncthreads();
  }

#pragma unroll
  for (int mi = 0; mi < 4; ++mi) {
#pragma unroll
    for (int ni = 0; ni < 4; ++ni) {
#pragma unroll
      for (int j = 0; j < 4; ++j) {
        int row = bm * 128 + wr + mi*16 + g*4 + j;
        int col = n_off + bn * 128 + wc + ni*16 + lr;
        size_t idx = (size_t)row * ldc + col;
        float v = acc[mi][ni][j];
        if (EPI == 2)      Cb[idx] = f2b(v / (1.0f + __expf(-v)));
        else if (EPI == 3) Cb[idx] = f2b(v * b2f(other[idx]));
        else if (EPI == 4) Cb[idx] = f2b(v);
        else if (EPI == 5) Cf[idx] += v;
        else if (EPI == 6) Cb[idx] = f2b(v + resf[idx]);
        else if (EPI == 7) Cf[idx] = v + b2f(resb[idx]);
      }
    }
  }
}

// ------- RoPE + relayout: qkv bf16 -> Q[bh][s][d], K[bkv][s][d], VT[bkv][d][s] --------
__global__ __launch_bounds__(256) void rope_kernel(
    const u16* __restrict__ qkv, const float* __restrict__ ct, const float* __restrict__ st,
    u16* __restrict__ Q, u16* __restrict__ Kt, u16* __restrict__ VT)
{
  const int tok = blockIdx.x;
  const int b = tok >> 11, s = tok & (S_LEN - 1);
  const int w = threadIdx.x >> 6, lane = threadIdx.x & 63;
  const size_t base = (size_t)tok * QKV_N;
  for (int slot = w; slot < 48; slot += 4) {
    int col = (slot < 32) ? slot * 64 : (slot < 40 ? 2048 + (slot - 32) * 64 : 2560 + (slot - 40) * 64);
    float v = b2f(qkv[base + col + lane]);
    if (slot < 40) {
      int i = lane & 31;
      float c = ct[s * 32 + i], sn = st[s * 32 + i];
      float p = b2f(qkv[base + col + (lane ^ 32)]);
      v = (lane < 32) ? (v * c - p * sn) : (v * c + p * sn);
    }
    u16 ob = f2b(v);
    if (slot < 32)      Q [((size_t)(b * 32 + slot)      * S_LEN + s) * 64 + lane] = ob;
    else if (slot < 40) Kt[((size_t)(b * 8 + slot - 32)  * S_LEN + s) * 64 + lane] = ob;
    else                VT[((size_t)(b * 8 + slot - 40)  * 64 + lane) * S_LEN + s] = ob;
  }
}

// ------- causal GQA flash attention: 1 wave per (bh, 16-row q tile) -------------------
__global__ __launch_bounds__(64) void attn_kernel(
    const u16* __restrict__ Q, const u16* __restrict__ Kt,
    const u16* __restrict__ VT, u16* __restrict__ ctx)
{
  const int bh = blockIdx.x;
  const int qt = blockIdx.y;
  const int b = bh >> 5, h = bh & 31;
  const int kvh = (b << 3) + (h >> 2);
  const int lane = threadIdx.x;
  const int g = lane >> 4, lr = lane & 15;
  const int q0 = qt << 4;

  const u16* Qb = Q  + ((size_t)bh * S_LEN + q0) * 64;
  const u16* Kb = Kt + (size_t)kvh * S_LEN * 64;
  const u16* Vb = VT + (size_t)kvh * 64 * S_LEN;

  bf16x8 qf0 = *reinterpret_cast<const bf16x8*>(&Qb[lr * 64 + g * 8]);
  bf16x8 qf1 = *reinterpret_cast<const bf16x8*>(&Qb[lr * 64 + 32 + g * 8]);

  const f32x4 fz = {0.f, 0.f, 0.f, 0.f};
  f32x4 o[4]; float m[4], l[4];
#pragma unroll
  for (int j = 0; j < 4; ++j) { m[j] = -1e30f; l[j] = 0.f; }
#pragma unroll
  for (int ni = 0; ni < 4; ++ni) o[ni] = fz;

  __shared__ u16 Plds[512];
  const int nkt = ((q0 + 15) >> 5) + 1;

  for (int kt = 0; kt < nkt; ++kt) {
    const int k0 = kt << 5;
    f32x4 s0 = fz, s1 = fz;
    {
      const u16* Kr0 = &Kb[(size_t)(k0 + lr) * 64];
      bf16x8 k00 = *reinterpret_cast<const bf16x8*>(&Kr0[g * 8]);
      bf16x8 k01 = *reinterpret_cast<const bf16x8*>(&Kr0[32 + g * 8]);
      s0 = __builtin_amdgcn_mfma_f32_16x16x32_bf16(qf0, k00, s0, 0, 0, 0);
      s0 = __builtin_amdgcn_mfma_f32_16x16x32_bf16(qf1, k01, s0, 0, 0, 0);
      const u16* Kr1 = &Kb[(size_t)(k0 + 16 + lr) * 64];
      bf16x8 k10 = *reinterpret_cast<const bf16x8*>(&Kr1[g * 8]);
      bf16x8 k11 = *reinterpret_cast<const bf16x8*>(&Kr1[32 + g * 8]);
      s1 = __builtin_amdgcn_mfma_f32_16x16x32_bf16(qf0, k10, s1, 0, 0, 0);
      s1 = __builtin_amdgcn_mfma_f32_16x16x32_bf16(qf1, k11, s1, 0, 0, 0);
    }
    float tm[4];
#pragma unroll
    for (int j = 0; j < 4; ++j) {
      int qrow = q0 + g * 4 + j;
      float a = s0[j] * 0.125f; if (k0 + lr > qrow)      a = -1e30f;
      float c = s1[j] * 0.125f; if (k0 + 16 + lr > qrow) c = -1e30f;
      s0[j] = a; s1[j] = c;
      tm[j] = fmaxf(a, c);
    }
#pragma unroll
    for (int d = 1; d < 16; d <<= 1)
#pragma unroll
      for (int j = 0; j < 4; ++j) tm[j] = fmaxf(tm[j], __shfl_xor(tm[j], d));
    float corr[4], ts[4];
#pragma unroll
    for (int j = 0; j < 4; ++j) {
      float mn = fmaxf(m[j], tm[j]);
      corr[j] = __expf(m[j] - mn);
      m[j] = mn;
      float p0 = __expf(s0[j] - mn);
      float p1 = __expf(s1[j] - mn);
      s0[j] = p0; s1[j] = p1;
      ts[j] = p0 + p1;
    }
#pragma unroll
    for (int d = 1; d < 16; d <<= 1)
#pragma unroll
      for (int j = 0; j < 4; ++j) ts[j] += __shfl_xor(ts[j], d);
#pragma unroll
    for (int j = 0; j < 4; ++j) {
      l[j] = l[j] * corr[j] + ts[j];
#pragma unroll
      for (int ni = 0; ni < 4; ++ni) o[ni][j] *= corr[j];
    }
#pragma unroll
    for (int j = 0; j < 4; ++j) {
      Plds[(g * 4 + j) * 32 + lr]      = f2b(s0[j]);
      Plds[(g * 4 + j) * 32 + 16 + lr] = f2b(s1[j]);
    }
    asm volatile("s_waitcnt lgkmcnt(0)" ::: "memory");
    __builtin_amdgcn_sched_barrier(0);
    bf16x8 pa = *reinterpret_cast<const bf16x8*>(&Plds[lr * 32 + g * 8]);
#pragma unroll
    for (int ni = 0; ni < 4; ++ni) {
      bf16x8 vf = *reinterpret_cast<const bf16x8*>(&Vb[(size_t)(ni * 16 + lr) * S_LEN + k0 + g * 8]);
      o[ni] = __builtin_amdgcn_mfma_f32_16x16x32_bf16(pa, vf, o[ni], 0, 0, 0);
    }
  }

  const int tokbase = b * S_LEN + q0;
#pragma unroll
  for (int j = 0; j < 4; ++j) {
    float inv = 1.0f / l[j];
    int tok = tokbase + g * 4 + j;
#pragma unroll
    for (int ni = 0; ni < 4; ++ni)
      ctx[(size_t)tok * D_MODEL + h * 64 + ni * 16 + lr] = f2b(o[ni][j] * inv);
  }
}

// ---------------------------------- host ---------------------------------------------
extern "C" void kernel_launch(void* const* d_in, const int* in_sizes, int n_in,
                              void* d_out, int out_size, void* d_ws, size_t ws_size,
                              hipStream_t stream)
{
  const float* x     = (const float*)d_in[0];
  const float* wn1   = (const float*)d_in[1];
  const float* wqkv  = (const float*)d_in[2];
  const float* wout  = (const float*)d_in[3];
  const float* wn2   = (const float*)d_in[4];
  const float* wgate = (const float*)d_in[5];
  const float* wup   = (const float*)d_in[6];
  const float* wdown = (const float*)d_in[7];
  float* out = (float*)d_out;
  char* ws = (char*)d_ws;

  // compact arena: 117,964,800 bytes total (fits 128 MiB ws)
  float* cosT = (float*)(ws + 0);            //  262,144
  float* sinT = (float*)(ws + 262144);       //  262,144
  u16*   wT   = (u16*)  (ws + 524288);       // 16,777,216 (reused per-GEMM)
  u16*   hB   = (u16*)  (ws + 17301504);     // 16,777,216 (h, then h2)
  u16*   x1b  = (u16*)  (ws + 34078720);     // 16,777,216 (residual, bf16)
  char*  S    = ws + 50855936;               // 67,108,864 scratch, time-shared
  u16*   qkvB = (u16*)(S + 0);               // 25,165,824
  u16*   qB   = (u16*)(S + 25165824);        // 16,777,216
  u16*   kB   = (u16*)(S + 41943040);        //  4,194,304
  u16*   vtB  = (u16*)(S + 46137344);        //  4,194,304
  u16*   ctxB = (u16*)(S + 50331648);        // 16,777,216
  u16*   gsB  = (u16*)(S + 0);               // 67,108,864 (gate*silu, then *up in place)

  sincos_kernel<<<dim3(256), 256, 0, stream>>>(cosT, sinT);
  rmsnorm_kernel<false><<<dim3(NTOK), 256, 0, stream>>>(x, wn1, hB);

  // qkv = h @ w_qkv
  wconv_kernel<<<dim3((2048/64)*(3072/64)), 256, 0, stream>>>(wqkv, wT, 3072, 2048, 3072, 0, 0);
  gemm_kernel<4><<<dim3(QKV_N/128, NTOK/128), 256, 0, stream>>>(hB, wT, 2048, 2048, 2048, 3072, 0, nullptr, qkvB, nullptr, nullptr, nullptr);
  rope_kernel<<<dim3(NTOK), 256, 0, stream>>>(qkvB, cosT, sinT, qB, kB, vtB);
  attn_kernel<<<dim3(64, 128), 64, 0, stream>>>(qB, kB, vtB, ctxB);

  // x1 = x + ctx @ w_out   (bf16 residual)
  wconv_kernel<<<dim3((2048/64)*(2048/64)), 256, 0, stream>>>(wout, wT, 2048, 2048, 2048, 0, 0);
  gemm_kernel<6><<<dim3(D_MODEL/128, NTOK/128), 256, 0, stream>>>(ctxB, wT, 2048, 2048, 2048, 2048, 0, nullptr, x1b, x, nullptr, nullptr);

  rmsnorm_kernel<true><<<dim3(NTOK), 256, 0, stream>>>(x1b, wn2, hB);

  // gs = silu(h2 @ w_gate), two N-chunks
  for (int c = 0; c < 2; ++c) {
    wconv_kernel<<<dim3((2048/64)*(4096/64)), 256, 0, stream>>>(wgate, wT, 8192, 2048, 4096, 0, c*4096);
    gemm_kernel<2><<<dim3(4096/128, NTOK/128), 256, 0, stream>>>(hB, wT, 2048, 2048, 2048, 8192, c*4096, nullptr, gsB, nullptr, nullptr, nullptr);
  }
  // gs *= (h2 @ w_up), in place, two N-chunks
  for (int c = 0; c < 2; ++c) {
    wconv_kernel<<<dim3((2048/64)*(4096/64)), 256, 0, stream>>>(wup, wT, 8192, 2048, 4096, 0, c*4096);
    gemm_kernel<3><<<dim3(4096/128, NTOK/128), 256, 0, stream>>>(hB, wT, 2048, 2048, 2048, 8192, c*4096, nullptr, gsB, nullptr, nullptr, gsB);
  }
  // out = x1 + gs @ w_down, two K-chunks
  wconv_kernel<<<dim3((4096/64)*(2048/64)), 256, 0, stream>>>(wdown, wT, 2048, 4096, 2048, 0, 0);
  gemm_kernel<7><<<dim3(D_MODEL/128, NTOK/128), 256, 0, stream>>>(gsB, wT, 4096, 8192, 4096, 2048, 0, out, nullptr, nullptr, x1b, nullptr);
  wconv_kernel<<<dim3((4096/64)*(2048/64)), 256, 0, stream>>>(wdown, wT, 2048, 4096, 2048, 4096, 0);
  gemm_kernel<5><<<dim3(D_MODEL/128, NTOK/128), 256, 0, stream>>>(gsB + 4096, wT, 4096, 8192, 4096, 2048, 0, out, nullptr, nullptr, nullptr, nullptr);
}

// Round 3
// 1065.227 us; speedup vs baseline: 1.0865x; 1.0865x over previous
//
#include <hip/hip_runtime.h>
#include <stdint.h>

#define D_MODEL 2048
#define S_LEN   2048
#define NTOK    4096
#define QKV_N   3072
#define DFF     8192

typedef float  f32x4  __attribute__((ext_vector_type(4)));
typedef __bf16 bf16x8 __attribute__((ext_vector_type(8)));
typedef unsigned short u16;
typedef unsigned short u16x8 __attribute__((ext_vector_type(8)));

__device__ __forceinline__ float b2f(u16 u){ union{float f; uint32_t i;} v; v.i = ((uint32_t)u) << 16; return v.f; }
__device__ __forceinline__ u16 f2b(float f){
  union{float f; uint32_t i;} v; v.f = f;
  uint32_t r = v.i + 0x7FFFu + ((v.i >> 16) & 1u);
  return (u16)(r >> 16);
}

__device__ __forceinline__ void gload_lds16(const void* gsrc, void* ldst){
  __builtin_amdgcn_global_load_lds(
      (const __attribute__((address_space(1))) void*)gsrc,
      (__attribute__((address_space(3))) void*)ldst,
      16, 0, 0);
}

// ------- weight convert+transpose (sub-block): W[k0g+.., n0g+..] f32 -> WT[Nt][Kt] bf16
__global__ __launch_bounds__(256) void wconv_kernel(const float* __restrict__ W, u16* __restrict__ WT,
                                                    int Nfull, int Kt, int Nt, int k0g, int n0g)
{
  __shared__ float tile[64][65];
  const int nTn = Nt >> 6;
  const int tk = blockIdx.x / nTn, tn = blockIdx.x % nTn;
  const int k0 = tk << 6, n0 = tn << 6;
  const int t  = threadIdx.x;
  const int c4 = (t & 15) << 2;
  const int r  = t >> 4;
#pragma unroll
  for (int i = 0; i < 4; ++i) {
    float4 v = *reinterpret_cast<const float4*>(&W[(size_t)(k0g + k0 + r + i*16) * Nfull + n0g + n0 + c4]);
    tile[r + i*16][c4+0] = v.x; tile[r + i*16][c4+1] = v.y;
    tile[r + i*16][c4+2] = v.z; tile[r + i*16][c4+3] = v.w;
  }
  __syncthreads();
#pragma unroll
  for (int i = 0; i < 4; ++i) {
    int n = r + i*16;
    ushort4 ov;
    ov.x = f2b(tile[c4+0][n]); ov.y = f2b(tile[c4+1][n]);
    ov.z = f2b(tile[c4+2][n]); ov.w = f2b(tile[c4+3][n]);
    *reinterpret_cast<ushort4*>(&WT[(size_t)(n0 + n) * Kt + k0 + c4]) = ov;
  }
}

// ------- rope cos/sin table --------------------------------------------------------
__global__ void sincos_kernel(float* __restrict__ ct, float* __restrict__ st)
{
  int idx = blockIdx.x * 256 + threadIdx.x;
  if (idx >= S_LEN * 32) return;
  int p = idx >> 5, i = idx & 31;
  double freq = pow(10000.0, -((double)(2*i)) / 64.0);
  double ang  = (double)p * freq;
  ct[idx] = (float)cos(ang);
  st[idx] = (float)sin(ang);
}

// ------- RMSNorm -------------------------------------------------------------------
template<bool BF16IN>
__global__ __launch_bounds__(256) void rmsnorm_kernel(const void* __restrict__ xin, const float* __restrict__ w, u16* __restrict__ out)
{
  const int row = blockIdx.x;
  const int t = threadIdx.x;
  float v[8];
  if (BF16IN) {
    const u16* xr = ((const u16*)xin) + (size_t)row * D_MODEL;
    u16x8 a = *reinterpret_cast<const u16x8*>(&xr[t*8]);
#pragma unroll
    for (int j = 0; j < 8; ++j) v[j] = b2f(a[j]);
  } else {
    const float* xr = ((const float*)xin) + (size_t)row * D_MODEL;
    float4 a = *reinterpret_cast<const float4*>(&xr[t*8]);
    float4 c = *reinterpret_cast<const float4*>(&xr[t*8+4]);
    v[0]=a.x; v[1]=a.y; v[2]=a.z; v[3]=a.w; v[4]=c.x; v[5]=c.y; v[6]=c.z; v[7]=c.w;
  }
  float ss = 0.f;
#pragma unroll
  for (int j = 0; j < 8; ++j) ss += v[j]*v[j];
#pragma unroll
  for (int d = 1; d < 64; d <<= 1) ss += __shfl_xor(ss, d);
  __shared__ float red[4];
  if ((t & 63) == 0) red[t >> 6] = ss;
  __syncthreads();
  ss = red[0] + red[1] + red[2] + red[3];
  const float sc = rsqrtf(ss * (1.0f / (float)D_MODEL) + 1e-5f);
  float4 w0 = *reinterpret_cast<const float4*>(&w[t*8]);
  float4 w1 = *reinterpret_cast<const float4*>(&w[t*8+4]);
  u16x8 o;
  o[0]=f2b(v[0]*sc*w0.x); o[1]=f2b(v[1]*sc*w0.y); o[2]=f2b(v[2]*sc*w0.z); o[3]=f2b(v[3]*sc*w0.w);
  o[4]=f2b(v[4]*sc*w1.x); o[5]=f2b(v[5]*sc*w1.y); o[6]=f2b(v[6]*sc*w1.z); o[7]=f2b(v[7]*sc*w1.w);
  *reinterpret_cast<u16x8*>(&out[(size_t)row * D_MODEL + t*8]) = o;
}

// ------- 256x256 deep-pipelined bf16 MFMA GEMM: A[M][lda] x BT[N][ldb] ----------------
// 512 thr = 8 waves (2M x 4N), BK=32, 4 LDS buffers, prefetch dist 3, vmcnt(8)/tile.
// Granule swizzle: LDS loc (row, G') holds data granule G'^(row&3); both sides applied.
// EPI: 2 silu->Cb; 3 Cb=v*other; 4 Cb=v; 5 Cf+=v; 6 Cb=f2b(v+resf); 7 Cf=v+b2f(resb)
template<int EPI>
__global__ __launch_bounds__(512, 2) void gemm256_kernel(
    const u16* __restrict__ A, const u16* __restrict__ BT,
    int K, int lda, int ldb, int ldc, int n_off,
    float* Cf, u16* Cb,
    const float* __restrict__ resf, const u16* __restrict__ resb, const u16* other)
{
  __shared__ u16 lds[4 * 16384];   // 128 KiB: per buf [A 256x32][B 256x32]
  const int tid = threadIdx.x;
  const int w = tid >> 6, lane = tid & 63;
  const int g = lane >> 4, lr = lane & 15;
  const int wm = w >> 2, wn = w & 3;
  const int bn = blockIdx.x, bm = blockIdx.y;
  const int NT = K >> 5;

  // stage mapping: call j in 0..3 -> (A/B half), row=(j&1)*128 + tid/4, dest granule tid&3
  const int sr  = tid >> 2;
  const int sGs = (tid & 3) ^ (sr & 3);   // swizzled source granule (involution)
  const u16* srcBase[4];
  {
    const size_t Abase = (size_t)(bm * 256) * lda;
    const size_t Bbase = (size_t)(bn * 256) * ldb;
    srcBase[0] = A  + Abase + (size_t)sr         * lda + sGs * 8;
    srcBase[1] = A  + Abase + (size_t)(128 + sr) * lda + sGs * 8;
    srcBase[2] = BT + Bbase + (size_t)sr         * ldb + sGs * 8;
    srcBase[3] = BT + Bbase + (size_t)(128 + sr) * ldb + sGs * 8;
  }
  const int ldsCallOff[4] = { w*512, 4096 + w*512, 8192 + w*512, 12288 + w*512 };

  const f32x4 fz = {0.f, 0.f, 0.f, 0.f};
  f32x4 acc[8][4];
#pragma unroll
  for (int i = 0; i < 8; ++i)
#pragma unroll
    for (int j = 0; j < 4; ++j) acc[i][j] = fz;

#define STAGE(T) do {                                                   \
    int tc = ((T) < NT) ? (T) : (NT - 1);                               \
    int bb = ((T) & 3) * 16384;                                         \
    int kk = tc << 5;                                                   \
    _Pragma("unroll")                                                   \
    for (int j = 0; j < 4; ++j)                                         \
      gload_lds16(srcBase[j] + kk, &lds[bb + ldsCallOff[j]]);           \
  } while (0)

  STAGE(0); STAGE(1); STAGE(2);

  // per-thread constant swizzled read granule offset (row&3 == lr&3 for all frags)
  const int rg = ((g ^ (lr & 3)) << 3);

  for (int t = 0; t < NT; ++t) {
    asm volatile("s_waitcnt vmcnt(8)" ::: "memory");
    __builtin_amdgcn_s_barrier();
    __builtin_amdgcn_sched_barrier(0);
    const u16* bufA = &lds[(t & 3) * 16384];
    const u16* bufB = bufA + 8192;
    bf16x8 af[8], bfr[4];
#pragma unroll
    for (int mi = 0; mi < 8; ++mi) {
      int row = wm*128 + mi*16 + lr;
      af[mi] = *reinterpret_cast<const bf16x8*>(&bufA[row*32 + rg]);
    }
#pragma unroll
    for (int ni = 0; ni < 4; ++ni) {
      int row = wn*64 + ni*16 + lr;
      bfr[ni] = *reinterpret_cast<const bf16x8*>(&bufB[row*32 + rg]);
    }
    STAGE(t + 3);
    __builtin_amdgcn_s_setprio(1);
#pragma unroll
    for (int mi = 0; mi < 8; ++mi)
#pragma unroll
      for (int ni = 0; ni < 4; ++ni)
        acc[mi][ni] = __builtin_amdgcn_mfma_f32_16x16x32_bf16(af[mi], bfr[ni], acc[mi][ni], 0, 0, 0);
    __builtin_amdgcn_s_setprio(0);
  }
#undef STAGE

#pragma unroll
  for (int mi = 0; mi < 8; ++mi) {
#pragma unroll
    for (int ni = 0; ni < 4; ++ni) {
#pragma unroll
      for (int j = 0; j < 4; ++j) {
        int row = bm*256 + wm*128 + mi*16 + g*4 + j;
        int col = n_off + bn*256 + wn*64 + ni*16 + lr;
        size_t idx = (size_t)row * ldc + col;
        float v = acc[mi][ni][j];
        if (EPI == 2)      Cb[idx] = f2b(v / (1.0f + __expf(-v)));
        else if (EPI == 3) Cb[idx] = f2b(v * b2f(other[idx]));
        else if (EPI == 4) Cb[idx] = f2b(v);
        else if (EPI == 5) Cf[idx] += v;
        else if (EPI == 6) Cb[idx] = f2b(v + resf[idx]);
        else if (EPI == 7) Cf[idx] = v + b2f(resb[idx]);
      }
    }
  }
}

// ------- RoPE + relayout ------------------------------------------------------------
__global__ __launch_bounds__(256) void rope_kernel(
    const u16* __restrict__ qkv, const float* __restrict__ ct, const float* __restrict__ st,
    u16* __restrict__ Q, u16* __restrict__ Kt, u16* __restrict__ VT)
{
  const int tok = blockIdx.x;
  const int b = tok >> 11, s = tok & (S_LEN - 1);
  const int w = threadIdx.x >> 6, lane = threadIdx.x & 63;
  const size_t base = (size_t)tok * QKV_N;
  for (int slot = w; slot < 48; slot += 4) {
    int col = (slot < 32) ? slot * 64 : (slot < 40 ? 2048 + (slot - 32) * 64 : 2560 + (slot - 40) * 64);
    float v = b2f(qkv[base + col + lane]);
    if (slot < 40) {
      int i = lane & 31;
      float c = ct[s * 32 + i], sn = st[s * 32 + i];
      float p = b2f(qkv[base + col + (lane ^ 32)]);
      v = (lane < 32) ? (v * c - p * sn) : (v * c + p * sn);
    }
    u16 ob = f2b(v);
    if (slot < 32)      Q [((size_t)(b * 32 + slot)      * S_LEN + s) * 64 + lane] = ob;
    else if (slot < 40) Kt[((size_t)(b * 8 + slot - 32)  * S_LEN + s) * 64 + lane] = ob;
    else                VT[((size_t)(b * 8 + slot - 40)  * 64 + lane) * S_LEN + s] = ob;
  }
}

// ------- causal GQA flash attention: 4 waves/block, 1 wave per 16-row q tile ----------
__global__ __launch_bounds__(256) void attn_kernel(
    const u16* __restrict__ Q, const u16* __restrict__ Kt,
    const u16* __restrict__ VT, u16* __restrict__ ctx)
{
  const int bh = blockIdx.x;
  const int wid = threadIdx.x >> 6;
  const int qt = blockIdx.y * 4 + wid;
  const int b = bh >> 5, h = bh & 31;
  const int kvh = (b << 3) + (h >> 2);
  const int lane = threadIdx.x & 63;
  const int g = lane >> 4, lr = lane & 15;
  const int q0 = qt << 4;

  const u16* Qb = Q  + ((size_t)bh * S_LEN + q0) * 64;
  const u16* Kb = Kt + (size_t)kvh * S_LEN * 64;
  const u16* Vb = VT + (size_t)kvh * 64 * S_LEN;

  bf16x8 qf0 = *reinterpret_cast<const bf16x8*>(&Qb[lr * 64 + g * 8]);
  bf16x8 qf1 = *reinterpret_cast<const bf16x8*>(&Qb[lr * 64 + 32 + g * 8]);

  const f32x4 fz = {0.f, 0.f, 0.f, 0.f};
  f32x4 o[4]; float m[4], l[4];
#pragma unroll
  for (int j = 0; j < 4; ++j) { m[j] = -1e30f; l[j] = 0.f; }
#pragma unroll
  for (int ni = 0; ni < 4; ++ni) o[ni] = fz;

  __shared__ u16 Plds[4][512];
  const int nkt = ((q0 + 15) >> 5) + 1;

  for (int kt = 0; kt < nkt; ++kt) {
    const int k0 = kt << 5;
    f32x4 s0 = fz, s1 = fz;
    {
      const u16* Kr0 = &Kb[(size_t)(k0 + lr) * 64];
      bf16x8 k00 = *reinterpret_cast<const bf16x8*>(&Kr0[g * 8]);
      bf16x8 k01 = *reinterpret_cast<const bf16x8*>(&Kr0[32 + g * 8]);
      s0 = __builtin_amdgcn_mfma_f32_16x16x32_bf16(qf0, k00, s0, 0, 0, 0);
      s0 = __builtin_amdgcn_mfma_f32_16x16x32_bf16(qf1, k01, s0, 0, 0, 0);
      const u16* Kr1 = &Kb[(size_t)(k0 + 16 + lr) * 64];
      bf16x8 k10 = *reinterpret_cast<const bf16x8*>(&Kr1[g * 8]);
      bf16x8 k11 = *reinterpret_cast<const bf16x8*>(&Kr1[32 + g * 8]);
      s1 = __builtin_amdgcn_mfma_f32_16x16x32_bf16(qf0, k10, s1, 0, 0, 0);
      s1 = __builtin_amdgcn_mfma_f32_16x16x32_bf16(qf1, k11, s1, 0, 0, 0);
    }
    float tm[4];
#pragma unroll
    for (int j = 0; j < 4; ++j) {
      int qrow = q0 + g * 4 + j;
      float a = s0[j] * 0.125f; if (k0 + lr > qrow)      a = -1e30f;
      float c = s1[j] * 0.125f; if (k0 + 16 + lr > qrow) c = -1e30f;
      s0[j] = a; s1[j] = c;
      tm[j] = fmaxf(a, c);
    }
#pragma unroll
    for (int d = 1; d < 16; d <<= 1)
#pragma unroll
      for (int j = 0; j < 4; ++j) tm[j] = fmaxf(tm[j], __shfl_xor(tm[j], d));
    float corr[4], ts[4];
#pragma unroll
    for (int j = 0; j < 4; ++j) {
      float mn = fmaxf(m[j], tm[j]);
      corr[j] = __expf(m[j] - mn);
      m[j] = mn;
      float p0 = __expf(s0[j] - mn);
      float p1 = __expf(s1[j] - mn);
      s0[j] = p0; s1[j] = p1;
      ts[j] = p0 + p1;
    }
#pragma unroll
    for (int d = 1; d < 16; d <<= 1)
#pragma unroll
      for (int j = 0; j < 4; ++j) ts[j] += __shfl_xor(ts[j], d);
#pragma unroll
    for (int j = 0; j < 4; ++j) {
      l[j] = l[j] * corr[j] + ts[j];
#pragma unroll
      for (int ni = 0; ni < 4; ++ni) o[ni][j] *= corr[j];
    }
#pragma unroll
    for (int j = 0; j < 4; ++j) {
      Plds[wid][(g * 4 + j) * 32 + lr]      = f2b(s0[j]);
      Plds[wid][(g * 4 + j) * 32 + 16 + lr] = f2b(s1[j]);
    }
    asm volatile("s_waitcnt lgkmcnt(0)" ::: "memory");
    __builtin_amdgcn_sched_barrier(0);
    bf16x8 pa = *reinterpret_cast<const bf16x8*>(&Plds[wid][lr * 32 + g * 8]);
#pragma unroll
    for (int ni = 0; ni < 4; ++ni) {
      bf16x8 vf = *reinterpret_cast<const bf16x8*>(&Vb[(size_t)(ni * 16 + lr) * S_LEN + k0 + g * 8]);
      o[ni] = __builtin_amdgcn_mfma_f32_16x16x32_bf16(pa, vf, o[ni], 0, 0, 0);
    }
  }

  const int tokbase = b * S_LEN + q0;
#pragma unroll
  for (int j = 0; j < 4; ++j) {
    float inv = 1.0f / l[j];
    int tok = tokbase + g * 4 + j;
#pragma unroll
    for (int ni = 0; ni < 4; ++ni)
      ctx[(size_t)tok * D_MODEL + h * 64 + ni * 16 + lr] = f2b(o[ni][j] * inv);
  }
}

// ---------------------------------- host ---------------------------------------------
extern "C" void kernel_launch(void* const* d_in, const int* in_sizes, int n_in,
                              void* d_out, int out_size, void* d_ws, size_t ws_size,
                              hipStream_t stream)
{
  const float* x     = (const float*)d_in[0];
  const float* wn1   = (const float*)d_in[1];
  const float* wqkv  = (const float*)d_in[2];
  const float* wout  = (const float*)d_in[3];
  const float* wn2   = (const float*)d_in[4];
  const float* wgate = (const float*)d_in[5];
  const float* wup   = (const float*)d_in[6];
  const float* wdown = (const float*)d_in[7];
  float* out = (float*)d_out;
  char* ws = (char*)d_ws;

  // compact arena: 117,964,800 bytes total
  float* cosT = (float*)(ws + 0);
  float* sinT = (float*)(ws + 262144);
  u16*   wT   = (u16*)  (ws + 524288);       // 16 MiB, reused per-GEMM
  u16*   hB   = (u16*)  (ws + 17301504);     // h, then h2
  u16*   x1b  = (u16*)  (ws + 34078720);     // residual, bf16
  char*  S    = ws + 50855936;               // 64 MiB scratch, time-shared
  u16*   qkvB = (u16*)(S + 0);
  u16*   qB   = (u16*)(S + 25165824);
  u16*   kB   = (u16*)(S + 41943040);
  u16*   vtB  = (u16*)(S + 46137344);
  u16*   ctxB = (u16*)(S + 50331648);
  u16*   gsB  = (u16*)(S + 0);

  sincos_kernel<<<dim3(256), 256, 0, stream>>>(cosT, sinT);
  rmsnorm_kernel<false><<<dim3(NTOK), 256, 0, stream>>>(x, wn1, hB);

  // qkv = h @ w_qkv
  wconv_kernel<<<dim3((2048/64)*(3072/64)), 256, 0, stream>>>(wqkv, wT, 3072, 2048, 3072, 0, 0);
  gemm256_kernel<4><<<dim3(QKV_N/256, NTOK/256), 512, 0, stream>>>(hB, wT, 2048, 2048, 2048, 3072, 0, nullptr, qkvB, nullptr, nullptr, nullptr);
  rope_kernel<<<dim3(NTOK), 256, 0, stream>>>(qkvB, cosT, sinT, qB, kB, vtB);
  attn_kernel<<<dim3(64, 32), 256, 0, stream>>>(qB, kB, vtB, ctxB);

  // x1 = x + ctx @ w_out (bf16 residual)
  wconv_kernel<<<dim3((2048/64)*(2048/64)), 256, 0, stream>>>(wout, wT, 2048, 2048, 2048, 0, 0);
  gemm256_kernel<6><<<dim3(D_MODEL/256, NTOK/256), 512, 0, stream>>>(ctxB, wT, 2048, 2048, 2048, 2048, 0, nullptr, x1b, x, nullptr, nullptr);

  rmsnorm_kernel<true><<<dim3(NTOK), 256, 0, stream>>>(x1b, wn2, hB);

  // gs = silu(h2 @ w_gate), two N-chunks
  for (int c = 0; c < 2; ++c) {
    wconv_kernel<<<dim3((2048/64)*(4096/64)), 256, 0, stream>>>(wgate, wT, 8192, 2048, 4096, 0, c*4096);
    gemm256_kernel<2><<<dim3(4096/256, NTOK/256), 512, 0, stream>>>(hB, wT, 2048, 2048, 2048, 8192, c*4096, nullptr, gsB, nullptr, nullptr, nullptr);
  }
  // gs *= (h2 @ w_up), in place, two N-chunks
  for (int c = 0; c < 2; ++c) {
    wconv_kernel<<<dim3((2048/64)*(4096/64)), 256, 0, stream>>>(wup, wT, 8192, 2048, 4096, 0, c*4096);
    gemm256_kernel<3><<<dim3(4096/256, NTOK/256), 512, 0, stream>>>(hB, wT, 2048, 2048, 2048, 8192, c*4096, nullptr, gsB, nullptr, nullptr, gsB);
  }
  // out = x1 + gs @ w_down, two K-chunks
  wconv_kernel<<<dim3((4096/64)*(2048/64)), 256, 0, stream>>>(wdown, wT, 2048, 4096, 2048, 0, 0);
  gemm256_kernel<7><<<dim3(D_MODEL/256, NTOK/256), 512, 0, stream>>>(gsB, wT, 4096, 8192, 4096, 2048, 0, out, nullptr, nullptr, x1b, nullptr);
  wconv_kernel<<<dim3((4096/64)*(2048/64)), 256, 0, stream>>>(wdown, wT, 2048, 4096, 2048, 4096, 0);
  gemm256_kernel<5><<<dim3(D_MODEL/256, NTOK/256), 512, 0, stream>>>(gsB + 4096, wT, 4096, 8192, 4096, 2048, 0, out, nullptr, nullptr, nullptr, nullptr);
}

// Round 4
// 945.916 us; speedup vs baseline: 1.2236x; 1.1261x over previous
//
#include <hip/hip_runtime.h>
#include <stdint.h>

#define D_MODEL 2048
#define S_LEN   2048
#define NTOK    4096
#define QKV_N   3072
#define DFF     8192

typedef float  f32x4   __attribute__((ext_vector_type(4)));
typedef float  f32x16  __attribute__((ext_vector_type(16)));
typedef __bf16 bf16x8  __attribute__((ext_vector_type(8)));
typedef unsigned short u16;
typedef unsigned short u16x8 __attribute__((ext_vector_type(8)));

__device__ __forceinline__ float b2f(u16 u){ union{float f; uint32_t i;} v; v.i = ((uint32_t)u) << 16; return v.f; }
__device__ __forceinline__ u16 f2b(float f){
  union{float f; uint32_t i;} v; v.f = f;
  uint32_t r = v.i + 0x7FFFu + ((v.i >> 16) & 1u);
  return (u16)(r >> 16);
}

__device__ __forceinline__ void gload_lds16(const void* gsrc, void* ldst){
  __builtin_amdgcn_global_load_lds(
      (const __attribute__((address_space(1))) void*)gsrc,
      (__attribute__((address_space(3))) void*)ldst,
      16, 0, 0);
}

// ------- weight convert+transpose (sub-block): W[k0g+.., n0g+..] f32 -> WT[Nt][Kt] bf16
__global__ __launch_bounds__(256) void wconv_kernel(const float* __restrict__ W, u16* __restrict__ WT,
                                                    int Nfull, int Kt, int Nt, int k0g, int n0g)
{
  __shared__ float tile[64][65];
  const int nTn = Nt >> 6;
  const int tk = blockIdx.x / nTn, tn = blockIdx.x % nTn;
  const int k0 = tk << 6, n0 = tn << 6;
  const int t  = threadIdx.x;
  const int c4 = (t & 15) << 2;
  const int r  = t >> 4;
#pragma unroll
  for (int i = 0; i < 4; ++i) {
    float4 v = *reinterpret_cast<const float4*>(&W[(size_t)(k0g + k0 + r + i*16) * Nfull + n0g + n0 + c4]);
    tile[r + i*16][c4+0] = v.x; tile[r + i*16][c4+1] = v.y;
    tile[r + i*16][c4+2] = v.z; tile[r + i*16][c4+3] = v.w;
  }
  __syncthreads();
#pragma unroll
  for (int i = 0; i < 4; ++i) {
    int n = r + i*16;
    ushort4 ov;
    ov.x = f2b(tile[c4+0][n]); ov.y = f2b(tile[c4+1][n]);
    ov.z = f2b(tile[c4+2][n]); ov.w = f2b(tile[c4+3][n]);
    *reinterpret_cast<ushort4*>(&WT[(size_t)(n0 + n) * Kt + k0 + c4]) = ov;
  }
}

// ------- rope cos/sin table --------------------------------------------------------
__global__ void sincos_kernel(float* __restrict__ ct, float* __restrict__ st)
{
  int idx = blockIdx.x * 256 + threadIdx.x;
  if (idx >= S_LEN * 32) return;
  int p = idx >> 5, i = idx & 31;
  double freq = pow(10000.0, -((double)(2*i)) / 64.0);
  double ang  = (double)p * freq;
  ct[idx] = (float)cos(ang);
  st[idx] = (float)sin(ang);
}

// ------- RMSNorm -------------------------------------------------------------------
template<bool BF16IN>
__global__ __launch_bounds__(256) void rmsnorm_kernel(const void* __restrict__ xin, const float* __restrict__ w, u16* __restrict__ out)
{
  const int row = blockIdx.x;
  const int t = threadIdx.x;
  float v[8];
  if (BF16IN) {
    const u16* xr = ((const u16*)xin) + (size_t)row * D_MODEL;
    u16x8 a = *reinterpret_cast<const u16x8*>(&xr[t*8]);
#pragma unroll
    for (int j = 0; j < 8; ++j) v[j] = b2f(a[j]);
  } else {
    const float* xr = ((const float*)xin) + (size_t)row * D_MODEL;
    float4 a = *reinterpret_cast<const float4*>(&xr[t*8]);
    float4 c = *reinterpret_cast<const float4*>(&xr[t*8+4]);
    v[0]=a.x; v[1]=a.y; v[2]=a.z; v[3]=a.w; v[4]=c.x; v[5]=c.y; v[6]=c.z; v[7]=c.w;
  }
  float ss = 0.f;
#pragma unroll
  for (int j = 0; j < 8; ++j) ss += v[j]*v[j];
#pragma unroll
  for (int d = 1; d < 64; d <<= 1) ss += __shfl_xor(ss, d);
  __shared__ float red[4];
  if ((t & 63) == 0) red[t >> 6] = ss;
  __syncthreads();
  ss = red[0] + red[1] + red[2] + red[3];
  const float sc = rsqrtf(ss * (1.0f / (float)D_MODEL) + 1e-5f);
  float4 w0 = *reinterpret_cast<const float4*>(&w[t*8]);
  float4 w1 = *reinterpret_cast<const float4*>(&w[t*8+4]);
  u16x8 o;
  o[0]=f2b(v[0]*sc*w0.x); o[1]=f2b(v[1]*sc*w0.y); o[2]=f2b(v[2]*sc*w0.z); o[3]=f2b(v[3]*sc*w0.w);
  o[4]=f2b(v[4]*sc*w1.x); o[5]=f2b(v[5]*sc*w1.y); o[6]=f2b(v[6]*sc*w1.z); o[7]=f2b(v[7]*sc*w1.w);
  *reinterpret_cast<u16x8*>(&out[(size_t)row * D_MODEL + t*8]) = o;
}

// ------- 256x256 deep-pipelined bf16 MFMA GEMM: A[M][lda] x BT[N][ldb] ----------------
template<int EPI>
__global__ __launch_bounds__(512, 2) void gemm256_kernel(
    const u16* __restrict__ A, const u16* __restrict__ BT,
    int K, int lda, int ldb, int ldc, int n_off,
    float* Cf, u16* Cb,
    const float* __restrict__ resf, const u16* __restrict__ resb, const u16* other)
{
  __shared__ u16 lds[4 * 16384];   // 128 KiB: per buf [A 256x32][B 256x32]
  const int tid = threadIdx.x;
  const int w = tid >> 6, lane = tid & 63;
  const int g = lane >> 4, lr = lane & 15;
  const int wm = w >> 2, wn = w & 3;
  const int bn = blockIdx.x, bm = blockIdx.y;
  const int NT = K >> 5;

  const int sr  = tid >> 2;
  const int sGs = (tid & 3) ^ (sr & 3);
  const u16* srcBase[4];
  {
    const size_t Abase = (size_t)(bm * 256) * lda;
    const size_t Bbase = (size_t)(bn * 256) * ldb;
    srcBase[0] = A  + Abase + (size_t)sr         * lda + sGs * 8;
    srcBase[1] = A  + Abase + (size_t)(128 + sr) * lda + sGs * 8;
    srcBase[2] = BT + Bbase + (size_t)sr         * ldb + sGs * 8;
    srcBase[3] = BT + Bbase + (size_t)(128 + sr) * ldb + sGs * 8;
  }
  const int ldsCallOff[4] = { w*512, 4096 + w*512, 8192 + w*512, 12288 + w*512 };

  const f32x4 fz = {0.f, 0.f, 0.f, 0.f};
  f32x4 acc[8][4];
#pragma unroll
  for (int i = 0; i < 8; ++i)
#pragma unroll
    for (int j = 0; j < 4; ++j) acc[i][j] = fz;

#define STAGE(T) do {                                                   \
    int tc = ((T) < NT) ? (T) : (NT - 1);                               \
    int bb = ((T) & 3) * 16384;                                         \
    int kk = tc << 5;                                                   \
    _Pragma("unroll")                                                   \
    for (int j = 0; j < 4; ++j)                                         \
      gload_lds16(srcBase[j] + kk, &lds[bb + ldsCallOff[j]]);           \
  } while (0)

  STAGE(0); STAGE(1); STAGE(2);

  const int rg = ((g ^ (lr & 3)) << 3);

  for (int t = 0; t < NT; ++t) {
    asm volatile("s_waitcnt vmcnt(8)" ::: "memory");
    __builtin_amdgcn_s_barrier();
    __builtin_amdgcn_sched_barrier(0);
    const u16* bufA = &lds[(t & 3) * 16384];
    const u16* bufB = bufA + 8192;
    bf16x8 af[8], bfr[4];
#pragma unroll
    for (int mi = 0; mi < 8; ++mi) {
      int row = wm*128 + mi*16 + lr;
      af[mi] = *reinterpret_cast<const bf16x8*>(&bufA[row*32 + rg]);
    }
#pragma unroll
    for (int ni = 0; ni < 4; ++ni) {
      int row = wn*64 + ni*16 + lr;
      bfr[ni] = *reinterpret_cast<const bf16x8*>(&bufB[row*32 + rg]);
    }
    STAGE(t + 3);
    __builtin_amdgcn_s_setprio(1);
#pragma unroll
    for (int mi = 0; mi < 8; ++mi)
#pragma unroll
      for (int ni = 0; ni < 4; ++ni)
        acc[mi][ni] = __builtin_amdgcn_mfma_f32_16x16x32_bf16(af[mi], bfr[ni], acc[mi][ni], 0, 0, 0);
    __builtin_amdgcn_s_setprio(0);
  }
#undef STAGE

#pragma unroll
  for (int mi = 0; mi < 8; ++mi) {
#pragma unroll
    for (int ni = 0; ni < 4; ++ni) {
#pragma unroll
      for (int j = 0; j < 4; ++j) {
        int row = bm*256 + wm*128 + mi*16 + g*4 + j;
        int col = n_off + bn*256 + wn*64 + ni*16 + lr;
        size_t idx = (size_t)row * ldc + col;
        float v = acc[mi][ni][j];
        if (EPI == 2)      Cb[idx] = f2b(v / (1.0f + __expf(-v)));
        else if (EPI == 3) Cb[idx] = f2b(v * b2f(other[idx]));
        else if (EPI == 4) Cb[idx] = f2b(v);
        else if (EPI == 5) Cf[idx] += v;
        else if (EPI == 6) Cb[idx] = f2b(v + resf[idx]);
        else if (EPI == 7) Cf[idx] = v + b2f(resb[idx]);
      }
    }
  }
}

// ------- RoPE + relayout ------------------------------------------------------------
__global__ __launch_bounds__(256) void rope_kernel(
    const u16* __restrict__ qkv, const float* __restrict__ ct, const float* __restrict__ st,
    u16* __restrict__ Q, u16* __restrict__ Kt, u16* __restrict__ VT)
{
  const int tok = blockIdx.x;
  const int b = tok >> 11, s = tok & (S_LEN - 1);
  const int w = threadIdx.x >> 6, lane = threadIdx.x & 63;
  const size_t base = (size_t)tok * QKV_N;
  for (int slot = w; slot < 48; slot += 4) {
    int col = (slot < 32) ? slot * 64 : (slot < 40 ? 2048 + (slot - 32) * 64 : 2560 + (slot - 40) * 64);
    float v = b2f(qkv[base + col + lane]);
    if (slot < 40) {
      int i = lane & 31;
      float c = ct[s * 32 + i], sn = st[s * 32 + i];
      float p = b2f(qkv[base + col + (lane ^ 32)]);
      v = (lane < 32) ? (v * c - p * sn) : (v * c + p * sn);
    }
    u16 ob = f2b(v);
    if (slot < 32)      Q [((size_t)(b * 32 + slot)      * S_LEN + s) * 64 + lane] = ob;
    else if (slot < 40) Kt[((size_t)(b * 8 + slot - 32)  * S_LEN + s) * 64 + lane] = ob;
    else                VT[((size_t)(b * 8 + slot - 40)  * 64 + lane) * S_LEN + s] = ob;
  }
}

// ------- causal GQA flash attention: swapped QK^T, in-register softmax ----------------
// 4 waves/block, 32 q-rows/wave, KVBLK=32, 32x32x16 MFMA. exp2-domain online softmax.
#define ASCALE 0.1803368801111204f   /* 0.125 * log2(e) */
__global__ __launch_bounds__(256, 3) void attn_kernel(
    const u16* __restrict__ Q, const u16* __restrict__ Kt,
    const u16* __restrict__ VT, u16* __restrict__ ctx)
{
  const int bh  = blockIdx.x;            // 0..63
  const int qb  = 15 - blockIdx.y;       // heavy blocks dispatched first
  const int wid = threadIdx.x >> 6;
  const int lane = threadIdx.x & 63;
  const int b = bh >> 5, h = bh & 31;
  const int kvh = (b << 3) + (h >> 2);
  const int q0 = qb * 128 + wid * 32;    // this wave's 32 q-rows
  const int cq = lane & 31;              // softmax column (q index) owned by this lane
  const int hi = lane >> 5;

  const u16* Qb = Q  + ((size_t)bh * S_LEN + q0) * 64;
  const u16* Kb = Kt + (size_t)kvh * S_LEN * 64;
  const u16* Vb = VT + (size_t)kvh * 64 * S_LEN;   // VT[d][s]

  // Q B-fragments (persistent): frag t holds Q[q0+cq][16t + 8hi + i]
  bf16x8 qf[4];
#pragma unroll
  for (int t = 0; t < 4; ++t)
    qf[t] = *reinterpret_cast<const bf16x8*>(&Qb[cq * 64 + t * 16 + hi * 8]);

  f32x16 o0 = {}, o1 = {};
  float m = -1e30f, l = 0.f;

  __shared__ float xch[4][32];

  const int nt = (q0 >> 5) + 1;
  for (int t = 0; t < nt; ++t) {
    const int k0 = t << 5;
    // K A-frags (row = k0+cq) and V B-frags (col d = dh*32+cq, k-rows from VT row)
    bf16x8 kf[4], vf[4];
#pragma unroll
    for (int tt = 0; tt < 4; ++tt)
      kf[tt] = *reinterpret_cast<const bf16x8*>(&Kb[(size_t)(k0 + cq) * 64 + tt * 16 + hi * 8]);
#pragma unroll
    for (int kh = 0; kh < 2; ++kh)
#pragma unroll
      for (int dh = 0; dh < 2; ++dh)
        vf[kh * 2 + dh] = *reinterpret_cast<const bf16x8*>(&Vb[(size_t)(dh * 32 + cq) * S_LEN + k0 + kh * 16 + hi * 8]);

    // S = K (32k x 64d) x Q^T (64d x 32q): two independent accumulation chains
    f32x16 sA = {}, sB = {};
    sA = __builtin_amdgcn_mfma_f32_32x32x16_bf16(kf[0], qf[0], sA, 0, 0, 0);
    sB = __builtin_amdgcn_mfma_f32_32x32x16_bf16(kf[1], qf[1], sB, 0, 0, 0);
    sA = __builtin_amdgcn_mfma_f32_32x32x16_bf16(kf[2], qf[2], sA, 0, 0, 0);
    sB = __builtin_amdgcn_mfma_f32_32x32x16_bf16(kf[3], qf[3], sB, 0, 0, 0);

    // lane holds S[k = k0 + (r&3)+8*(r>>2)+4*hi][q = q0+cq], exp2-domain
    float p[16];
#pragma unroll
    for (int r = 0; r < 16; ++r) p[r] = (sA[r] + sB[r]) * ASCALE;
    if (t == nt - 1) {   // diagonal tile: k0 == q0
#pragma unroll
      for (int r = 0; r < 16; ++r) {
        int kk = (r & 3) + 8 * (r >> 2) + 4 * hi;
        if (kk > cq) p[r] = -1e30f;
      }
    }
    float tmax = p[0];
#pragma unroll
    for (int r = 1; r < 16; ++r) tmax = fmaxf(tmax, p[r]);
    tmax = fmaxf(tmax, __shfl_xor(tmax, 32));

    if (!__all(tmax <= m + 8.0f)) {        // defer-max (T13)
      float mn = fmaxf(m, tmax);
      float corr = exp2f(m - mn);
      m = mn;
      l *= corr;
      if (hi == 0) xch[wid][cq] = corr;
      asm volatile("s_waitcnt lgkmcnt(0)" ::: "memory");
      __builtin_amdgcn_sched_barrier(0);
      float4 c0 = *reinterpret_cast<const float4*>(&xch[wid][4 * hi + 0]);
      float4 c1 = *reinterpret_cast<const float4*>(&xch[wid][4 * hi + 8]);
      float4 c2 = *reinterpret_cast<const float4*>(&xch[wid][4 * hi + 16]);
      float4 c3 = *reinterpret_cast<const float4*>(&xch[wid][4 * hi + 24]);
      float ca[16] = {c0.x,c0.y,c0.z,c0.w, c1.x,c1.y,c1.z,c1.w,
                      c2.x,c2.y,c2.z,c2.w, c3.x,c3.y,c3.z,c3.w};
#pragma unroll
      for (int r = 0; r < 16; ++r) { o0[r] *= ca[r]; o1[r] *= ca[r]; }
    }

    float ts = 0.f;
#pragma unroll
    for (int r = 0; r < 16; ++r) { p[r] = exp2f(p[r] - m); ts += p[r]; }
    ts += __shfl_xor(ts, 32);
    l += ts;

    // pack P to bf16 words (RNE via cvt_pk), exchange halves, build A-frags
    uint32_t wds[8], pw[8];
#pragma unroll
    for (int j = 0; j < 8; ++j) {
      uint32_t wv;
      asm("v_cvt_pk_bf16_f32 %0, %1, %2" : "=v"(wv) : "v"(p[2*j]), "v"(p[2*j+1]));
      wds[j] = wv;
    }
#pragma unroll
    for (int j = 0; j < 8; ++j) pw[j] = __shfl_xor(wds[j], 32);
    union { uint32_t u[4]; bf16x8 v; } pa0, pa1;
    pa0.u[0] = hi ? pw[2]  : wds[0];
    pa0.u[1] = hi ? pw[3]  : wds[1];
    pa0.u[2] = hi ? wds[2] : pw[0];
    pa0.u[3] = hi ? wds[3] : pw[1];
    pa1.u[0] = hi ? pw[6]  : wds[4];
    pa1.u[1] = hi ? pw[7]  : wds[5];
    pa1.u[2] = hi ? wds[6] : pw[4];
    pa1.u[3] = hi ? wds[7] : pw[5];

    o0 = __builtin_amdgcn_mfma_f32_32x32x16_bf16(pa0.v, vf[0], o0, 0, 0, 0);
    o0 = __builtin_amdgcn_mfma_f32_32x32x16_bf16(pa1.v, vf[2], o0, 0, 0, 0);
    o1 = __builtin_amdgcn_mfma_f32_32x32x16_bf16(pa0.v, vf[1], o1, 0, 0, 0);
    o1 = __builtin_amdgcn_mfma_f32_32x32x16_bf16(pa1.v, vf[3], o1, 0, 0, 0);
  }

  // epilogue: per-row 1/l broadcast via LDS, normalize, store
  float linv = 1.0f / l;
  if (hi == 0) xch[wid][cq] = linv;
  asm volatile("s_waitcnt lgkmcnt(0)" ::: "memory");
  __builtin_amdgcn_sched_barrier(0);
  float4 n0 = *reinterpret_cast<const float4*>(&xch[wid][4 * hi + 0]);
  float4 n1 = *reinterpret_cast<const float4*>(&xch[wid][4 * hi + 8]);
  float4 n2 = *reinterpret_cast<const float4*>(&xch[wid][4 * hi + 16]);
  float4 n3 = *reinterpret_cast<const float4*>(&xch[wid][4 * hi + 24]);
  float na[16] = {n0.x,n0.y,n0.z,n0.w, n1.x,n1.y,n1.z,n1.w,
                  n2.x,n2.y,n2.z,n2.w, n3.x,n3.y,n3.z,n3.w};
#pragma unroll
  for (int r = 0; r < 16; ++r) {
    int row = (r & 3) + 8 * (r >> 2) + 4 * hi;
    size_t base = (size_t)(b * S_LEN + q0 + row) * D_MODEL + h * 64;
    ctx[base + cq]      = f2b(o0[r] * na[r]);
    ctx[base + 32 + cq] = f2b(o1[r] * na[r]);
  }
}

// ---------------------------------- host ---------------------------------------------
extern "C" void kernel_launch(void* const* d_in, const int* in_sizes, int n_in,
                              void* d_out, int out_size, void* d_ws, size_t ws_size,
                              hipStream_t stream)
{
  const float* x     = (const float*)d_in[0];
  const float* wn1   = (const float*)d_in[1];
  const float* wqkv  = (const float*)d_in[2];
  const float* wout  = (const float*)d_in[3];
  const float* wn2   = (const float*)d_in[4];
  const float* wgate = (const float*)d_in[5];
  const float* wup   = (const float*)d_in[6];
  const float* wdown = (const float*)d_in[7];
  float* out = (float*)d_out;
  char* ws = (char*)d_ws;

  float* cosT = (float*)(ws + 0);
  float* sinT = (float*)(ws + 262144);
  u16*   wT   = (u16*)  (ws + 524288);
  u16*   hB   = (u16*)  (ws + 17301504);
  u16*   x1b  = (u16*)  (ws + 34078720);
  char*  S    = ws + 50855936;
  u16*   qkvB = (u16*)(S + 0);
  u16*   qB   = (u16*)(S + 25165824);
  u16*   kB   = (u16*)(S + 41943040);
  u16*   vtB  = (u16*)(S + 46137344);
  u16*   ctxB = (u16*)(S + 50331648);
  u16*   gsB  = (u16*)(S + 0);

  sincos_kernel<<<dim3(256), 256, 0, stream>>>(cosT, sinT);
  rmsnorm_kernel<false><<<dim3(NTOK), 256, 0, stream>>>(x, wn1, hB);

  wconv_kernel<<<dim3((2048/64)*(3072/64)), 256, 0, stream>>>(wqkv, wT, 3072, 2048, 3072, 0, 0);
  gemm256_kernel<4><<<dim3(QKV_N/256, NTOK/256), 512, 0, stream>>>(hB, wT, 2048, 2048, 2048, 3072, 0, nullptr, qkvB, nullptr, nullptr, nullptr);
  rope_kernel<<<dim3(NTOK), 256, 0, stream>>>(qkvB, cosT, sinT, qB, kB, vtB);
  attn_kernel<<<dim3(64, 16), 256, 0, stream>>>(qB, kB, vtB, ctxB);

  wconv_kernel<<<dim3((2048/64)*(2048/64)), 256, 0, stream>>>(wout, wT, 2048, 2048, 2048, 0, 0);
  gemm256_kernel<6><<<dim3(D_MODEL/256, NTOK/256), 512, 0, stream>>>(ctxB, wT, 2048, 2048, 2048, 2048, 0, nullptr, x1b, x, nullptr, nullptr);

  rmsnorm_kernel<true><<<dim3(NTOK), 256, 0, stream>>>(x1b, wn2, hB);

  for (int c = 0; c < 2; ++c) {
    wconv_kernel<<<dim3((2048/64)*(4096/64)), 256, 0, stream>>>(wgate, wT, 8192, 2048, 4096, 0, c*4096);
    gemm256_kernel<2><<<dim3(4096/256, NTOK/256), 512, 0, stream>>>(hB, wT, 2048, 2048, 2048, 8192, c*4096, nullptr, gsB, nullptr, nullptr, nullptr);
  }
  for (int c = 0; c < 2; ++c) {
    wconv_kernel<<<dim3((2048/64)*(4096/64)), 256, 0, stream>>>(wup, wT, 8192, 2048, 4096, 0, c*4096);
    gemm256_kernel<3><<<dim3(4096/256, NTOK/256), 512, 0, stream>>>(hB, wT, 2048, 2048, 2048, 8192, c*4096, nullptr, gsB, nullptr, nullptr, gsB);
  }
  wconv_kernel<<<dim3((4096/64)*(2048/64)), 256, 0, stream>>>(wdown, wT, 2048, 4096, 2048, 0, 0);
  gemm256_kernel<7><<<dim3(D_MODEL/256, NTOK/256), 512, 0, stream>>>(gsB, wT, 4096, 8192, 4096, 2048, 0, out, nullptr, nullptr, x1b, nullptr);
  wconv_kernel<<<dim3((4096/64)*(2048/64)), 256, 0, stream>>>(wdown, wT, 2048, 4096, 2048, 4096, 0);
  gemm256_kernel<5><<<dim3(D_MODEL/256, NTOK/256), 512, 0, stream>>>(gsB + 4096, wT, 4096, 8192, 4096, 2048, 0, out, nullptr, nullptr, nullptr, nullptr);
}

// Round 5
// 900.279 us; speedup vs baseline: 1.2856x; 1.0507x over previous
//
#include <hip/hip_runtime.h>
#include <stdint.h>

#define D_MODEL 2048
#define S_LEN   2048
#define NTOK    4096
#define QKV_N   3072
#define DFF     8192

typedef float  f32x4   __attribute__((ext_vector_type(4)));
typedef float  f32x16  __attribute__((ext_vector_type(16)));
typedef __bf16 bf16x8  __attribute__((ext_vector_type(8)));
typedef unsigned short u16;
typedef unsigned short u16x8 __attribute__((ext_vector_type(8)));

__device__ __forceinline__ float b2f(u16 u){ union{float f; uint32_t i;} v; v.i = ((uint32_t)u) << 16; return v.f; }
__device__ __forceinline__ u16 f2b(float f){
  union{float f; uint32_t i;} v; v.f = f;
  uint32_t r = v.i + 0x7FFFu + ((v.i >> 16) & 1u);
  return (u16)(r >> 16);
}

__device__ __forceinline__ void gload_lds16(const void* gsrc, void* ldst){
  __builtin_amdgcn_global_load_lds(
      (const __attribute__((address_space(1))) void*)gsrc,
      (__attribute__((address_space(3))) void*)ldst,
      16, 0, 0);
}

// ------- weight convert+transpose (sub-block): W[k0g+.., n0g+..] f32 -> WT[Nt][Kt] bf16
__global__ __launch_bounds__(256) void wconv_kernel(const float* __restrict__ W, u16* __restrict__ WT,
                                                    int Nfull, int Kt, int Nt, int k0g, int n0g)
{
  __shared__ float tile[64][65];
  const int nTn = Nt >> 6;
  const int tk = blockIdx.x / nTn, tn = blockIdx.x % nTn;
  const int k0 = tk << 6, n0 = tn << 6;
  const int t  = threadIdx.x;
  const int c4 = (t & 15) << 2;
  const int r  = t >> 4;
#pragma unroll
  for (int i = 0; i < 4; ++i) {
    float4 v = *reinterpret_cast<const float4*>(&W[(size_t)(k0g + k0 + r + i*16) * Nfull + n0g + n0 + c4]);
    tile[r + i*16][c4+0] = v.x; tile[r + i*16][c4+1] = v.y;
    tile[r + i*16][c4+2] = v.z; tile[r + i*16][c4+3] = v.w;
  }
  __syncthreads();
#pragma unroll
  for (int i = 0; i < 4; ++i) {
    int n = r + i*16;
    ushort4 ov;
    ov.x = f2b(tile[c4+0][n]); ov.y = f2b(tile[c4+1][n]);
    ov.z = f2b(tile[c4+2][n]); ov.w = f2b(tile[c4+3][n]);
    *reinterpret_cast<ushort4*>(&WT[(size_t)(n0 + n) * Kt + k0 + c4]) = ov;
  }
}

// ------- rope cos/sin table --------------------------------------------------------
__global__ void sincos_kernel(float* __restrict__ ct, float* __restrict__ st)
{
  int idx = blockIdx.x * 256 + threadIdx.x;
  if (idx >= S_LEN * 32) return;
  int p = idx >> 5, i = idx & 31;
  double freq = pow(10000.0, -((double)(2*i)) / 64.0);
  double ang  = (double)p * freq;
  ct[idx] = (float)cos(ang);
  st[idx] = (float)sin(ang);
}

// ------- RMSNorm -------------------------------------------------------------------
template<bool BF16IN>
__global__ __launch_bounds__(256) void rmsnorm_kernel(const void* __restrict__ xin, const float* __restrict__ w, u16* __restrict__ out)
{
  const int row = blockIdx.x;
  const int t = threadIdx.x;
  float v[8];
  if (BF16IN) {
    const u16* xr = ((const u16*)xin) + (size_t)row * D_MODEL;
    u16x8 a = *reinterpret_cast<const u16x8*>(&xr[t*8]);
#pragma unroll
    for (int j = 0; j < 8; ++j) v[j] = b2f(a[j]);
  } else {
    const float* xr = ((const float*)xin) + (size_t)row * D_MODEL;
    float4 a = *reinterpret_cast<const float4*>(&xr[t*8]);
    float4 c = *reinterpret_cast<const float4*>(&xr[t*8+4]);
    v[0]=a.x; v[1]=a.y; v[2]=a.z; v[3]=a.w; v[4]=c.x; v[5]=c.y; v[6]=c.z; v[7]=c.w;
  }
  float ss = 0.f;
#pragma unroll
  for (int j = 0; j < 8; ++j) ss += v[j]*v[j];
#pragma unroll
  for (int d = 1; d < 64; d <<= 1) ss += __shfl_xor(ss, d);
  __shared__ float red[4];
  if ((t & 63) == 0) red[t >> 6] = ss;
  __syncthreads();
  ss = red[0] + red[1] + red[2] + red[3];
  const float sc = rsqrtf(ss * (1.0f / (float)D_MODEL) + 1e-5f);
  float4 w0 = *reinterpret_cast<const float4*>(&w[t*8]);
  float4 w1 = *reinterpret_cast<const float4*>(&w[t*8+4]);
  u16x8 o;
  o[0]=f2b(v[0]*sc*w0.x); o[1]=f2b(v[1]*sc*w0.y); o[2]=f2b(v[2]*sc*w0.z); o[3]=f2b(v[3]*sc*w0.w);
  o[4]=f2b(v[4]*sc*w1.x); o[5]=f2b(v[5]*sc*w1.y); o[6]=f2b(v[6]*sc*w1.z); o[7]=f2b(v[7]*sc*w1.w);
  *reinterpret_cast<u16x8*>(&out[(size_t)row * D_MODEL + t*8]) = o;
}

// ------- 256x256 8-phase bf16 MFMA GEMM (m201 template): A[M][lda] x BT[N][ldb] -------
// 8 waves (2M x 4N), per-wave 128x64. BK=64, 2 K-tiles/iter, 8 phases.
// LDS 128KiB = 2 bufs x (A 256x64 + B 256x64). Granule swizzle: col_granule ^= row&7,
// applied on pre-swizzled global source (linear gload_lds dest) AND swizzled ds_read.
// Counted vmcnt(4) at phases 4/8 only. EPI as before.
template<int EPI>
__global__ __launch_bounds__(512, 2) void gemm8p_kernel(
    const u16* __restrict__ A, const u16* __restrict__ BT,
    int K, int lda, int ldb, int ldc, int n_off,
    float* Cf, u16* Cb,
    const float* __restrict__ resf, const u16* __restrict__ resb, const u16* other)
{
  __shared__ u16 lds[65536];
  const int tid = threadIdx.x;
  const int w = tid >> 6, lane = tid & 63;
  const int g = lane >> 4, lr = lane & 15;
  const int wm = w >> 2, wn = w & 3;
  const int bn = blockIdx.x, bm = blockIdx.y;
  const int NT = K >> 6;
  const int NI = NT >> 1;

  const int srow = tid >> 3;                    // 0..63
  const int sg   = (tid & 7) ^ (srow & 7);      // swizzled source granule
  const u16* Asrc = A  + (size_t)(bm * 256) * lda;
  const u16* Bsrc = BT + (size_t)(bn * 256) * ldb;

  const int agc0 = ((0 + g) ^ (lr & 7)) * 8;    // read granule offsets (u16)
  const int agc1 = ((4 + g) ^ (lr & 7)) * 8;

  f32x4 acc[8][4];
#pragma unroll
  for (int i = 0; i < 8; ++i)
#pragma unroll
    for (int j = 0; j < 4; ++j) acc[i][j] = (f32x4){0.f, 0.f, 0.f, 0.f};
  bf16x8 af[4][2], bf0[2][2], bf1[2][2];

#define STAGE_H(isB, h, b, T) do {                                           \
    int tc = ((T) < NT) ? (T) : (NT - 1);                                    \
    const u16* sb = (isB) ? Bsrc : Asrc;                                     \
    const int  sld = (isB) ? ldb : lda;                                      \
    const u16* s0 = sb + (size_t)((h)*128 + srow) * sld + tc*64 + sg*8;      \
    u16* dst = &lds[(b)*32768 + (isB)*16384 + (h)*8192 + tid*8];             \
    gload_lds16(s0, dst);                                                    \
    gload_lds16(s0 + (size_t)64 * sld, dst + 4096);                          \
  } while (0)

#define LOADA(mih, b) { _Pragma("unroll") for (int q = 0; q < 4; ++q) {      \
    const u16* rp = &lds[(b)*32768 + (wm*128 + (mih)*64 + q*16 + lr) * 64];  \
    af[q][0] = *(const bf16x8*)(rp + agc0);                                  \
    af[q][1] = *(const bf16x8*)(rp + agc1); } }

#define LOADB(dst, nih, b) { _Pragma("unroll") for (int nq = 0; nq < 2; ++nq) { \
    const u16* rp = &lds[(b)*32768 + 16384 + (wn*64 + (nih)*32 + nq*16 + lr) * 64]; \
    dst[nq][0] = *(const bf16x8*)(rp + agc0);                                \
    dst[nq][1] = *(const bf16x8*)(rp + agc1); } }

#define MM(mih, nih, BF) {                                                   \
    __builtin_amdgcn_s_setprio(1);                                           \
    _Pragma("unroll") for (int kk = 0; kk < 2; ++kk)                         \
      _Pragma("unroll") for (int q = 0; q < 4; ++q)                          \
        _Pragma("unroll") for (int nq = 0; nq < 2; ++nq)                     \
          acc[(mih)*4+q][(nih)*2+nq] = __builtin_amdgcn_mfma_f32_16x16x32_bf16( \
              af[q][kk], BF[nq][kk], acc[(mih)*4+q][(nih)*2+nq], 0, 0, 0);   \
    __builtin_amdgcn_s_setprio(0); }

#define SYNC_MID  __builtin_amdgcn_s_barrier();                              \
                  asm volatile("s_waitcnt lgkmcnt(0)" ::: "memory");         \
                  __builtin_amdgcn_sched_barrier(0);
#define PHEND     __builtin_amdgcn_s_barrier();
#define PHEND_VM  asm volatile("s_waitcnt vmcnt(4)" ::: "memory");           \
                  __builtin_amdgcn_s_barrier();

  // prologue: tile0 full (8 loads), tile1 B halves (4 loads)
  STAGE_H(0, 0, 0, 0); STAGE_H(0, 1, 0, 0);
  STAGE_H(1, 0, 0, 0); STAGE_H(1, 1, 0, 0);
  STAGE_H(1, 0, 1, 1); STAGE_H(1, 1, 1, 1);
  asm volatile("s_waitcnt vmcnt(4)" ::: "memory");
  __builtin_amdgcn_s_barrier();

  for (int i = 0; i < NI; ++i) {
    const int t0 = 2 * i;
    // ph1: compute tile t0 Q(A0,B0); stage buf1.A0 <- tile t0+1
    LOADA(0, 0); LOADB(bf0, 0, 0);
    STAGE_H(0, 0, 1, t0 + 1);
    SYNC_MID; MM(0, 0, bf0); PHEND;
    // ph2: Q(A0,B1); stage buf1.A1
    LOADB(bf1, 1, 0);
    STAGE_H(0, 1, 1, t0 + 1);
    SYNC_MID; MM(0, 1, bf1); PHEND;
    // ph3: Q(A1,B1); stage buf0.B0 <- tile t0+2
    LOADA(1, 0);
    STAGE_H(1, 0, 0, t0 + 2);
    SYNC_MID; MM(1, 1, bf1); PHEND;
    // ph4: Q(A1,B0); stage buf0.B1; vmcnt(4) -> tile t0+1 ready
    STAGE_H(1, 1, 0, t0 + 2);
    SYNC_MID; MM(1, 0, bf0); PHEND_VM;
    // ph5: compute tile t0+1 Q(A0,B0); stage buf0.A0 <- tile t0+2
    LOADA(0, 1); LOADB(bf0, 0, 1);
    STAGE_H(0, 0, 0, t0 + 2);
    SYNC_MID; MM(0, 0, bf0); PHEND;
    // ph6: Q(A0,B1); stage buf0.A1
    LOADB(bf1, 1, 1);
    STAGE_H(0, 1, 0, t0 + 2);
    SYNC_MID; MM(0, 1, bf1); PHEND;
    // ph7: Q(A1,B1); stage buf1.B0 <- tile t0+3
    LOADA(1, 1);
    STAGE_H(1, 0, 1, t0 + 3);
    SYNC_MID; MM(1, 1, bf1); PHEND;
    // ph8: Q(A1,B0); stage buf1.B1; vmcnt(4) -> tile t0+2 ready
    STAGE_H(1, 1, 1, t0 + 3);
    SYNC_MID; MM(1, 0, bf0); PHEND_VM;
  }
#undef STAGE_H
#undef LOADA
#undef LOADB
#undef MM
#undef SYNC_MID
#undef PHEND
#undef PHEND_VM

#pragma unroll
  for (int mi = 0; mi < 8; ++mi) {
    const int rowOff = (mi >> 2) * 64 + (mi & 3) * 16;
#pragma unroll
    for (int ni = 0; ni < 4; ++ni) {
      const int colOff = (ni >> 1) * 32 + (ni & 1) * 16;
#pragma unroll
      for (int j = 0; j < 4; ++j) {
        int row = bm*256 + wm*128 + rowOff + g*4 + j;
        int col = n_off + bn*256 + wn*64 + colOff + lr;
        size_t idx = (size_t)row * ldc + col;
        float v = acc[mi][ni][j];
        if (EPI == 2)      Cb[idx] = f2b(v / (1.0f + __expf(-v)));
        else if (EPI == 3) Cb[idx] = f2b(v * b2f(other[idx]));
        else if (EPI == 4) Cb[idx] = f2b(v);
        else if (EPI == 5) Cf[idx] += v;
        else if (EPI == 6) Cb[idx] = f2b(v + resf[idx]);
        else if (EPI == 7) Cf[idx] = v + b2f(resb[idx]);
      }
    }
  }
}

// ------- RoPE + relayout ------------------------------------------------------------
__global__ __launch_bounds__(256) void rope_kernel(
    const u16* __restrict__ qkv, const float* __restrict__ ct, const float* __restrict__ st,
    u16* __restrict__ Q, u16* __restrict__ Kt, u16* __restrict__ VT)
{
  const int tok = blockIdx.x;
  const int b = tok >> 11, s = tok & (S_LEN - 1);
  const int w = threadIdx.x >> 6, lane = threadIdx.x & 63;
  const size_t base = (size_t)tok * QKV_N;
  for (int slot = w; slot < 48; slot += 4) {
    int col = (slot < 32) ? slot * 64 : (slot < 40 ? 2048 + (slot - 32) * 64 : 2560 + (slot - 40) * 64);
    float v = b2f(qkv[base + col + lane]);
    if (slot < 40) {
      int i = lane & 31;
      float c = ct[s * 32 + i], sn = st[s * 32 + i];
      float p = b2f(qkv[base + col + (lane ^ 32)]);
      v = (lane < 32) ? (v * c - p * sn) : (v * c + p * sn);
    }
    u16 ob = f2b(v);
    if (slot < 32)      Q [((size_t)(b * 32 + slot)      * S_LEN + s) * 64 + lane] = ob;
    else if (slot < 40) Kt[((size_t)(b * 8 + slot - 32)  * S_LEN + s) * 64 + lane] = ob;
    else                VT[((size_t)(b * 8 + slot - 40)  * 64 + lane) * S_LEN + s] = ob;
  }
}

// ------- causal GQA flash attention: swapped QK^T, in-register softmax ----------------
#define ASCALE 0.1803368801111204f   /* 0.125 * log2(e) */
__global__ __launch_bounds__(256, 3) void attn_kernel(
    const u16* __restrict__ Q, const u16* __restrict__ Kt,
    const u16* __restrict__ VT, u16* __restrict__ ctx)
{
  const int bh  = blockIdx.x;
  const int qb  = 15 - blockIdx.y;
  const int wid = threadIdx.x >> 6;
  const int lane = threadIdx.x & 63;
  const int b = bh >> 5, h = bh & 31;
  const int kvh = (b << 3) + (h >> 2);
  const int q0 = qb * 128 + wid * 32;
  const int cq = lane & 31;
  const int hi = lane >> 5;

  const u16* Qb = Q  + ((size_t)bh * S_LEN + q0) * 64;
  const u16* Kb = Kt + (size_t)kvh * S_LEN * 64;
  const u16* Vb = VT + (size_t)kvh * 64 * S_LEN;

  bf16x8 qf[4];
#pragma unroll
  for (int t = 0; t < 4; ++t)
    qf[t] = *reinterpret_cast<const bf16x8*>(&Qb[cq * 64 + t * 16 + hi * 8]);

  f32x16 o0 = {}, o1 = {};
  float m = -1e30f, l = 0.f;

  __shared__ float xch[4][32];

  const int nt = (q0 >> 5) + 1;
  for (int t = 0; t < nt; ++t) {
    const int k0 = t << 5;
    bf16x8 kf[4], vf[4];
#pragma unroll
    for (int tt = 0; tt < 4; ++tt)
      kf[tt] = *reinterpret_cast<const bf16x8*>(&Kb[(size_t)(k0 + cq) * 64 + tt * 16 + hi * 8]);
#pragma unroll
    for (int kh = 0; kh < 2; ++kh)
#pragma unroll
      for (int dh = 0; dh < 2; ++dh)
        vf[kh * 2 + dh] = *reinterpret_cast<const bf16x8*>(&Vb[(size_t)(dh * 32 + cq) * S_LEN + k0 + kh * 16 + hi * 8]);

    f32x16 sA = {}, sB = {};
    sA = __builtin_amdgcn_mfma_f32_32x32x16_bf16(kf[0], qf[0], sA, 0, 0, 0);
    sB = __builtin_amdgcn_mfma_f32_32x32x16_bf16(kf[1], qf[1], sB, 0, 0, 0);
    sA = __builtin_amdgcn_mfma_f32_32x32x16_bf16(kf[2], qf[2], sA, 0, 0, 0);
    sB = __builtin_amdgcn_mfma_f32_32x32x16_bf16(kf[3], qf[3], sB, 0, 0, 0);

    float p[16];
#pragma unroll
    for (int r = 0; r < 16; ++r) p[r] = (sA[r] + sB[r]) * ASCALE;
    if (t == nt - 1) {
#pragma unroll
      for (int r = 0; r < 16; ++r) {
        int kk = (r & 3) + 8 * (r >> 2) + 4 * hi;
        if (kk > cq) p[r] = -1e30f;
      }
    }
    float tmax = p[0];
#pragma unroll
    for (int r = 1; r < 16; ++r) tmax = fmaxf(tmax, p[r]);
    tmax = fmaxf(tmax, __shfl_xor(tmax, 32));

    if (!__all(tmax <= m + 8.0f)) {
      float mn = fmaxf(m, tmax);
      float corr = exp2f(m - mn);
      m = mn;
      l *= corr;
      if (hi == 0) xch[wid][cq] = corr;
      asm volatile("s_waitcnt lgkmcnt(0)" ::: "memory");
      __builtin_amdgcn_sched_barrier(0);
      float4 c0 = *reinterpret_cast<const float4*>(&xch[wid][4 * hi + 0]);
      float4 c1 = *reinterpret_cast<const float4*>(&xch[wid][4 * hi + 8]);
      float4 c2 = *reinterpret_cast<const float4*>(&xch[wid][4 * hi + 16]);
      float4 c3 = *reinterpret_cast<const float4*>(&xch[wid][4 * hi + 24]);
      float ca[16] = {c0.x,c0.y,c0.z,c0.w, c1.x,c1.y,c1.z,c1.w,
                      c2.x,c2.y,c2.z,c2.w, c3.x,c3.y,c3.z,c3.w};
#pragma unroll
      for (int r = 0; r < 16; ++r) { o0[r] *= ca[r]; o1[r] *= ca[r]; }
    }

    float ts = 0.f;
#pragma unroll
    for (int r = 0; r < 16; ++r) { p[r] = exp2f(p[r] - m); ts += p[r]; }
    ts += __shfl_xor(ts, 32);
    l += ts;

    uint32_t wds[8], pw[8];
#pragma unroll
    for (int j = 0; j < 8; ++j) {
      uint32_t wv;
      asm("v_cvt_pk_bf16_f32 %0, %1, %2" : "=v"(wv) : "v"(p[2*j]), "v"(p[2*j+1]));
      wds[j] = wv;
    }
#pragma unroll
    for (int j = 0; j < 8; ++j) pw[j] = __shfl_xor(wds[j], 32);
    union { uint32_t u[4]; bf16x8 v; } pa0, pa1;
    pa0.u[0] = hi ? pw[2]  : wds[0];
    pa0.u[1] = hi ? pw[3]  : wds[1];
    pa0.u[2] = hi ? wds[2] : pw[0];
    pa0.u[3] = hi ? wds[3] : pw[1];
    pa1.u[0] = hi ? pw[6]  : wds[4];
    pa1.u[1] = hi ? pw[7]  : wds[5];
    pa1.u[2] = hi ? wds[6] : pw[4];
    pa1.u[3] = hi ? wds[7] : pw[5];

    o0 = __builtin_amdgcn_mfma_f32_32x32x16_bf16(pa0.v, vf[0], o0, 0, 0, 0);
    o0 = __builtin_amdgcn_mfma_f32_32x32x16_bf16(pa1.v, vf[2], o0, 0, 0, 0);
    o1 = __builtin_amdgcn_mfma_f32_32x32x16_bf16(pa0.v, vf[1], o1, 0, 0, 0);
    o1 = __builtin_amdgcn_mfma_f32_32x32x16_bf16(pa1.v, vf[3], o1, 0, 0, 0);
  }

  float linv = 1.0f / l;
  if (hi == 0) xch[wid][cq] = linv;
  asm volatile("s_waitcnt lgkmcnt(0)" ::: "memory");
  __builtin_amdgcn_sched_barrier(0);
  float4 n0 = *reinterpret_cast<const float4*>(&xch[wid][4 * hi + 0]);
  float4 n1 = *reinterpret_cast<const float4*>(&xch[wid][4 * hi + 8]);
  float4 n2 = *reinterpret_cast<const float4*>(&xch[wid][4 * hi + 16]);
  float4 n3 = *reinterpret_cast<const float4*>(&xch[wid][4 * hi + 24]);
  float na[16] = {n0.x,n0.y,n0.z,n0.w, n1.x,n1.y,n1.z,n1.w,
                  n2.x,n2.y,n2.z,n2.w, n3.x,n3.y,n3.z,n3.w};
#pragma unroll
  for (int r = 0; r < 16; ++r) {
    int row = (r & 3) + 8 * (r >> 2) + 4 * hi;
    size_t base = (size_t)(b * S_LEN + q0 + row) * D_MODEL + h * 64;
    ctx[base + cq]      = f2b(o0[r] * na[r]);
    ctx[base + 32 + cq] = f2b(o1[r] * na[r]);
  }
}

// ---------------------------------- host ---------------------------------------------
extern "C" void kernel_launch(void* const* d_in, const int* in_sizes, int n_in,
                              void* d_out, int out_size, void* d_ws, size_t ws_size,
                              hipStream_t stream)
{
  const float* x     = (const float*)d_in[0];
  const float* wn1   = (const float*)d_in[1];
  const float* wqkv  = (const float*)d_in[2];
  const float* wout  = (const float*)d_in[3];
  const float* wn2   = (const float*)d_in[4];
  const float* wgate = (const float*)d_in[5];
  const float* wup   = (const float*)d_in[6];
  const float* wdown = (const float*)d_in[7];
  float* out = (float*)d_out;
  char* ws = (char*)d_ws;

  float* cosT = (float*)(ws + 0);
  float* sinT = (float*)(ws + 262144);
  u16*   wT   = (u16*)  (ws + 524288);
  u16*   hB   = (u16*)  (ws + 17301504);
  u16*   x1b  = (u16*)  (ws + 34078720);
  char*  S    = ws + 50855936;
  u16*   qkvB = (u16*)(S + 0);
  u16*   qB   = (u16*)(S + 25165824);
  u16*   kB   = (u16*)(S + 41943040);
  u16*   vtB  = (u16*)(S + 46137344);
  u16*   ctxB = (u16*)(S + 50331648);
  u16*   gsB  = (u16*)(S + 0);

  sincos_kernel<<<dim3(256), 256, 0, stream>>>(cosT, sinT);
  rmsnorm_kernel<false><<<dim3(NTOK), 256, 0, stream>>>(x, wn1, hB);

  wconv_kernel<<<dim3((2048/64)*(3072/64)), 256, 0, stream>>>(wqkv, wT, 3072, 2048, 3072, 0, 0);
  gemm8p_kernel<4><<<dim3(QKV_N/256, NTOK/256), 512, 0, stream>>>(hB, wT, 2048, 2048, 2048, 3072, 0, nullptr, qkvB, nullptr, nullptr, nullptr);
  rope_kernel<<<dim3(NTOK), 256, 0, stream>>>(qkvB, cosT, sinT, qB, kB, vtB);
  attn_kernel<<<dim3(64, 16), 256, 0, stream>>>(qB, kB, vtB, ctxB);

  wconv_kernel<<<dim3((2048/64)*(2048/64)), 256, 0, stream>>>(wout, wT, 2048, 2048, 2048, 0, 0);
  gemm8p_kernel<6><<<dim3(D_MODEL/256, NTOK/256), 512, 0, stream>>>(ctxB, wT, 2048, 2048, 2048, 2048, 0, nullptr, x1b, x, nullptr, nullptr);

  rmsnorm_kernel<true><<<dim3(NTOK), 256, 0, stream>>>(x1b, wn2, hB);

  for (int c = 0; c < 2; ++c) {
    wconv_kernel<<<dim3((2048/64)*(4096/64)), 256, 0, stream>>>(wgate, wT, 8192, 2048, 4096, 0, c*4096);
    gemm8p_kernel<2><<<dim3(4096/256, NTOK/256), 512, 0, stream>>>(hB, wT, 2048, 2048, 2048, 8192, c*4096, nullptr, gsB, nullptr, nullptr, nullptr);
  }
  for (int c = 0; c < 2; ++c) {
    wconv_kernel<<<dim3((2048/64)*(4096/64)), 256, 0, stream>>>(wup, wT, 8192, 2048, 4096, 0, c*4096);
    gemm8p_kernel<3><<<dim3(4096/256, NTOK/256), 512, 0, stream>>>(hB, wT, 2048, 2048, 2048, 8192, c*4096, nullptr, gsB, nullptr, nullptr, gsB);
  }
  wconv_kernel<<<dim3((4096/64)*(2048/64)), 256, 0, stream>>>(wdown, wT, 2048, 4096, 2048, 0, 0);
  gemm8p_kernel<7><<<dim3(D_MODEL/256, NTOK/256), 512, 0, stream>>>(gsB, wT, 4096, 8192, 4096, 2048, 0, out, nullptr, nullptr, x1b, nullptr);
  wconv_kernel<<<dim3((4096/64)*(2048/64)), 256, 0, stream>>>(wdown, wT, 2048, 4096, 2048, 4096, 0);
  gemm8p_kernel<5><<<dim3(D_MODEL/256, NTOK/256), 512, 0, stream>>>(gsB + 4096, wT, 4096, 8192, 4096, 2048, 0, out, nullptr, nullptr, nullptr, nullptr);
}

// Round 6
// 826.439 us; speedup vs baseline: 1.4004x; 1.0893x over previous
//
#include <hip/hip_runtime.h>
#include <stdint.h>

#define D_MODEL 2048
#define S_LEN   2048
#define NTOK    4096
#define QKV_N   3072
#define DFF     8192

typedef float  f32x4   __attribute__((ext_vector_type(4)));
typedef float  f32x16  __attribute__((ext_vector_type(16)));
typedef __bf16 bf16x8  __attribute__((ext_vector_type(8)));
typedef unsigned short u16;
typedef unsigned short u16x8 __attribute__((ext_vector_type(8)));

__device__ __forceinline__ float b2f(u16 u){ union{float f; uint32_t i;} v; v.i = ((uint32_t)u) << 16; return v.f; }
__device__ __forceinline__ u16 f2b(float f){
  union{float f; uint32_t i;} v; v.f = f;
  uint32_t r = v.i + 0x7FFFu + ((v.i >> 16) & 1u);
  return (u16)(r >> 16);
}

__device__ __forceinline__ void gload_lds16(const void* gsrc, void* ldst){
  __builtin_amdgcn_global_load_lds(
      (const __attribute__((address_space(1))) void*)gsrc,
      (__attribute__((address_space(3))) void*)ldst,
      16, 0, 0);
}

// ------- weight convert+transpose (sub-block): W[k0g+.., n0g+..] f32 -> WT[Nt][Kt] bf16
__global__ __launch_bounds__(256) void wconv_kernel(const float* __restrict__ W, u16* __restrict__ WT,
                                                    int Nfull, int Kt, int Nt, int k0g, int n0g)
{
  __shared__ float tile[64][65];
  const int nTn = Nt >> 6;
  const int tk = blockIdx.x / nTn, tn = blockIdx.x % nTn;
  const int k0 = tk << 6, n0 = tn << 6;
  const int t  = threadIdx.x;
  const int c4 = (t & 15) << 2;
  const int r  = t >> 4;
#pragma unroll
  for (int i = 0; i < 4; ++i) {
    float4 v = *reinterpret_cast<const float4*>(&W[(size_t)(k0g + k0 + r + i*16) * Nfull + n0g + n0 + c4]);
    tile[r + i*16][c4+0] = v.x; tile[r + i*16][c4+1] = v.y;
    tile[r + i*16][c4+2] = v.z; tile[r + i*16][c4+3] = v.w;
  }
  __syncthreads();
#pragma unroll
  for (int i = 0; i < 4; ++i) {
    int n = r + i*16;
    ushort4 ov;
    ov.x = f2b(tile[c4+0][n]); ov.y = f2b(tile[c4+1][n]);
    ov.z = f2b(tile[c4+2][n]); ov.w = f2b(tile[c4+3][n]);
    *reinterpret_cast<ushort4*>(&WT[(size_t)(n0 + n) * Kt + k0 + c4]) = ov;
  }
}

// ------- rope cos/sin table --------------------------------------------------------
__global__ void sincos_kernel(float* __restrict__ ct, float* __restrict__ st)
{
  int idx = blockIdx.x * 256 + threadIdx.x;
  if (idx >= S_LEN * 32) return;
  int p = idx >> 5, i = idx & 31;
  double freq = pow(10000.0, -((double)(2*i)) / 64.0);
  double ang  = (double)p * freq;
  ct[idx] = (float)cos(ang);
  st[idx] = (float)sin(ang);
}

// ------- RMSNorm -------------------------------------------------------------------
template<bool BF16IN>
__global__ __launch_bounds__(256) void rmsnorm_kernel(const void* __restrict__ xin, const float* __restrict__ w, u16* __restrict__ out)
{
  const int row = blockIdx.x;
  const int t = threadIdx.x;
  float v[8];
  if (BF16IN) {
    const u16* xr = ((const u16*)xin) + (size_t)row * D_MODEL;
    u16x8 a = *reinterpret_cast<const u16x8*>(&xr[t*8]);
#pragma unroll
    for (int j = 0; j < 8; ++j) v[j] = b2f(a[j]);
  } else {
    const float* xr = ((const float*)xin) + (size_t)row * D_MODEL;
    float4 a = *reinterpret_cast<const float4*>(&xr[t*8]);
    float4 c = *reinterpret_cast<const float4*>(&xr[t*8+4]);
    v[0]=a.x; v[1]=a.y; v[2]=a.z; v[3]=a.w; v[4]=c.x; v[5]=c.y; v[6]=c.z; v[7]=c.w;
  }
  float ss = 0.f;
#pragma unroll
  for (int j = 0; j < 8; ++j) ss += v[j]*v[j];
#pragma unroll
  for (int d = 1; d < 64; d <<= 1) ss += __shfl_xor(ss, d);
  __shared__ float red[4];
  if ((t & 63) == 0) red[t >> 6] = ss;
  __syncthreads();
  ss = red[0] + red[1] + red[2] + red[3];
  const float sc = rsqrtf(ss * (1.0f / (float)D_MODEL) + 1e-5f);
  float4 w0 = *reinterpret_cast<const float4*>(&w[t*8]);
  float4 w1 = *reinterpret_cast<const float4*>(&w[t*8+4]);
  u16x8 o;
  o[0]=f2b(v[0]*sc*w0.x); o[1]=f2b(v[1]*sc*w0.y); o[2]=f2b(v[2]*sc*w0.z); o[3]=f2b(v[3]*sc*w0.w);
  o[4]=f2b(v[4]*sc*w1.x); o[5]=f2b(v[5]*sc*w1.y); o[6]=f2b(v[6]*sc*w1.z); o[7]=f2b(v[7]*sc*w1.w);
  *reinterpret_cast<u16x8*>(&out[(size_t)row * D_MODEL + t*8]) = o;
}

// ------- shared GEMM epilogue dispatch ------------------------------------------------
// EPI: 2 silu->Cb; 3 Cb=v*other; 4 Cb=v; 5 Cf+=v; 6 Cb=f2b(v+resf); 7 Cf=v+b2f(resb)
template<int EPI>
__device__ __forceinline__ void epi_store(size_t idx, float v, float* Cf, u16* Cb,
                                          const float* resf, const u16* resb, const u16* other)
{
  if (EPI == 2)      Cb[idx] = f2b(v / (1.0f + __expf(-v)));
  else if (EPI == 3) Cb[idx] = f2b(v * b2f(other[idx]));
  else if (EPI == 4) Cb[idx] = f2b(v);
  else if (EPI == 5) Cf[idx] += v;
  else if (EPI == 6) Cb[idx] = f2b(v + resf[idx]);
  else if (EPI == 7) Cf[idx] = v + b2f(resb[idx]);
}

// ------- 256x256 8-phase bf16 MFMA GEMM (m201 template): A[M][lda] x BT[N][ldb] -------
template<int EPI>
__global__ __launch_bounds__(512, 2) void gemm8p_kernel(
    const u16* __restrict__ A, const u16* __restrict__ BT,
    int K, int lda, int ldb, int ldc, int n_off,
    float* Cf, u16* Cb,
    const float* __restrict__ resf, const u16* __restrict__ resb, const u16* other)
{
  __shared__ u16 lds[65536];
  const int tid = threadIdx.x;
  const int w = tid >> 6, lane = tid & 63;
  const int g = lane >> 4, lr = lane & 15;
  const int wm = w >> 2, wn = w & 3;
  const int bn = blockIdx.x, bm = blockIdx.y;
  const int NT = K >> 6;
  const int NI = NT >> 1;

  const int srow = tid >> 3;
  const int sg   = (tid & 7) ^ (srow & 7);
  const u16* Asrc = A  + (size_t)(bm * 256) * lda;
  const u16* Bsrc = BT + (size_t)(bn * 256) * ldb;

  const int agc0 = ((0 + g) ^ (lr & 7)) * 8;
  const int agc1 = ((4 + g) ^ (lr & 7)) * 8;

  f32x4 acc[8][4];
#pragma unroll
  for (int i = 0; i < 8; ++i)
#pragma unroll
    for (int j = 0; j < 4; ++j) acc[i][j] = (f32x4){0.f, 0.f, 0.f, 0.f};
  bf16x8 af[4][2], bf0[2][2], bf1[2][2];

#define STAGE_H(isB, h, b, T) do {                                           \
    int tc = ((T) < NT) ? (T) : (NT - 1);                                    \
    const u16* sb = (isB) ? Bsrc : Asrc;                                     \
    const int  sld = (isB) ? ldb : lda;                                      \
    const u16* s0 = sb + (size_t)((h)*128 + srow) * sld + tc*64 + sg*8;      \
    u16* dst = &lds[(b)*32768 + (isB)*16384 + (h)*8192 + tid*8];             \
    gload_lds16(s0, dst);                                                    \
    gload_lds16(s0 + (size_t)64 * sld, dst + 4096);                          \
  } while (0)

#define LOADA(mih, b) { _Pragma("unroll") for (int q = 0; q < 4; ++q) {      \
    const u16* rp = &lds[(b)*32768 + (wm*128 + (mih)*64 + q*16 + lr) * 64];  \
    af[q][0] = *(const bf16x8*)(rp + agc0);                                  \
    af[q][1] = *(const bf16x8*)(rp + agc1); } }

#define LOADB(dst, nih, b) { _Pragma("unroll") for (int nq = 0; nq < 2; ++nq) { \
    const u16* rp = &lds[(b)*32768 + 16384 + (wn*64 + (nih)*32 + nq*16 + lr) * 64]; \
    dst[nq][0] = *(const bf16x8*)(rp + agc0);                                \
    dst[nq][1] = *(const bf16x8*)(rp + agc1); } }

#define MM(mih, nih, BF) {                                                   \
    __builtin_amdgcn_s_setprio(1);                                           \
    _Pragma("unroll") for (int kk = 0; kk < 2; ++kk)                         \
      _Pragma("unroll") for (int q = 0; q < 4; ++q)                          \
        _Pragma("unroll") for (int nq = 0; nq < 2; ++nq)                     \
          acc[(mih)*4+q][(nih)*2+nq] = __builtin_amdgcn_mfma_f32_16x16x32_bf16( \
              af[q][kk], BF[nq][kk], acc[(mih)*4+q][(nih)*2+nq], 0, 0, 0);   \
    __builtin_amdgcn_s_setprio(0); }

#define SYNC_MID  __builtin_amdgcn_s_barrier();                              \
                  asm volatile("s_waitcnt lgkmcnt(0)" ::: "memory");         \
                  __builtin_amdgcn_sched_barrier(0);
#define PHEND     __builtin_amdgcn_s_barrier();
#define PHEND_VM  asm volatile("s_waitcnt vmcnt(4)" ::: "memory");           \
                  __builtin_amdgcn_s_barrier();

  STAGE_H(0, 0, 0, 0); STAGE_H(0, 1, 0, 0);
  STAGE_H(1, 0, 0, 0); STAGE_H(1, 1, 0, 0);
  STAGE_H(1, 0, 1, 1); STAGE_H(1, 1, 1, 1);
  asm volatile("s_waitcnt vmcnt(4)" ::: "memory");
  __builtin_amdgcn_s_barrier();

  for (int i = 0; i < NI; ++i) {
    const int t0 = 2 * i;
    LOADA(0, 0); LOADB(bf0, 0, 0);
    STAGE_H(0, 0, 1, t0 + 1);
    SYNC_MID; MM(0, 0, bf0); PHEND;
    LOADB(bf1, 1, 0);
    STAGE_H(0, 1, 1, t0 + 1);
    SYNC_MID; MM(0, 1, bf1); PHEND;
    LOADA(1, 0);
    STAGE_H(1, 0, 0, t0 + 2);
    SYNC_MID; MM(1, 1, bf1); PHEND;
    STAGE_H(1, 1, 0, t0 + 2);
    SYNC_MID; MM(1, 0, bf0); PHEND_VM;
    LOADA(0, 1); LOADB(bf0, 0, 1);
    STAGE_H(0, 0, 0, t0 + 2);
    SYNC_MID; MM(0, 0, bf0); PHEND;
    LOADB(bf1, 1, 1);
    STAGE_H(0, 1, 0, t0 + 2);
    SYNC_MID; MM(0, 1, bf1); PHEND;
    LOADA(1, 1);
    STAGE_H(1, 0, 1, t0 + 3);
    SYNC_MID; MM(1, 1, bf1); PHEND;
    STAGE_H(1, 1, 1, t0 + 3);
    SYNC_MID; MM(1, 0, bf0); PHEND_VM;
  }
#undef STAGE_H
#undef LOADA
#undef LOADB
#undef MM

#pragma unroll
  for (int mi = 0; mi < 8; ++mi) {
    const int rowOff = (mi >> 2) * 64 + (mi & 3) * 16;
#pragma unroll
    for (int ni = 0; ni < 4; ++ni) {
      const int colOff = (ni >> 1) * 32 + (ni & 1) * 16;
#pragma unroll
      for (int j = 0; j < 4; ++j) {
        int row = bm*256 + wm*128 + rowOff + g*4 + j;
        int col = n_off + bn*256 + wn*64 + colOff + lr;
        epi_store<EPI>((size_t)row * ldc + col, acc[mi][ni][j], Cf, Cb, resf, resb, other);
      }
    }
  }
}

// ------- 128x256 8-phase bf16 MFMA GEMM (fills 256 CUs for N=2048 outputs) ------------
// 8 waves 2Mx4N, per-wave 64x64. BK=64, 2 tiles/iter, vmcnt(6)@ph4, vmcnt(4)@ph8.
// LDS 96KB = 2 bufs x (A 128x64 | B0 128x64 | B1 128x64). Same granule swizzle.
template<int EPI>
__global__ __launch_bounds__(512) void gemm128_kernel(
    const u16* __restrict__ A, const u16* __restrict__ BT,
    int K, int lda, int ldb, int ldc, int n_off,
    float* Cf, u16* Cb,
    const float* __restrict__ resf, const u16* __restrict__ resb, const u16* other)
{
  __shared__ u16 lds[49152];
  const int tid = threadIdx.x;
  const int w = tid >> 6, lane = tid & 63;
  const int g = lane >> 4, lr = lane & 15;
  const int wm = w >> 2, wn = w & 3;
  const int bn = blockIdx.x, bm = blockIdx.y;
  const int NT = K >> 6;
  const int NI = NT >> 1;

  const int srow = tid >> 3;
  const int sg   = (tid & 7) ^ (srow & 7);
  const u16* Asrc = A  + (size_t)(bm * 128) * lda;
  const u16* Bsrc = BT + (size_t)(bn * 256) * ldb;

  const int agc0 = ((0 + g) ^ (lr & 7)) * 8;
  const int agc1 = ((4 + g) ^ (lr & 7)) * 8;

  f32x4 acc[4][4];
#pragma unroll
  for (int i = 0; i < 4; ++i)
#pragma unroll
    for (int j = 0; j < 4; ++j) acc[i][j] = (f32x4){0.f, 0.f, 0.f, 0.f};
  bf16x8 af[2][2], bf0[2][2], bf1[2][2];

#define STAGE_A(b, T) do {                                                   \
    int tc = ((T) < NT) ? (T) : (NT - 1);                                    \
    const u16* s0 = Asrc + (size_t)srow * lda + tc*64 + sg*8;                \
    u16* dst = &lds[(b)*24576 + tid*8];                                      \
    gload_lds16(s0, dst);                                                    \
    gload_lds16(s0 + (size_t)64 * lda, dst + 4096);                          \
  } while (0)

#define STAGE_BH(h, b, T) do {                                               \
    int tc = ((T) < NT) ? (T) : (NT - 1);                                    \
    const u16* s0 = Bsrc + (size_t)((h)*128 + srow) * ldb + tc*64 + sg*8;    \
    u16* dst = &lds[(b)*24576 + 8192 + (h)*8192 + tid*8];                    \
    gload_lds16(s0, dst);                                                    \
    gload_lds16(s0 + (size_t)64 * ldb, dst + 4096);                         \
  } while (0)

#define LOADA(mih, b) { _Pragma("unroll") for (int q = 0; q < 2; ++q) {      \
    const u16* rp = &lds[(b)*24576 + (wm*64 + (mih)*32 + q*16 + lr) * 64];   \
    af[q][0] = *(const bf16x8*)(rp + agc0);                                  \
    af[q][1] = *(const bf16x8*)(rp + agc1); } }

#define LOADB(dst, nih, b) { _Pragma("unroll") for (int nq = 0; nq < 2; ++nq) { \
    const u16* rp = &lds[(b)*24576 + 8192 + (wn*64 + (nih)*32 + nq*16 + lr) * 64]; \
    dst[nq][0] = *(const bf16x8*)(rp + agc0);                                \
    dst[nq][1] = *(const bf16x8*)(rp + agc1); } }

#define MM(mih, nih, BF) {                                                   \
    __builtin_amdgcn_s_setprio(1);                                           \
    _Pragma("unroll") for (int kk = 0; kk < 2; ++kk)                         \
      _Pragma("unroll") for (int q = 0; q < 2; ++q)                          \
        _Pragma("unroll") for (int nq = 0; nq < 2; ++nq)                     \
          acc[(mih)*2+q][(nih)*2+nq] = __builtin_amdgcn_mfma_f32_16x16x32_bf16( \
              af[q][kk], BF[nq][kk], acc[(mih)*2+q][(nih)*2+nq], 0, 0, 0);   \
    __builtin_amdgcn_s_setprio(0); }

  // prologue: buf0 <- tile0 full; buf1 <- tile1 B
  STAGE_A(0, 0); STAGE_BH(0, 0, 0); STAGE_BH(1, 0, 0);
  STAGE_BH(0, 1, 1); STAGE_BH(1, 1, 1);
  asm volatile("s_waitcnt vmcnt(4)" ::: "memory");
  __builtin_amdgcn_s_barrier();

  for (int i = 0; i < NI; ++i) {
    const int t0 = 2 * i;
    // ph1
    LOADA(0, 0); LOADB(bf0, 0, 0);
    STAGE_A(1, t0 + 1);
    SYNC_MID; MM(0, 0, bf0); PHEND;
    // ph2
    LOADB(bf1, 1, 0);
    STAGE_BH(0, 0, t0 + 2);
    SYNC_MID; MM(0, 1, bf1); PHEND;
    // ph3
    LOADA(1, 0);
    STAGE_BH(1, 0, t0 + 2);
    SYNC_MID; MM(1, 1, bf1); PHEND;
    // ph4
    STAGE_A(0, t0 + 2);
    SYNC_MID; MM(1, 0, bf0);
    asm volatile("s_waitcnt vmcnt(6)" ::: "memory");
    __builtin_amdgcn_s_barrier();
    // ph5
    LOADA(0, 1); LOADB(bf0, 0, 1);
    SYNC_MID; MM(0, 0, bf0); PHEND;
    // ph6
    LOADB(bf1, 1, 1);
    STAGE_BH(0, 1, t0 + 3);
    SYNC_MID; MM(0, 1, bf1); PHEND;
    // ph7
    LOADA(1, 1);
    STAGE_BH(1, 1, t0 + 3);
    SYNC_MID; MM(1, 1, bf1); PHEND;
    // ph8
    SYNC_MID; MM(1, 0, bf0);
    asm volatile("s_waitcnt vmcnt(4)" ::: "memory");
    __builtin_amdgcn_s_barrier();
  }
#undef STAGE_A
#undef STAGE_BH
#undef LOADA
#undef LOADB
#undef MM
#undef SYNC_MID
#undef PHEND
#undef PHEND_VM

#pragma unroll
  for (int mi = 0; mi < 4; ++mi) {
    const int rowOff = (mi >> 1) * 32 + (mi & 1) * 16;
#pragma unroll
    for (int ni = 0; ni < 4; ++ni) {
      const int colOff = (ni >> 1) * 32 + (ni & 1) * 16;
#pragma unroll
      for (int j = 0; j < 4; ++j) {
        int row = bm*128 + wm*64 + rowOff + g*4 + j;
        int col = n_off + bn*256 + wn*64 + colOff + lr;
        epi_store<EPI>((size_t)row * ldc + col, acc[mi][ni][j], Cf, Cb, resf, resb, other);
      }
    }
  }
}

// ------- RoPE + relayout ------------------------------------------------------------
__global__ __launch_bounds__(256) void rope_kernel(
    const u16* __restrict__ qkv, const float* __restrict__ ct, const float* __restrict__ st,
    u16* __restrict__ Q, u16* __restrict__ Kt, u16* __restrict__ VT)
{
  const int tok = blockIdx.x;
  const int b = tok >> 11, s = tok & (S_LEN - 1);
  const int w = threadIdx.x >> 6, lane = threadIdx.x & 63;
  const size_t base = (size_t)tok * QKV_N;
  for (int slot = w; slot < 48; slot += 4) {
    int col = (slot < 32) ? slot * 64 : (slot < 40 ? 2048 + (slot - 32) * 64 : 2560 + (slot - 40) * 64);
    float v = b2f(qkv[base + col + lane]);
    if (slot < 40) {
      int i = lane & 31;
      float c = ct[s * 32 + i], sn = st[s * 32 + i];
      float p = b2f(qkv[base + col + (lane ^ 32)]);
      v = (lane < 32) ? (v * c - p * sn) : (v * c + p * sn);
    }
    u16 ob = f2b(v);
    if (slot < 32)      Q [((size_t)(b * 32 + slot)      * S_LEN + s) * 64 + lane] = ob;
    else if (slot < 40) Kt[((size_t)(b * 8 + slot - 32)  * S_LEN + s) * 64 + lane] = ob;
    else                VT[((size_t)(b * 8 + slot - 40)  * 64 + lane) * S_LEN + s] = ob;
  }
}

// ------- causal GQA flash attention with KV-split for heavy q-blocks ------------------
// split==-1: full range, write ctx. split 0/1: half KV range, write unnormalized
// partials (po bf16, pml float2) for combine.
#define ASCALE 0.1803368801111204f   /* 0.125 * log2(e) */
__global__ __launch_bounds__(256, 3) void attn_kernel(
    const u16* __restrict__ Q, const u16* __restrict__ Kt,
    const u16* __restrict__ VT, u16* __restrict__ ctx,
    u16* __restrict__ po, float2* __restrict__ pml)
{
  const int bh  = blockIdx.x;
  const int y   = blockIdx.y;            // 0..23; heavy parts first
  int qb, split;
  if (y < 16) { qb = 15 - (y >> 1); split = y & 1; }
  else        { qb = 23 - y;        split = -1;    }
  const int wid = threadIdx.x >> 6;
  const int lane = threadIdx.x & 63;
  const int b = bh >> 5, h = bh & 31;
  const int kvh = (b << 3) + (h >> 2);
  const int q0 = qb * 128 + wid * 32;
  const int cq = lane & 31;
  const int hi = lane >> 5;

  const u16* Qb = Q  + ((size_t)bh * S_LEN + q0) * 64;
  const u16* Kb = Kt + (size_t)kvh * S_LEN * 64;
  const u16* Vb = VT + (size_t)kvh * 64 * S_LEN;

  bf16x8 qf[4];
#pragma unroll
  for (int t = 0; t < 4; ++t)
    qf[t] = *reinterpret_cast<const bf16x8*>(&Qb[cq * 64 + t * 16 + hi * 8]);

  f32x16 o0 = {}, o1 = {};
  float m = -1e30f, l = 0.f;

  __shared__ float xch[4][32];

  const int nt = qb * 4 + wid + 1;
  const int ts = (split == 1) ? (nt >> 1) : 0;
  const int te = (split == 0) ? (nt >> 1) : nt;

  for (int t = ts; t < te; ++t) {
    const int k0 = t << 5;
    bf16x8 kf[4], vf[4];
#pragma unroll
    for (int tt = 0; tt < 4; ++tt)
      kf[tt] = *reinterpret_cast<const bf16x8*>(&Kb[(size_t)(k0 + cq) * 64 + tt * 16 + hi * 8]);
#pragma unroll
    for (int kh = 0; kh < 2; ++kh)
#pragma unroll
      for (int dh = 0; dh < 2; ++dh)
        vf[kh * 2 + dh] = *reinterpret_cast<const bf16x8*>(&Vb[(size_t)(dh * 32 + cq) * S_LEN + k0 + kh * 16 + hi * 8]);

    f32x16 sA = {}, sB = {};
    sA = __builtin_amdgcn_mfma_f32_32x32x16_bf16(kf[0], qf[0], sA, 0, 0, 0);
    sB = __builtin_amdgcn_mfma_f32_32x32x16_bf16(kf[1], qf[1], sB, 0, 0, 0);
    sA = __builtin_amdgcn_mfma_f32_32x32x16_bf16(kf[2], qf[2], sA, 0, 0, 0);
    sB = __builtin_amdgcn_mfma_f32_32x32x16_bf16(kf[3], qf[3], sB, 0, 0, 0);

    float p[16];
#pragma unroll
    for (int r = 0; r < 16; ++r) p[r] = (sA[r] + sB[r]) * ASCALE;
    if (t == nt - 1) {
#pragma unroll
      for (int r = 0; r < 16; ++r) {
        int kk = (r & 3) + 8 * (r >> 2) + 4 * hi;
        if (kk > cq) p[r] = -1e30f;
      }
    }
    float tmax = p[0];
#pragma unroll
    for (int r = 1; r < 16; ++r) tmax = fmaxf(tmax, p[r]);
    tmax = fmaxf(tmax, __shfl_xor(tmax, 32));

    if (!__all(tmax <= m + 8.0f)) {
      float mn = fmaxf(m, tmax);
      float corr = exp2f(m - mn);
      m = mn;
      l *= corr;
      if (hi == 0) xch[wid][cq] = corr;
      asm volatile("s_waitcnt lgkmcnt(0)" ::: "memory");
      __builtin_amdgcn_sched_barrier(0);
      float4 c0 = *reinterpret_cast<const float4*>(&xch[wid][4 * hi + 0]);
      float4 c1 = *reinterpret_cast<const float4*>(&xch[wid][4 * hi + 8]);
      float4 c2 = *reinterpret_cast<const float4*>(&xch[wid][4 * hi + 16]);
      float4 c3 = *reinterpret_cast<const float4*>(&xch[wid][4 * hi + 24]);
      float ca[16] = {c0.x,c0.y,c0.z,c0.w, c1.x,c1.y,c1.z,c1.w,
                      c2.x,c2.y,c2.z,c2.w, c3.x,c3.y,c3.z,c3.w};
#pragma unroll
      for (int r = 0; r < 16; ++r) { o0[r] *= ca[r]; o1[r] *= ca[r]; }
    }

    float tsum = 0.f;
#pragma unroll
    for (int r = 0; r < 16; ++r) { p[r] = exp2f(p[r] - m); tsum += p[r]; }
    tsum += __shfl_xor(tsum, 32);
    l += tsum;

    uint32_t wds[8], pw[8];
#pragma unroll
    for (int j = 0; j < 8; ++j) {
      uint32_t wv;
      asm("v_cvt_pk_bf16_f32 %0, %1, %2" : "=v"(wv) : "v"(p[2*j]), "v"(p[2*j+1]));
      wds[j] = wv;
    }
#pragma unroll
    for (int j = 0; j < 8; ++j) pw[j] = __shfl_xor(wds[j], 32);
    union { uint32_t u[4]; bf16x8 v; } pa0, pa1;
    pa0.u[0] = hi ? pw[2]  : wds[0];
    pa0.u[1] = hi ? pw[3]  : wds[1];
    pa0.u[2] = hi ? wds[2] : pw[0];
    pa0.u[3] = hi ? wds[3] : pw[1];
    pa1.u[0] = hi ? pw[6]  : wds[4];
    pa1.u[1] = hi ? pw[7]  : wds[5];
    pa1.u[2] = hi ? wds[6] : pw[4];
    pa1.u[3] = hi ? wds[7] : pw[5];

    o0 = __builtin_amdgcn_mfma_f32_32x32x16_bf16(pa0.v, vf[0], o0, 0, 0, 0);
    o0 = __builtin_amdgcn_mfma_f32_32x32x16_bf16(pa1.v, vf[2], o0, 0, 0, 0);
    o1 = __builtin_amdgcn_mfma_f32_32x32x16_bf16(pa0.v, vf[1], o1, 0, 0, 0);
    o1 = __builtin_amdgcn_mfma_f32_32x32x16_bf16(pa1.v, vf[3], o1, 0, 0, 0);
  }

  if (split < 0) {
    float linv = 1.0f / l;
    if (hi == 0) xch[wid][cq] = linv;
    asm volatile("s_waitcnt lgkmcnt(0)" ::: "memory");
    __builtin_amdgcn_sched_barrier(0);
    float4 n0 = *reinterpret_cast<const float4*>(&xch[wid][4 * hi + 0]);
    float4 n1 = *reinterpret_cast<const float4*>(&xch[wid][4 * hi + 8]);
    float4 n2 = *reinterpret_cast<const float4*>(&xch[wid][4 * hi + 16]);
    float4 n3 = *reinterpret_cast<const float4*>(&xch[wid][4 * hi + 24]);
    float na[16] = {n0.x,n0.y,n0.z,n0.w, n1.x,n1.y,n1.z,n1.w,
                    n2.x,n2.y,n2.z,n2.w, n3.x,n3.y,n3.z,n3.w};
#pragma unroll
    for (int r = 0; r < 16; ++r) {
      int row = (r & 3) + 8 * (r >> 2) + 4 * hi;
      size_t base = (size_t)(b * S_LEN + q0 + row) * D_MODEL + h * 64;
      ctx[base + cq]      = f2b(o0[r] * na[r]);
      ctx[base + 32 + cq] = f2b(o1[r] * na[r]);
    }
  } else {
    const int qr0 = q0 - 1024;
    if (hi == 0) {
      float2 v; v.x = m; v.y = l;
      pml[((size_t)(split * 64 + bh)) * 1024 + qr0 + cq] = v;
    }
#pragma unroll
    for (int r = 0; r < 16; ++r) {
      int row = (r & 3) + 8 * (r >> 2) + 4 * hi;
      size_t base = (((size_t)(split * 64 + bh)) * 1024 + qr0 + row) * 64;
      po[base + cq]      = f2b(o0[r]);
      po[base + 32 + cq] = f2b(o1[r]);
    }
  }
}

// ------- combine the two KV-split partials for q rows 1024..2047 ----------------------
__global__ __launch_bounds__(256) void attn_combine(
    const u16* __restrict__ po, const float2* __restrict__ pml, u16* __restrict__ ctx)
{
  const int bh = blockIdx.x;
  const int b = bh >> 5, h = bh & 31;
  const int d = threadIdx.x & 63;
  for (int rr = threadIdx.x >> 6; rr < 64; rr += 4) {
    const int qr = blockIdx.y * 64 + rr;
    float2 ml1 = pml[(size_t)bh * 1024 + qr];
    float2 ml2 = pml[(size_t)(64 + bh) * 1024 + qr];
    float mm = fmaxf(ml1.x, ml2.x);
    float w1 = exp2f(ml1.x - mm), w2 = exp2f(ml2.x - mm);
    float denom = ml1.y * w1 + ml2.y * w2;
    float v1 = b2f(po[((size_t)bh * 1024 + qr) * 64 + d]);
    float v2 = b2f(po[((size_t)(64 + bh) * 1024 + qr) * 64 + d]);
    ctx[((size_t)(b * S_LEN) + 1024 + qr) * D_MODEL + h * 64 + d] = f2b((v1 * w1 + v2 * w2) / denom);
  }
}

// ---------------------------------- host ---------------------------------------------
extern "C" void kernel_launch(void* const* d_in, const int* in_sizes, int n_in,
                              void* d_out, int out_size, void* d_ws, size_t ws_size,
                              hipStream_t stream)
{
  const float* x     = (const float*)d_in[0];
  const float* wn1   = (const float*)d_in[1];
  const float* wqkv  = (const float*)d_in[2];
  const float* wout  = (const float*)d_in[3];
  const float* wn2   = (const float*)d_in[4];
  const float* wgate = (const float*)d_in[5];
  const float* wup   = (const float*)d_in[6];
  const float* wdown = (const float*)d_in[7];
  float* out = (float*)d_out;
  char* ws = (char*)d_ws;

  float* cosT = (float*)(ws + 0);
  float* sinT = (float*)(ws + 262144);
  u16*   wT   = (u16*)  (ws + 524288);
  u16*   hB   = (u16*)  (ws + 17301504);
  u16*   x1b  = (u16*)  (ws + 34078720);
  char*  S    = ws + 50855936;
  u16*   qkvB = (u16*)(S + 0);
  u16*   poB  = (u16*)(S + 0);               // partials alias dead qkvB (16.8MB + 1MB)
  float2* pmlB= (float2*)(S + 16777216);
  u16*   qB   = (u16*)(S + 25165824);
  u16*   kB   = (u16*)(S + 41943040);
  u16*   vtB  = (u16*)(S + 46137344);
  u16*   ctxB = (u16*)(S + 50331648);
  u16*   gsB  = (u16*)(S + 0);

  sincos_kernel<<<dim3(256), 256, 0, stream>>>(cosT, sinT);
  rmsnorm_kernel<false><<<dim3(NTOK), 256, 0, stream>>>(x, wn1, hB);

  // qkv = h @ w_qkv  (128x256 tiles -> 384 blocks)
  wconv_kernel<<<dim3((2048/64)*(3072/64)), 256, 0, stream>>>(wqkv, wT, 3072, 2048, 3072, 0, 0);
  gemm128_kernel<4><<<dim3(QKV_N/256, NTOK/128), 512, 0, stream>>>(hB, wT, 2048, 2048, 2048, 3072, 0, nullptr, qkvB, nullptr, nullptr, nullptr);
  rope_kernel<<<dim3(NTOK), 256, 0, stream>>>(qkvB, cosT, sinT, qB, kB, vtB);
  attn_kernel<<<dim3(64, 24), 256, 0, stream>>>(qB, kB, vtB, ctxB, poB, pmlB);
  attn_combine<<<dim3(64, 16), 256, 0, stream>>>(poB, pmlB, ctxB);

  // x1 = x + ctx @ w_out  (256 blocks)
  wconv_kernel<<<dim3((2048/64)*(2048/64)), 256, 0, stream>>>(wout, wT, 2048, 2048, 2048, 0, 0);
  gemm128_kernel<6><<<dim3(D_MODEL/256, NTOK/128), 512, 0, stream>>>(ctxB, wT, 2048, 2048, 2048, 2048, 0, nullptr, x1b, x, nullptr, nullptr);

  rmsnorm_kernel<true><<<dim3(NTOK), 256, 0, stream>>>(x1b, wn2, hB);

  for (int c = 0; c < 2; ++c) {
    wconv_kernel<<<dim3((2048/64)*(4096/64)), 256, 0, stream>>>(wgate, wT, 8192, 2048, 4096, 0, c*4096);
    gemm8p_kernel<2><<<dim3(4096/256, NTOK/256), 512, 0, stream>>>(hB, wT, 2048, 2048, 2048, 8192, c*4096, nullptr, gsB, nullptr, nullptr, nullptr);
  }
  for (int c = 0; c < 2; ++c) {
    wconv_kernel<<<dim3((2048/64)*(4096/64)), 256, 0, stream>>>(wup, wT, 8192, 2048, 4096, 0, c*4096);
    gemm8p_kernel<3><<<dim3(4096/256, NTOK/256), 512, 0, stream>>>(hB, wT, 2048, 2048, 2048, 8192, c*4096, nullptr, gsB, nullptr, nullptr, gsB);
  }
  // out = x1 + gs @ w_down, two K-chunks (256 blocks each)
  wconv_kernel<<<dim3((4096/64)*(2048/64)), 256, 0, stream>>>(wdown, wT, 2048, 4096, 2048, 0, 0);
  gemm128_kernel<7><<<dim3(D_MODEL/256, NTOK/128), 512, 0, stream>>>(gsB, wT, 4096, 8192, 4096, 2048, 0, out, nullptr, nullptr, x1b, nullptr);
  wconv_kernel<<<dim3((4096/64)*(2048/64)), 256, 0, stream>>>(wdown, wT, 2048, 4096, 2048, 4096, 0);
  gemm128_kernel<5><<<dim3(D_MODEL/256, NTOK/128), 512, 0, stream>>>(gsB + 4096, wT, 4096, 8192, 4096, 2048, 0, out, nullptr, nullptr, nullptr, nullptr);
}

// Round 7
// 811.783 us; speedup vs baseline: 1.4257x; 1.0181x over previous
//
#include <hip/hip_runtime.h>
#include <stdint.h>

#define D_MODEL 2048
#define S_LEN   2048
#define NTOK    4096
#define QKV_N   3072
#define DFF     8192

typedef float  f32x4   __attribute__((ext_vector_type(4)));
typedef float  f32x16  __attribute__((ext_vector_type(16)));
typedef __bf16 bf16x8  __attribute__((ext_vector_type(8)));
typedef unsigned short u16;
typedef unsigned short u16x8 __attribute__((ext_vector_type(8)));

__device__ __forceinline__ float b2f(u16 u){ union{float f; uint32_t i;} v; v.i = ((uint32_t)u) << 16; return v.f; }
__device__ __forceinline__ u16 f2b(float f){
  union{float f; uint32_t i;} v; v.f = f;
  uint32_t r = v.i + 0x7FFFu + ((v.i >> 16) & 1u);
  return (u16)(r >> 16);
}

__device__ __forceinline__ void gload_lds16(const void* gsrc, void* ldst){
  __builtin_amdgcn_global_load_lds(
      (const __attribute__((address_space(1))) void*)gsrc,
      (__attribute__((address_space(3))) void*)ldst,
      16, 0, 0);
}

// ------- weight convert+transpose (sub-block): W[k0g+.., n0g+..] f32 -> WT[Nt][Kt] bf16
__global__ __launch_bounds__(256) void wconv_kernel(const float* __restrict__ W, u16* __restrict__ WT,
                                                    int Nfull, int Kt, int Nt, int k0g, int n0g)
{
  __shared__ float tile[64][65];
  const int nTn = Nt >> 6;
  const int tk = blockIdx.x / nTn, tn = blockIdx.x % nTn;
  const int k0 = tk << 6, n0 = tn << 6;
  const int t  = threadIdx.x;
  const int c4 = (t & 15) << 2;
  const int r  = t >> 4;
#pragma unroll
  for (int i = 0; i < 4; ++i) {
    float4 v = *reinterpret_cast<const float4*>(&W[(size_t)(k0g + k0 + r + i*16) * Nfull + n0g + n0 + c4]);
    tile[r + i*16][c4+0] = v.x; tile[r + i*16][c4+1] = v.y;
    tile[r + i*16][c4+2] = v.z; tile[r + i*16][c4+3] = v.w;
  }
  __syncthreads();
#pragma unroll
  for (int i = 0; i < 4; ++i) {
    int n = r + i*16;
    ushort4 ov;
    ov.x = f2b(tile[c4+0][n]); ov.y = f2b(tile[c4+1][n]);
    ov.z = f2b(tile[c4+2][n]); ov.w = f2b(tile[c4+3][n]);
    *reinterpret_cast<ushort4*>(&WT[(size_t)(n0 + n) * Kt + k0 + c4]) = ov;
  }
}

// ------- rope cos/sin table --------------------------------------------------------
__global__ void sincos_kernel(float* __restrict__ ct, float* __restrict__ st)
{
  int idx = blockIdx.x * 256 + threadIdx.x;
  if (idx >= S_LEN * 32) return;
  int p = idx >> 5, i = idx & 31;
  double freq = pow(10000.0, -((double)(2*i)) / 64.0);
  double ang  = (double)p * freq;
  ct[idx] = (float)cos(ang);
  st[idx] = (float)sin(ang);
}

// ------- RMSNorm -------------------------------------------------------------------
template<bool BF16IN>
__global__ __launch_bounds__(256) void rmsnorm_kernel(const void* __restrict__ xin, const float* __restrict__ w, u16* __restrict__ out)
{
  const int row = blockIdx.x;
  const int t = threadIdx.x;
  float v[8];
  if (BF16IN) {
    const u16* xr = ((const u16*)xin) + (size_t)row * D_MODEL;
    u16x8 a = *reinterpret_cast<const u16x8*>(&xr[t*8]);
#pragma unroll
    for (int j = 0; j < 8; ++j) v[j] = b2f(a[j]);
  } else {
    const float* xr = ((const float*)xin) + (size_t)row * D_MODEL;
    float4 a = *reinterpret_cast<const float4*>(&xr[t*8]);
    float4 c = *reinterpret_cast<const float4*>(&xr[t*8+4]);
    v[0]=a.x; v[1]=a.y; v[2]=a.z; v[3]=a.w; v[4]=c.x; v[5]=c.y; v[6]=c.z; v[7]=c.w;
  }
  float ss = 0.f;
#pragma unroll
  for (int j = 0; j < 8; ++j) ss += v[j]*v[j];
#pragma unroll
  for (int d = 1; d < 64; d <<= 1) ss += __shfl_xor(ss, d);
  __shared__ float red[4];
  if ((t & 63) == 0) red[t >> 6] = ss;
  __syncthreads();
  ss = red[0] + red[1] + red[2] + red[3];
  const float sc = rsqrtf(ss * (1.0f / (float)D_MODEL) + 1e-5f);
  float4 w0 = *reinterpret_cast<const float4*>(&w[t*8]);
  float4 w1 = *reinterpret_cast<const float4*>(&w[t*8+4]);
  u16x8 o;
  o[0]=f2b(v[0]*sc*w0.x); o[1]=f2b(v[1]*sc*w0.y); o[2]=f2b(v[2]*sc*w0.z); o[3]=f2b(v[3]*sc*w0.w);
  o[4]=f2b(v[4]*sc*w1.x); o[5]=f2b(v[5]*sc*w1.y); o[6]=f2b(v[6]*sc*w1.z); o[7]=f2b(v[7]*sc*w1.w);
  *reinterpret_cast<u16x8*>(&out[(size_t)row * D_MODEL + t*8]) = o;
}

// ------- shared GEMM epilogue dispatch ------------------------------------------------
// EPI: 2 silu->Cb; 3 Cb=v*other; 4 Cb=v; 5 Cf+=v; 6 Cb=f2b(v+resf); 7 Cf=v+b2f(resb)
template<int EPI>
__device__ __forceinline__ void epi_store(size_t idx, float v, float* Cf, u16* Cb,
                                          const float* resf, const u16* resb, const u16* other)
{
  if (EPI == 2)      Cb[idx] = f2b(v / (1.0f + __expf(-v)));
  else if (EPI == 3) Cb[idx] = f2b(v * b2f(other[idx]));
  else if (EPI == 4) Cb[idx] = f2b(v);
  else if (EPI == 5) Cf[idx] += v;
  else if (EPI == 6) Cb[idx] = f2b(v + resf[idx]);
  else if (EPI == 7) Cf[idx] = v + b2f(resb[idx]);
}

// ------- 256x256 8-phase bf16 MFMA GEMM (m201 template): A[M][lda] x BT[N][ldb] -------
template<int EPI>
__global__ __launch_bounds__(512, 2) void gemm8p_kernel(
    const u16* __restrict__ A, const u16* __restrict__ BT,
    int K, int lda, int ldb, int ldc, int n_off,
    float* Cf, u16* Cb,
    const float* __restrict__ resf, const u16* __restrict__ resb, const u16* other)
{
  __shared__ u16 lds[65536];
  const int tid = threadIdx.x;
  const int w = tid >> 6, lane = tid & 63;
  const int g = lane >> 4, lr = lane & 15;
  const int wm = w >> 2, wn = w & 3;
  const int bn = blockIdx.x, bm = blockIdx.y;
  const int NT = K >> 6;
  const int NI = NT >> 1;

  const int srow = tid >> 3;
  const int sg   = (tid & 7) ^ (srow & 7);
  const u16* Asrc = A  + (size_t)(bm * 256) * lda;
  const u16* Bsrc = BT + (size_t)(bn * 256) * ldb;

  const int agc0 = ((0 + g) ^ (lr & 7)) * 8;
  const int agc1 = ((4 + g) ^ (lr & 7)) * 8;

  f32x4 acc[8][4];
#pragma unroll
  for (int i = 0; i < 8; ++i)
#pragma unroll
    for (int j = 0; j < 4; ++j) acc[i][j] = (f32x4){0.f, 0.f, 0.f, 0.f};
  bf16x8 af[4][2], bf0[2][2], bf1[2][2];

#define STAGE_H(isB, h, b, T) do {                                           \
    int tc = ((T) < NT) ? (T) : (NT - 1);                                    \
    const u16* sb = (isB) ? Bsrc : Asrc;                                     \
    const int  sld = (isB) ? ldb : lda;                                      \
    const u16* s0 = sb + (size_t)((h)*128 + srow) * sld + tc*64 + sg*8;      \
    u16* dst = &lds[(b)*32768 + (isB)*16384 + (h)*8192 + tid*8];             \
    gload_lds16(s0, dst);                                                    \
    gload_lds16(s0 + (size_t)64 * sld, dst + 4096);                          \
  } while (0)

#define LOADA(mih, b) { _Pragma("unroll") for (int q = 0; q < 4; ++q) {      \
    const u16* rp = &lds[(b)*32768 + (wm*128 + (mih)*64 + q*16 + lr) * 64];  \
    af[q][0] = *(const bf16x8*)(rp + agc0);                                  \
    af[q][1] = *(const bf16x8*)(rp + agc1); } }

#define LOADB(dst, nih, b) { _Pragma("unroll") for (int nq = 0; nq < 2; ++nq) { \
    const u16* rp = &lds[(b)*32768 + 16384 + (wn*64 + (nih)*32 + nq*16 + lr) * 64]; \
    dst[nq][0] = *(const bf16x8*)(rp + agc0);                                \
    dst[nq][1] = *(const bf16x8*)(rp + agc1); } }

#define MM(mih, nih, BF) {                                                   \
    __builtin_amdgcn_s_setprio(1);                                           \
    _Pragma("unroll") for (int kk = 0; kk < 2; ++kk)                         \
      _Pragma("unroll") for (int q = 0; q < 4; ++q)                          \
        _Pragma("unroll") for (int nq = 0; nq < 2; ++nq)                     \
          acc[(mih)*4+q][(nih)*2+nq] = __builtin_amdgcn_mfma_f32_16x16x32_bf16( \
              af[q][kk], BF[nq][kk], acc[(mih)*4+q][(nih)*2+nq], 0, 0, 0);   \
    __builtin_amdgcn_s_setprio(0); }

#define SYNC_MID  __builtin_amdgcn_s_barrier();                              \
                  asm volatile("s_waitcnt lgkmcnt(0)" ::: "memory");         \
                  __builtin_amdgcn_sched_barrier(0);
#define PHEND     __builtin_amdgcn_s_barrier();
#define PHEND_VM  asm volatile("s_waitcnt vmcnt(4)" ::: "memory");           \
                  __builtin_amdgcn_s_barrier();

  STAGE_H(0, 0, 0, 0); STAGE_H(0, 1, 0, 0);
  STAGE_H(1, 0, 0, 0); STAGE_H(1, 1, 0, 0);
  STAGE_H(1, 0, 1, 1); STAGE_H(1, 1, 1, 1);
  asm volatile("s_waitcnt vmcnt(4)" ::: "memory");
  __builtin_amdgcn_s_barrier();

  for (int i = 0; i < NI; ++i) {
    const int t0 = 2 * i;
    LOADA(0, 0); LOADB(bf0, 0, 0);
    STAGE_H(0, 0, 1, t0 + 1);
    SYNC_MID; MM(0, 0, bf0); PHEND;
    LOADB(bf1, 1, 0);
    STAGE_H(0, 1, 1, t0 + 1);
    SYNC_MID; MM(0, 1, bf1); PHEND;
    LOADA(1, 0);
    STAGE_H(1, 0, 0, t0 + 2);
    SYNC_MID; MM(1, 1, bf1); PHEND;
    STAGE_H(1, 1, 0, t0 + 2);
    SYNC_MID; MM(1, 0, bf0); PHEND_VM;
    LOADA(0, 1); LOADB(bf0, 0, 1);
    STAGE_H(0, 0, 0, t0 + 2);
    SYNC_MID; MM(0, 0, bf0); PHEND;
    LOADB(bf1, 1, 1);
    STAGE_H(0, 1, 0, t0 + 2);
    SYNC_MID; MM(0, 1, bf1); PHEND;
    LOADA(1, 1);
    STAGE_H(1, 0, 1, t0 + 3);
    SYNC_MID; MM(1, 1, bf1); PHEND;
    STAGE_H(1, 1, 1, t0 + 3);
    SYNC_MID; MM(1, 0, bf0); PHEND_VM;
  }
#undef STAGE_H
#undef LOADA
#undef LOADB
#undef MM

#pragma unroll
  for (int mi = 0; mi < 8; ++mi) {
    const int rowOff = (mi >> 2) * 64 + (mi & 3) * 16;
#pragma unroll
    for (int ni = 0; ni < 4; ++ni) {
      const int colOff = (ni >> 1) * 32 + (ni & 1) * 16;
#pragma unroll
      for (int j = 0; j < 4; ++j) {
        int row = bm*256 + wm*128 + rowOff + g*4 + j;
        int col = n_off + bn*256 + wn*64 + colOff + lr;
        epi_store<EPI>((size_t)row * ldc + col, acc[mi][ni][j], Cf, Cb, resf, resb, other);
      }
    }
  }
}

// ------- 128x256 8-phase bf16 MFMA GEMM (fills 256 CUs for N=2048 outputs) ------------
template<int EPI>
__global__ __launch_bounds__(512) void gemm128_kernel(
    const u16* __restrict__ A, const u16* __restrict__ BT,
    int K, int lda, int ldb, int ldc, int n_off,
    float* Cf, u16* Cb,
    const float* __restrict__ resf, const u16* __restrict__ resb, const u16* other)
{
  __shared__ u16 lds[49152];
  const int tid = threadIdx.x;
  const int w = tid >> 6, lane = tid & 63;
  const int g = lane >> 4, lr = lane & 15;
  const int wm = w >> 2, wn = w & 3;
  const int bn = blockIdx.x, bm = blockIdx.y;
  const int NT = K >> 6;
  const int NI = NT >> 1;

  const int srow = tid >> 3;
  const int sg   = (tid & 7) ^ (srow & 7);
  const u16* Asrc = A  + (size_t)(bm * 128) * lda;
  const u16* Bsrc = BT + (size_t)(bn * 256) * ldb;

  const int agc0 = ((0 + g) ^ (lr & 7)) * 8;
  const int agc1 = ((4 + g) ^ (lr & 7)) * 8;

  f32x4 acc[4][4];
#pragma unroll
  for (int i = 0; i < 4; ++i)
#pragma unroll
    for (int j = 0; j < 4; ++j) acc[i][j] = (f32x4){0.f, 0.f, 0.f, 0.f};
  bf16x8 af[2][2], bf0[2][2], bf1[2][2];

#define STAGE_A(b, T) do {                                                   \
    int tc = ((T) < NT) ? (T) : (NT - 1);                                    \
    const u16* s0 = Asrc + (size_t)srow * lda + tc*64 + sg*8;                \
    u16* dst = &lds[(b)*24576 + tid*8];                                      \
    gload_lds16(s0, dst);                                                    \
    gload_lds16(s0 + (size_t)64 * lda, dst + 4096);                          \
  } while (0)

#define STAGE_BH(h, b, T) do {                                               \
    int tc = ((T) < NT) ? (T) : (NT - 1);                                    \
    const u16* s0 = Bsrc + (size_t)((h)*128 + srow) * ldb + tc*64 + sg*8;    \
    u16* dst = &lds[(b)*24576 + 8192 + (h)*8192 + tid*8];                    \
    gload_lds16(s0, dst);                                                    \
    gload_lds16(s0 + (size_t)64 * ldb, dst + 4096);                         \
  } while (0)

#define LOADA(mih, b) { _Pragma("unroll") for (int q = 0; q < 2; ++q) {      \
    const u16* rp = &lds[(b)*24576 + (wm*64 + (mih)*32 + q*16 + lr) * 64];   \
    af[q][0] = *(const bf16x8*)(rp + agc0);                                  \
    af[q][1] = *(const bf16x8*)(rp + agc1); } }

#define LOADB(dst, nih, b) { _Pragma("unroll") for (int nq = 0; nq < 2; ++nq) { \
    const u16* rp = &lds[(b)*24576 + 8192 + (wn*64 + (nih)*32 + nq*16 + lr) * 64]; \
    dst[nq][0] = *(const bf16x8*)(rp + agc0);                                \
    dst[nq][1] = *(const bf16x8*)(rp + agc1); } }

#define MM(mih, nih, BF) {                                                   \
    __builtin_amdgcn_s_setprio(1);                                           \
    _Pragma("unroll") for (int kk = 0; kk < 2; ++kk)                         \
      _Pragma("unroll") for (int q = 0; q < 2; ++q)                          \
        _Pragma("unroll") for (int nq = 0; nq < 2; ++nq)                     \
          acc[(mih)*2+q][(nih)*2+nq] = __builtin_amdgcn_mfma_f32_16x16x32_bf16( \
              af[q][kk], BF[nq][kk], acc[(mih)*2+q][(nih)*2+nq], 0, 0, 0);   \
    __builtin_amdgcn_s_setprio(0); }

  STAGE_A(0, 0); STAGE_BH(0, 0, 0); STAGE_BH(1, 0, 0);
  STAGE_BH(0, 1, 1); STAGE_BH(1, 1, 1);
  asm volatile("s_waitcnt vmcnt(4)" ::: "memory");
  __builtin_amdgcn_s_barrier();

  for (int i = 0; i < NI; ++i) {
    const int t0 = 2 * i;
    LOADA(0, 0); LOADB(bf0, 0, 0);
    STAGE_A(1, t0 + 1);
    SYNC_MID; MM(0, 0, bf0); PHEND;
    LOADB(bf1, 1, 0);
    STAGE_BH(0, 0, t0 + 2);
    SYNC_MID; MM(0, 1, bf1); PHEND;
    LOADA(1, 0);
    STAGE_BH(1, 0, t0 + 2);
    SYNC_MID; MM(1, 1, bf1); PHEND;
    STAGE_A(0, t0 + 2);
    SYNC_MID; MM(1, 0, bf0);
    asm volatile("s_waitcnt vmcnt(6)" ::: "memory");
    __builtin_amdgcn_s_barrier();
    LOADA(0, 1); LOADB(bf0, 0, 1);
    SYNC_MID; MM(0, 0, bf0); PHEND;
    LOADB(bf1, 1, 1);
    STAGE_BH(0, 1, t0 + 3);
    SYNC_MID; MM(0, 1, bf1); PHEND;
    LOADA(1, 1);
    STAGE_BH(1, 1, t0 + 3);
    SYNC_MID; MM(1, 1, bf1); PHEND;
    SYNC_MID; MM(1, 0, bf0);
    asm volatile("s_waitcnt vmcnt(4)" ::: "memory");
    __builtin_amdgcn_s_barrier();
  }
#undef STAGE_A
#undef STAGE_BH
#undef LOADA
#undef LOADB
#undef MM
#undef SYNC_MID
#undef PHEND
#undef PHEND_VM

#pragma unroll
  for (int mi = 0; mi < 4; ++mi) {
    const int rowOff = (mi >> 1) * 32 + (mi & 1) * 16;
#pragma unroll
    for (int ni = 0; ni < 4; ++ni) {
      const int colOff = (ni >> 1) * 32 + (ni & 1) * 16;
#pragma unroll
      for (int j = 0; j < 4; ++j) {
        int row = bm*128 + wm*64 + rowOff + g*4 + j;
        int col = n_off + bn*256 + wn*64 + colOff + lr;
        epi_store<EPI>((size_t)row * ldc + col, acc[mi][ni][j], Cf, Cb, resf, resb, other);
      }
    }
  }
}

// ------- RoPE + relayout ------------------------------------------------------------
__global__ __launch_bounds__(256) void rope_kernel(
    const u16* __restrict__ qkv, const float* __restrict__ ct, const float* __restrict__ st,
    u16* __restrict__ Q, u16* __restrict__ Kt, u16* __restrict__ VT)
{
  const int tok = blockIdx.x;
  const int b = tok >> 11, s = tok & (S_LEN - 1);
  const int w = threadIdx.x >> 6, lane = threadIdx.x & 63;
  const size_t base = (size_t)tok * QKV_N;
  for (int slot = w; slot < 48; slot += 4) {
    int col = (slot < 32) ? slot * 64 : (slot < 40 ? 2048 + (slot - 32) * 64 : 2560 + (slot - 40) * 64);
    float v = b2f(qkv[base + col + lane]);
    if (slot < 40) {
      int i = lane & 31;
      float c = ct[s * 32 + i], sn = st[s * 32 + i];
      float p = b2f(qkv[base + col + (lane ^ 32)]);
      v = (lane < 32) ? (v * c - p * sn) : (v * c + p * sn);
    }
    u16 ob = f2b(v);
    if (slot < 32)      Q [((size_t)(b * 32 + slot)      * S_LEN + s) * 64 + lane] = ob;
    else if (slot < 40) Kt[((size_t)(b * 8 + slot - 32)  * S_LEN + s) * 64 + lane] = ob;
    else                VT[((size_t)(b * 8 + slot - 40)  * 64 + lane) * S_LEN + s] = ob;
  }
}

// ------- causal GQA flash attention: swapped QK^T, in-reg softmax, K-prefetch ---------
#define ASCALE 0.1803368801111204f   /* 0.125 * log2(e) */
__global__ __launch_bounds__(256, 3) void attn_kernel(
    const u16* __restrict__ Q, const u16* __restrict__ Kt,
    const u16* __restrict__ VT, u16* __restrict__ ctx)
{
  const int bh  = blockIdx.x;
  const int qb  = 15 - blockIdx.y;       // heavy blocks first
  const int wid = threadIdx.x >> 6;
  const int lane = threadIdx.x & 63;
  const int b = bh >> 5, h = bh & 31;
  const int kvh = (b << 3) + (h >> 2);
  const int q0 = qb * 128 + wid * 32;
  const int cq = lane & 31;
  const int hi = lane >> 5;

  const u16* Qb = Q  + ((size_t)bh * S_LEN + q0) * 64;
  const u16* Kp = Kt + (size_t)kvh * S_LEN * 64 + cq * 64 + hi * 8;  // +t*2048, +q*16
  const u16* Vbase = VT + (size_t)kvh * 64 * S_LEN + hi * 8;
  const u16* Vp[4];
#pragma unroll
  for (int v = 0; v < 4; ++v)
    Vp[v] = Vbase + (size_t)((v & 1) * 32 + cq) * S_LEN + (v >> 1) * 16;     // +t*32

  bf16x8 qf[4];
#pragma unroll
  for (int t = 0; t < 4; ++t)
    qf[t] = *reinterpret_cast<const bf16x8*>(&Qb[cq * 64 + t * 16 + hi * 8]);

  f32x16 o0 = {}, o1 = {};
  float m = -1e30f, l = 0.f;    // l: this lane's half-sum; combined at end

  __shared__ float xch[4][32];

  const int nt = qb * 4 + wid + 1;

#define ATT_LOADK(KF, T) { _Pragma("unroll") for (int q_ = 0; q_ < 4; ++q_) \
    KF[q_] = *(const bf16x8*)(Kp + (T) * 2048 + q_ * 16); }
#define ATT_LOADV(VF, T) { _Pragma("unroll") for (int v_ = 0; v_ < 4; ++v_) \
    VF[v_] = *(const bf16x8*)(Vp[v_] + (T) * 32); }

#define ATT_COMPUTE(KF, VF, T) do {                                          \
    f32x16 sA = {}, sB = {};                                                 \
    sA = __builtin_amdgcn_mfma_f32_32x32x16_bf16(KF[0], qf[0], sA, 0, 0, 0); \
    sB = __builtin_amdgcn_mfma_f32_32x32x16_bf16(KF[1], qf[1], sB, 0, 0, 0); \
    sA = __builtin_amdgcn_mfma_f32_32x32x16_bf16(KF[2], qf[2], sA, 0, 0, 0); \
    sB = __builtin_amdgcn_mfma_f32_32x32x16_bf16(KF[3], qf[3], sB, 0, 0, 0); \
    float p[16];                                                             \
    _Pragma("unroll") for (int r = 0; r < 16; ++r) p[r] = (sA[r] + sB[r]) * ASCALE; \
    if ((T) == nt - 1) {                                                     \
      _Pragma("unroll") for (int r = 0; r < 16; ++r) {                       \
        int kk = (r & 3) + 8 * (r >> 2) + 4 * hi;                            \
        if (kk > cq) p[r] = -1e30f;                                          \
      }                                                                      \
    }                                                                        \
    float m0_ = fmaxf(fmaxf(p[0], p[1]), p[2]);                              \
    float m1_ = fmaxf(fmaxf(p[3], p[4]), p[5]);                              \
    float m2_ = fmaxf(fmaxf(p[6], p[7]), p[8]);                              \
    float m3_ = fmaxf(fmaxf(p[9], p[10]), p[11]);                            \
    float m4_ = fmaxf(fmaxf(p[12], p[13]), p[14]);                           \
    float tmax = fmaxf(fmaxf(fmaxf(m0_, m1_), m2_), fmaxf(fmaxf(m3_, m4_), p[15])); \
    tmax = fmaxf(tmax, __shfl_xor(tmax, 32));                                \
    if (!__all(tmax <= m + 8.0f)) {                                          \
      float mn = fmaxf(m, tmax);                                             \
      float corr = exp2f(m - mn);                                            \
      m = mn;                                                                \
      l *= corr;                                                             \
      if (hi == 0) xch[wid][cq] = corr;                                      \
      asm volatile("s_waitcnt lgkmcnt(0)" ::: "memory");                     \
      __builtin_amdgcn_sched_barrier(0);                                     \
      float4 c0 = *reinterpret_cast<const float4*>(&xch[wid][4 * hi + 0]);   \
      float4 c1 = *reinterpret_cast<const float4*>(&xch[wid][4 * hi + 8]);   \
      float4 c2 = *reinterpret_cast<const float4*>(&xch[wid][4 * hi + 16]);  \
      float4 c3 = *reinterpret_cast<const float4*>(&xch[wid][4 * hi + 24]);  \
      float ca[16] = {c0.x,c0.y,c0.z,c0.w, c1.x,c1.y,c1.z,c1.w,              \
                      c2.x,c2.y,c2.z,c2.w, c3.x,c3.y,c3.z,c3.w};             \
      _Pragma("unroll") for (int r = 0; r < 16; ++r) { o0[r] *= ca[r]; o1[r] *= ca[r]; } \
    }                                                                        \
    float tsum = 0.f;                                                        \
    _Pragma("unroll") for (int r = 0; r < 16; ++r) { p[r] = exp2f(p[r] - m); tsum += p[r]; } \
    l += tsum;                                                               \
    uint32_t wds[8], pw[8];                                                  \
    _Pragma("unroll") for (int j = 0; j < 8; ++j) {                          \
      uint32_t wv;                                                           \
      asm("v_cvt_pk_bf16_f32 %0, %1, %2" : "=v"(wv) : "v"(p[2*j]), "v"(p[2*j+1])); \
      wds[j] = wv;                                                           \
    }                                                                        \
    _Pragma("unroll") for (int j = 0; j < 8; ++j) pw[j] = __shfl_xor(wds[j], 32); \
    union { uint32_t u[4]; bf16x8 v; } pa0, pa1;                             \
    pa0.u[0] = hi ? pw[2]  : wds[0];                                         \
    pa0.u[1] = hi ? pw[3]  : wds[1];                                         \
    pa0.u[2] = hi ? wds[2] : pw[0];                                          \
    pa0.u[3] = hi ? wds[3] : pw[1];                                          \
    pa1.u[0] = hi ? pw[6]  : wds[4];                                         \
    pa1.u[1] = hi ? pw[7]  : wds[5];                                         \
    pa1.u[2] = hi ? wds[6] : pw[4];                                          \
    pa1.u[3] = hi ? wds[7] : pw[5];                                          \
    o0 = __builtin_amdgcn_mfma_f32_32x32x16_bf16(pa0.v, VF[0], o0, 0, 0, 0); \
    o0 = __builtin_amdgcn_mfma_f32_32x32x16_bf16(pa1.v, VF[2], o0, 0, 0, 0); \
    o1 = __builtin_amdgcn_mfma_f32_32x32x16_bf16(pa0.v, VF[1], o1, 0, 0, 0); \
    o1 = __builtin_amdgcn_mfma_f32_32x32x16_bf16(pa1.v, VF[3], o1, 0, 0, 0); \
  } while (0)

  bf16x8 kf0[4], kf1[4], vf[4];
  ATT_LOADK(kf0, 0);
  for (int t = 0; t < nt; ) {
    if (t + 1 < nt) ATT_LOADK(kf1, t + 1);
    ATT_LOADV(vf, t);
    ATT_COMPUTE(kf0, vf, t);
    ++t; if (t >= nt) break;
    if (t + 1 < nt) ATT_LOADK(kf0, t + 1);
    ATT_LOADV(vf, t);
    ATT_COMPUTE(kf1, vf, t);
    ++t;
  }
#undef ATT_LOADK
#undef ATT_LOADV
#undef ATT_COMPUTE

  // combine the two 16-row half-sums, then broadcast 1/l per q-row
  l += __shfl_xor(l, 32);
  float linv = 1.0f / l;
  if (hi == 0) xch[wid][cq] = linv;
  asm volatile("s_waitcnt lgkmcnt(0)" ::: "memory");
  __builtin_amdgcn_sched_barrier(0);
  float4 n0 = *reinterpret_cast<const float4*>(&xch[wid][4 * hi + 0]);
  float4 n1 = *reinterpret_cast<const float4*>(&xch[wid][4 * hi + 8]);
  float4 n2 = *reinterpret_cast<const float4*>(&xch[wid][4 * hi + 16]);
  float4 n3 = *reinterpret_cast<const float4*>(&xch[wid][4 * hi + 24]);
  float na[16] = {n0.x,n0.y,n0.z,n0.w, n1.x,n1.y,n1.z,n1.w,
                  n2.x,n2.y,n2.z,n2.w, n3.x,n3.y,n3.z,n3.w};
#pragma unroll
  for (int r = 0; r < 16; ++r) {
    int row = (r & 3) + 8 * (r >> 2) + 4 * hi;
    size_t base = (size_t)(b * S_LEN + q0 + row) * D_MODEL + h * 64;
    ctx[base + cq]      = f2b(o0[r] * na[r]);
    ctx[base + 32 + cq] = f2b(o1[r] * na[r]);
  }
}

// ---------------------------------- host ---------------------------------------------
extern "C" void kernel_launch(void* const* d_in, const int* in_sizes, int n_in,
                              void* d_out, int out_size, void* d_ws, size_t ws_size,
                              hipStream_t stream)
{
  const float* x     = (const float*)d_in[0];
  const float* wn1   = (const float*)d_in[1];
  const float* wqkv  = (const float*)d_in[2];
  const float* wout  = (const float*)d_in[3];
  const float* wn2   = (const float*)d_in[4];
  const float* wgate = (const float*)d_in[5];
  const float* wup   = (const float*)d_in[6];
  const float* wdown = (const float*)d_in[7];
  float* out = (float*)d_out;
  char* ws = (char*)d_ws;

  float* cosT = (float*)(ws + 0);
  float* sinT = (float*)(ws + 262144);
  u16*   wT   = (u16*)  (ws + 524288);
  u16*   hB   = (u16*)  (ws + 17301504);
  u16*   x1b  = (u16*)  (ws + 34078720);
  char*  S    = ws + 50855936;
  u16*   qkvB = (u16*)(S + 0);
  u16*   qB   = (u16*)(S + 25165824);
  u16*   kB   = (u16*)(S + 41943040);
  u16*   vtB  = (u16*)(S + 46137344);
  u16*   ctxB = (u16*)(S + 50331648);
  u16*   gsB  = (u16*)(S + 0);

  sincos_kernel<<<dim3(256), 256, 0, stream>>>(cosT, sinT);
  rmsnorm_kernel<false><<<dim3(NTOK), 256, 0, stream>>>(x, wn1, hB);

  // qkv = h @ w_qkv  (128x256 tiles -> 384 blocks)
  wconv_kernel<<<dim3((2048/64)*(3072/64)), 256, 0, stream>>>(wqkv, wT, 3072, 2048, 3072, 0, 0);
  gemm128_kernel<4><<<dim3(QKV_N/256, NTOK/128), 512, 0, stream>>>(hB, wT, 2048, 2048, 2048, 3072, 0, nullptr, qkvB, nullptr, nullptr, nullptr);
  rope_kernel<<<dim3(NTOK), 256, 0, stream>>>(qkvB, cosT, sinT, qB, kB, vtB);
  attn_kernel<<<dim3(64, 16), 256, 0, stream>>>(qB, kB, vtB, ctxB);

  // x1 = x + ctx @ w_out  (256 blocks)
  wconv_kernel<<<dim3((2048/64)*(2048/64)), 256, 0, stream>>>(wout, wT, 2048, 2048, 2048, 0, 0);
  gemm128_kernel<6><<<dim3(D_MODEL/256, NTOK/128), 512, 0, stream>>>(ctxB, wT, 2048, 2048, 2048, 2048, 0, nullptr, x1b, x, nullptr, nullptr);

  rmsnorm_kernel<true><<<dim3(NTOK), 256, 0, stream>>>(x1b, wn2, hB);

  for (int c = 0; c < 2; ++c) {
    wconv_kernel<<<dim3((2048/64)*(4096/64)), 256, 0, stream>>>(wgate, wT, 8192, 2048, 4096, 0, c*4096);
    gemm8p_kernel<2><<<dim3(4096/256, NTOK/256), 512, 0, stream>>>(hB, wT, 2048, 2048, 2048, 8192, c*4096, nullptr, gsB, nullptr, nullptr, nullptr);
  }
  for (int c = 0; c < 2; ++c) {
    wconv_kernel<<<dim3((2048/64)*(4096/64)), 256, 0, stream>>>(wup, wT, 8192, 2048, 4096, 0, c*4096);
    gemm8p_kernel<3><<<dim3(4096/256, NTOK/256), 512, 0, stream>>>(hB, wT, 2048, 2048, 2048, 8192, c*4096, nullptr, gsB, nullptr, nullptr, gsB);
  }
  // out = x1 + gs @ w_down, two K-chunks (256 blocks each)
  wconv_kernel<<<dim3((4096/64)*(2048/64)), 256, 0, stream>>>(wdown, wT, 2048, 4096, 2048, 0, 0);
  gemm128_kernel<7><<<dim3(D_MODEL/256, NTOK/128), 512, 0, stream>>>(gsB, wT, 4096, 8192, 4096, 2048, 0, out, nullptr, nullptr, x1b, nullptr);
  wconv_kernel<<<dim3((4096/64)*(2048/64)), 256, 0, stream>>>(wdown, wT, 2048, 4096, 2048, 4096, 0);
  gemm128_kernel<5><<<dim3(D_MODEL/256, NTOK/128), 512, 0, stream>>>(gsB + 4096, wT, 4096, 8192, 4096, 2048, 0, out, nullptr, nullptr, nullptr, nullptr);
}

// Round 8
// 791.394 us; speedup vs baseline: 1.4625x; 1.0258x over previous
//
#include <hip/hip_runtime.h>
#include <stdint.h>

#define D_MODEL 2048
#define S_LEN   2048
#define NTOK    4096
#define QKV_N   3072
#define DFF     8192

typedef float  f32x4   __attribute__((ext_vector_type(4)));
typedef float  f32x16  __attribute__((ext_vector_type(16)));
typedef __bf16 bf16x8  __attribute__((ext_vector_type(8)));
typedef unsigned short u16;
typedef unsigned short u16x8 __attribute__((ext_vector_type(8)));

__device__ __forceinline__ float b2f(u16 u){ union{float f; uint32_t i;} v; v.i = ((uint32_t)u) << 16; return v.f; }
__device__ __forceinline__ u16 f2b(float f){
  union{float f; uint32_t i;} v; v.f = f;
  uint32_t r = v.i + 0x7FFFu + ((v.i >> 16) & 1u);
  return (u16)(r >> 16);
}

__device__ __forceinline__ void gload_lds16(const void* gsrc, void* ldst){
  __builtin_amdgcn_global_load_lds(
      (const __attribute__((address_space(1))) void*)gsrc,
      (__attribute__((address_space(3))) void*)ldst,
      16, 0, 0);
}

// ------- grid-stride weight convert+transpose tail task ------------------------------
// Converts W[k0g.., n0g..] (f32, row-stride Nfull) -> WT[Nt][Kt] bf16, 64x64 tiles.
// Uses 16.6 KB of the caller's LDS (after barrier). Safe with any blockDim >= 256.
__device__ __forceinline__ void conv_tiles(const float* W, u16* WT,
    int Nfull, int Kt, int Nt, int k0g, int n0g, void* ldsbuf)
{
  if (W == nullptr) return;
  float* tf = (float*)ldsbuf;
  const int tt  = threadIdx.x;
  const int nTn = Nt >> 6;
  const int nT  = (Kt >> 6) * nTn;
  const int bid = blockIdx.y * gridDim.x + blockIdx.x;
  const int gsz = gridDim.x * gridDim.y;
  const int c4 = (tt & 15) << 2;
  const int r  = tt >> 4;
  for (int tile = bid; tile < nT; tile += gsz) {
    const int k0 = (tile / nTn) << 6, n0 = (tile % nTn) << 6;
    __syncthreads();
    if (tt < 256) {
#pragma unroll
      for (int i = 0; i < 4; ++i) {
        int row = r + i * 16;
        float4 v = *reinterpret_cast<const float4*>(&W[(size_t)(k0g + k0 + row) * Nfull + n0g + n0 + c4]);
        tf[row * 65 + c4 + 0] = v.x; tf[row * 65 + c4 + 1] = v.y;
        tf[row * 65 + c4 + 2] = v.z; tf[row * 65 + c4 + 3] = v.w;
      }
    }
    __syncthreads();
    if (tt < 256) {
#pragma unroll
      for (int i = 0; i < 4; ++i) {
        int n = r + i * 16;
        ushort4 ov;
        ov.x = f2b(tf[(c4 + 0) * 65 + n]); ov.y = f2b(tf[(c4 + 1) * 65 + n]);
        ov.z = f2b(tf[(c4 + 2) * 65 + n]); ov.w = f2b(tf[(c4 + 3) * 65 + n]);
        *reinterpret_cast<ushort4*>(&WT[(size_t)(n0 + n) * Kt + k0 + c4]) = ov;
      }
    }
  }
}

// ------- standalone wconv (first weight only) ----------------------------------------
__global__ __launch_bounds__(256) void wconv_kernel(const float* __restrict__ W, u16* __restrict__ WT,
                                                    int Nfull, int Kt, int Nt, int k0g, int n0g)
{
  __shared__ float tile[64 * 65];
  conv_tiles(W, WT, Nfull, Kt, Nt, k0g, n0g, tile);
}

// ------- rope cos/sin table --------------------------------------------------------
__global__ void sincos_kernel(float* __restrict__ ct, float* __restrict__ st)
{
  int idx = blockIdx.x * 256 + threadIdx.x;
  if (idx >= S_LEN * 32) return;
  int p = idx >> 5, i = idx & 31;
  double freq = pow(10000.0, -((double)(2*i)) / 64.0);
  double ang  = (double)p * freq;
  ct[idx] = (float)cos(ang);
  st[idx] = (float)sin(ang);
}

// ------- RMSNorm (+ optional conversion tail) ----------------------------------------
template<bool BF16IN>
__global__ __launch_bounds__(256) void rmsnorm_kernel(const void* __restrict__ xin, const float* __restrict__ w, u16* __restrict__ out,
                                                      const float* cvW, u16* cvWT, int cvNfull, int cvKt, int cvNt, int cvK0g, int cvN0g)
{
  __shared__ float tfbuf[64 * 65];
  const int row = blockIdx.x;
  const int t = threadIdx.x;
  float v[8];
  if (BF16IN) {
    const u16* xr = ((const u16*)xin) + (size_t)row * D_MODEL;
    u16x8 a = *reinterpret_cast<const u16x8*>(&xr[t*8]);
#pragma unroll
    for (int j = 0; j < 8; ++j) v[j] = b2f(a[j]);
  } else {
    const float* xr = ((const float*)xin) + (size_t)row * D_MODEL;
    float4 a = *reinterpret_cast<const float4*>(&xr[t*8]);
    float4 c = *reinterpret_cast<const float4*>(&xr[t*8+4]);
    v[0]=a.x; v[1]=a.y; v[2]=a.z; v[3]=a.w; v[4]=c.x; v[5]=c.y; v[6]=c.z; v[7]=c.w;
  }
  float ss = 0.f;
#pragma unroll
  for (int j = 0; j < 8; ++j) ss += v[j]*v[j];
#pragma unroll
  for (int d = 1; d < 64; d <<= 1) ss += __shfl_xor(ss, d);
  __shared__ float red[4];
  if ((t & 63) == 0) red[t >> 6] = ss;
  __syncthreads();
  ss = red[0] + red[1] + red[2] + red[3];
  const float sc = rsqrtf(ss * (1.0f / (float)D_MODEL) + 1e-5f);
  float4 w0 = *reinterpret_cast<const float4*>(&w[t*8]);
  float4 w1 = *reinterpret_cast<const float4*>(&w[t*8+4]);
  u16x8 o;
  o[0]=f2b(v[0]*sc*w0.x); o[1]=f2b(v[1]*sc*w0.y); o[2]=f2b(v[2]*sc*w0.z); o[3]=f2b(v[3]*sc*w0.w);
  o[4]=f2b(v[4]*sc*w1.x); o[5]=f2b(v[5]*sc*w1.y); o[6]=f2b(v[6]*sc*w1.z); o[7]=f2b(v[7]*sc*w1.w);
  *reinterpret_cast<u16x8*>(&out[(size_t)row * D_MODEL + t*8]) = o;
  conv_tiles(cvW, cvWT, cvNfull, cvKt, cvNt, cvK0g, cvN0g, tfbuf);
}

// ------- shared GEMM epilogue dispatch ------------------------------------------------
// EPI: 2 silu->Cb; 3 Cb=v*other; 4 Cb=v; 5 Cf+=v; 6 Cb=f2b(v+resf); 7 Cf=v+b2f(resb)
template<int EPI>
__device__ __forceinline__ void epi_store(size_t idx, float v, float* Cf, u16* Cb,
                                          const float* resf, const u16* resb, const u16* other)
{
  if (EPI == 2)      Cb[idx] = f2b(v / (1.0f + __expf(-v)));
  else if (EPI == 3) Cb[idx] = f2b(v * b2f(other[idx]));
  else if (EPI == 4) Cb[idx] = f2b(v);
  else if (EPI == 5) Cf[idx] += v;
  else if (EPI == 6) Cb[idx] = f2b(v + resf[idx]);
  else if (EPI == 7) Cf[idx] = v + b2f(resb[idx]);
}

// ------- 256x256 8-phase bf16 MFMA GEMM: A[M][lda] x BT[N][ldb] -----------------------
template<int EPI>
__global__ __launch_bounds__(512, 2) void gemm8p_kernel(
    const u16* __restrict__ A, const u16* __restrict__ BT,
    int K, int lda, int ldb, int ldc, int n_off,
    float* Cf, u16* Cb,
    const float* __restrict__ resf, const u16* __restrict__ resb, const u16* other,
    const float* cvW, u16* cvWT, int cvNfull, int cvKt, int cvNt, int cvK0g, int cvN0g)
{
  __shared__ u16 lds[65536];
  const int tid = threadIdx.x;
  const int w = tid >> 6, lane = tid & 63;
  const int g = lane >> 4, lr = lane & 15;
  const int wm = w >> 2, wn = w & 3;
  const int bn = blockIdx.x, bm = blockIdx.y;
  const int NT = K >> 6;
  const int NI = NT >> 1;

  const int srow = tid >> 3;
  const int sg   = (tid & 7) ^ (srow & 7);
  const u16* Asrc = A  + (size_t)(bm * 256) * lda;
  const u16* Bsrc = BT + (size_t)(bn * 256) * ldb;

  const int agc0 = ((0 + g) ^ (lr & 7)) * 8;
  const int agc1 = ((4 + g) ^ (lr & 7)) * 8;

  f32x4 acc[8][4];
#pragma unroll
  for (int i = 0; i < 8; ++i)
#pragma unroll
    for (int j = 0; j < 4; ++j) acc[i][j] = (f32x4){0.f, 0.f, 0.f, 0.f};
  bf16x8 af[4][2], bf0[2][2], bf1[2][2];

#define STAGE_H(isB, h, b, T) do {                                           \
    int tc = ((T) < NT) ? (T) : (NT - 1);                                    \
    const u16* sb = (isB) ? Bsrc : Asrc;                                     \
    const int  sld = (isB) ? ldb : lda;                                      \
    const u16* s0 = sb + (size_t)((h)*128 + srow) * sld + tc*64 + sg*8;      \
    u16* dst = &lds[(b)*32768 + (isB)*16384 + (h)*8192 + tid*8];             \
    gload_lds16(s0, dst);                                                    \
    gload_lds16(s0 + (size_t)64 * sld, dst + 4096);                          \
  } while (0)

#define LOADA(mih, b) { _Pragma("unroll") for (int q = 0; q < 4; ++q) {      \
    const u16* rp = &lds[(b)*32768 + (wm*128 + (mih)*64 + q*16 + lr) * 64];  \
    af[q][0] = *(const bf16x8*)(rp + agc0);                                  \
    af[q][1] = *(const bf16x8*)(rp + agc1); } }

#define LOADB(dst, nih, b) { _Pragma("unroll") for (int nq = 0; nq < 2; ++nq) { \
    const u16* rp = &lds[(b)*32768 + 16384 + (wn*64 + (nih)*32 + nq*16 + lr) * 64]; \
    dst[nq][0] = *(const bf16x8*)(rp + agc0);                                \
    dst[nq][1] = *(const bf16x8*)(rp + agc1); } }

#define MM(mih, nih, BF) {                                                   \
    __builtin_amdgcn_s_setprio(1);                                           \
    _Pragma("unroll") for (int kk = 0; kk < 2; ++kk)                         \
      _Pragma("unroll") for (int q = 0; q < 4; ++q)                          \
        _Pragma("unroll") for (int nq = 0; nq < 2; ++nq)                     \
          acc[(mih)*4+q][(nih)*2+nq] = __builtin_amdgcn_mfma_f32_16x16x32_bf16( \
              af[q][kk], BF[nq][kk], acc[(mih)*4+q][(nih)*2+nq], 0, 0, 0);   \
    __builtin_amdgcn_s_setprio(0); }

#define SYNC_MID  __builtin_amdgcn_s_barrier();                              \
                  asm volatile("s_waitcnt lgkmcnt(0)" ::: "memory");         \
                  __builtin_amdgcn_sched_barrier(0);
#define PHEND     __builtin_amdgcn_s_barrier();
#define PHEND_VM  asm volatile("s_waitcnt vmcnt(4)" ::: "memory");           \
                  __builtin_amdgcn_s_barrier();

  STAGE_H(0, 0, 0, 0); STAGE_H(0, 1, 0, 0);
  STAGE_H(1, 0, 0, 0); STAGE_H(1, 1, 0, 0);
  STAGE_H(1, 0, 1, 1); STAGE_H(1, 1, 1, 1);
  asm volatile("s_waitcnt vmcnt(4)" ::: "memory");
  __builtin_amdgcn_s_barrier();

  for (int i = 0; i < NI; ++i) {
    const int t0 = 2 * i;
    LOADA(0, 0); LOADB(bf0, 0, 0);
    STAGE_H(0, 0, 1, t0 + 1);
    SYNC_MID; MM(0, 0, bf0); PHEND;
    LOADB(bf1, 1, 0);
    STAGE_H(0, 1, 1, t0 + 1);
    SYNC_MID; MM(0, 1, bf1); PHEND;
    LOADA(1, 0);
    STAGE_H(1, 0, 0, t0 + 2);
    SYNC_MID; MM(1, 1, bf1); PHEND;
    STAGE_H(1, 1, 0, t0 + 2);
    SYNC_MID; MM(1, 0, bf0); PHEND_VM;
    LOADA(0, 1); LOADB(bf0, 0, 1);
    STAGE_H(0, 0, 0, t0 + 2);
    SYNC_MID; MM(0, 0, bf0); PHEND;
    LOADB(bf1, 1, 1);
    STAGE_H(0, 1, 0, t0 + 2);
    SYNC_MID; MM(0, 1, bf1); PHEND;
    LOADA(1, 1);
    STAGE_H(1, 0, 1, t0 + 3);
    SYNC_MID; MM(1, 1, bf1); PHEND;
    STAGE_H(1, 1, 1, t0 + 3);
    SYNC_MID; MM(1, 0, bf0); PHEND_VM;
  }
#undef STAGE_H
#undef LOADA
#undef LOADB
#undef MM

#pragma unroll
  for (int mi = 0; mi < 8; ++mi) {
    const int rowOff = (mi >> 2) * 64 + (mi & 3) * 16;
#pragma unroll
    for (int ni = 0; ni < 4; ++ni) {
      const int colOff = (ni >> 1) * 32 + (ni & 1) * 16;
#pragma unroll
      for (int j = 0; j < 4; ++j) {
        int row = bm*256 + wm*128 + rowOff + g*4 + j;
        int col = n_off + bn*256 + wn*64 + colOff + lr;
        epi_store<EPI>((size_t)row * ldc + col, acc[mi][ni][j], Cf, Cb, resf, resb, other);
      }
    }
  }
  conv_tiles(cvW, cvWT, cvNfull, cvKt, cvNt, cvK0g, cvN0g, lds);
}

// ------- 128x256 8-phase bf16 MFMA GEMM (fills 256 CUs for N=2048 outputs) ------------
template<int EPI>
__global__ __launch_bounds__(512) void gemm128_kernel(
    const u16* __restrict__ A, const u16* __restrict__ BT,
    int K, int lda, int ldb, int ldc, int n_off,
    float* Cf, u16* Cb,
    const float* __restrict__ resf, const u16* __restrict__ resb, const u16* other,
    const float* cvW, u16* cvWT, int cvNfull, int cvKt, int cvNt, int cvK0g, int cvN0g)
{
  __shared__ u16 lds[49152];
  const int tid = threadIdx.x;
  const int w = tid >> 6, lane = tid & 63;
  const int g = lane >> 4, lr = lane & 15;
  const int wm = w >> 2, wn = w & 3;
  const int bn = blockIdx.x, bm = blockIdx.y;
  const int NT = K >> 6;
  const int NI = NT >> 1;

  const int srow = tid >> 3;
  const int sg   = (tid & 7) ^ (srow & 7);
  const u16* Asrc = A  + (size_t)(bm * 128) * lda;
  const u16* Bsrc = BT + (size_t)(bn * 256) * ldb;

  const int agc0 = ((0 + g) ^ (lr & 7)) * 8;
  const int agc1 = ((4 + g) ^ (lr & 7)) * 8;

  f32x4 acc[4][4];
#pragma unroll
  for (int i = 0; i < 4; ++i)
#pragma unroll
    for (int j = 0; j < 4; ++j) acc[i][j] = (f32x4){0.f, 0.f, 0.f, 0.f};
  bf16x8 af[2][2], bf0[2][2], bf1[2][2];

#define STAGE_A(b, T) do {                                                   \
    int tc = ((T) < NT) ? (T) : (NT - 1);                                    \
    const u16* s0 = Asrc + (size_t)srow * lda + tc*64 + sg*8;                \
    u16* dst = &lds[(b)*24576 + tid*8];                                      \
    gload_lds16(s0, dst);                                                    \
    gload_lds16(s0 + (size_t)64 * lda, dst + 4096);                          \
  } while (0)

#define STAGE_BH(h, b, T) do {                                               \
    int tc = ((T) < NT) ? (T) : (NT - 1);                                    \
    const u16* s0 = Bsrc + (size_t)((h)*128 + srow) * ldb + tc*64 + sg*8;    \
    u16* dst = &lds[(b)*24576 + 8192 + (h)*8192 + tid*8];                    \
    gload_lds16(s0, dst);                                                    \
    gload_lds16(s0 + (size_t)64 * ldb, dst + 4096);                         \
  } while (0)

#define LOADA(mih, b) { _Pragma("unroll") for (int q = 0; q < 2; ++q) {      \
    const u16* rp = &lds[(b)*24576 + (wm*64 + (mih)*32 + q*16 + lr) * 64];   \
    af[q][0] = *(const bf16x8*)(rp + agc0);                                  \
    af[q][1] = *(const bf16x8*)(rp + agc1); } }

#define LOADB(dst, nih, b) { _Pragma("unroll") for (int nq = 0; nq < 2; ++nq) { \
    const u16* rp = &lds[(b)*24576 + 8192 + (wn*64 + (nih)*32 + nq*16 + lr) * 64]; \
    dst[nq][0] = *(const bf16x8*)(rp + agc0);                                \
    dst[nq][1] = *(const bf16x8*)(rp + agc1); } }

#define MM(mih, nih, BF) {                                                   \
    __builtin_amdgcn_s_setprio(1);                                           \
    _Pragma("unroll") for (int kk = 0; kk < 2; ++kk)                         \
      _Pragma("unroll") for (int q = 0; q < 2; ++q)                          \
        _Pragma("unroll") for (int nq = 0; nq < 2; ++nq)                     \
          acc[(mih)*2+q][(nih)*2+nq] = __builtin_amdgcn_mfma_f32_16x16x32_bf16( \
              af[q][kk], BF[nq][kk], acc[(mih)*2+q][(nih)*2+nq], 0, 0, 0);   \
    __builtin_amdgcn_s_setprio(0); }

  STAGE_A(0, 0); STAGE_BH(0, 0, 0); STAGE_BH(1, 0, 0);
  STAGE_BH(0, 1, 1); STAGE_BH(1, 1, 1);
  asm volatile("s_waitcnt vmcnt(4)" ::: "memory");
  __builtin_amdgcn_s_barrier();

  for (int i = 0; i < NI; ++i) {
    const int t0 = 2 * i;
    LOADA(0, 0); LOADB(bf0, 0, 0);
    STAGE_A(1, t0 + 1);
    SYNC_MID; MM(0, 0, bf0); PHEND;
    LOADB(bf1, 1, 0);
    STAGE_BH(0, 0, t0 + 2);
    SYNC_MID; MM(0, 1, bf1); PHEND;
    LOADA(1, 0);
    STAGE_BH(1, 0, t0 + 2);
    SYNC_MID; MM(1, 1, bf1); PHEND;
    STAGE_A(0, t0 + 2);
    SYNC_MID; MM(1, 0, bf0);
    asm volatile("s_waitcnt vmcnt(6)" ::: "memory");
    __builtin_amdgcn_s_barrier();
    LOADA(0, 1); LOADB(bf0, 0, 1);
    SYNC_MID; MM(0, 0, bf0); PHEND;
    LOADB(bf1, 1, 1);
    STAGE_BH(0, 1, t0 + 3);
    SYNC_MID; MM(0, 1, bf1); PHEND;
    LOADA(1, 1);
    STAGE_BH(1, 1, t0 + 3);
    SYNC_MID; MM(1, 1, bf1); PHEND;
    SYNC_MID; MM(1, 0, bf0);
    asm volatile("s_waitcnt vmcnt(4)" ::: "memory");
    __builtin_amdgcn_s_barrier();
  }
#undef STAGE_A
#undef STAGE_BH
#undef LOADA
#undef LOADB
#undef MM
#undef SYNC_MID
#undef PHEND
#undef PHEND_VM

#pragma unroll
  for (int mi = 0; mi < 4; ++mi) {
    const int rowOff = (mi >> 1) * 32 + (mi & 1) * 16;
#pragma unroll
    for (int ni = 0; ni < 4; ++ni) {
      const int colOff = (ni >> 1) * 32 + (ni & 1) * 16;
#pragma unroll
      for (int j = 0; j < 4; ++j) {
        int row = bm*128 + wm*64 + rowOff + g*4 + j;
        int col = n_off + bn*256 + wn*64 + colOff + lr;
        epi_store<EPI>((size_t)row * ldc + col, acc[mi][ni][j], Cf, Cb, resf, resb, other);
      }
    }
  }
  conv_tiles(cvW, cvWT, cvNfull, cvKt, cvNt, cvK0g, cvN0g, lds);
}

// ------- RoPE + relayout for K, V only (Q handled inside attention) -------------------
__global__ __launch_bounds__(256) void rope_kernel(
    const u16* __restrict__ qkv, const float* __restrict__ ct, const float* __restrict__ st,
    u16* __restrict__ Kt, u16* __restrict__ VT)
{
  const int tok = blockIdx.x;
  const int b = tok >> 11, s = tok & (S_LEN - 1);
  const int w = threadIdx.x >> 6, lane = threadIdx.x & 63;
  const size_t base = (size_t)tok * QKV_N;
  for (int slot = w; slot < 16; slot += 4) {
    int col = (slot < 8) ? 2048 + slot * 64 : 2560 + (slot - 8) * 64;
    float v = b2f(qkv[base + col + lane]);
    if (slot < 8) {  // K: rope
      int i = lane & 31;
      float c = ct[s * 32 + i], sn = st[s * 32 + i];
      float p = b2f(qkv[base + col + (lane ^ 32)]);
      v = (lane < 32) ? (v * c - p * sn) : (v * c + p * sn);
    }
    u16 ob = f2b(v);
    if (slot < 8) Kt[((size_t)(b * 8 + slot)     * S_LEN + s) * 64 + lane] = ob;
    else          VT[((size_t)(b * 8 + slot - 8) * 64 + lane) * S_LEN + s] = ob;
  }
}

// ------- causal GQA flash attention: Q from qkvB w/ in-reg rope; + conv tail ----------
#define ASCALE 0.1803368801111204f   /* 0.125 * log2(e) */
__global__ __launch_bounds__(256, 3) void attn_kernel(
    const u16* __restrict__ qkv, const u16* __restrict__ Kt,
    const u16* __restrict__ VT, u16* __restrict__ ctx,
    const float* __restrict__ ct, const float* __restrict__ st,
    const float* cvW, u16* cvWT, int cvNfull, int cvKt, int cvNt, int cvK0g, int cvN0g)
{
  __shared__ float tfbuf[64 * 65];
  const int bh  = blockIdx.x;
  const int qb  = 15 - blockIdx.y;       // heavy blocks first
  const int wid = threadIdx.x >> 6;
  const int lane = threadIdx.x & 63;
  const int b = bh >> 5, h = bh & 31;
  const int kvh = (b << 3) + (h >> 2);
  const int q0 = qb * 128 + wid * 32;
  const int cq = lane & 31;
  const int hi = lane >> 5;

  const u16* Kp = Kt + (size_t)kvh * S_LEN * 64 + cq * 64 + hi * 8;
  const u16* Vbase = VT + (size_t)kvh * 64 * S_LEN + hi * 8;
  const u16* Vp[4];
#pragma unroll
  for (int v = 0; v < 4; ++v)
    Vp[v] = Vbase + (size_t)((v & 1) * 32 + cq) * S_LEN + (v >> 1) * 16;

  // Q load from qkvB + in-register RoPE (pairs (d, d+32) are lane-local)
  bf16x8 qf[4];
  {
    const u16* Qr = qkv + (size_t)(b * S_LEN + q0 + cq) * QKV_N + h * 64 + hi * 8;
    u16 qr[4][8];
#pragma unroll
    for (int t = 0; t < 4; ++t)
      *reinterpret_cast<u16x8*>(qr[t]) = *reinterpret_cast<const u16x8*>(Qr + t * 16);
    const float* cb = ct + (size_t)(q0 + cq) * 32 + hi * 8;
    const float* sb = st + (size_t)(q0 + cq) * 32 + hi * 8;
    union { u16 u[8]; bf16x8 v; } qo[4];
#pragma unroll
    for (int t = 0; t < 2; ++t) {
      float4 c0 = *reinterpret_cast<const float4*>(cb + 16 * t);
      float4 c1 = *reinterpret_cast<const float4*>(cb + 16 * t + 4);
      float4 s0 = *reinterpret_cast<const float4*>(sb + 16 * t);
      float4 s1 = *reinterpret_cast<const float4*>(sb + 16 * t + 4);
      float cc[8] = {c0.x,c0.y,c0.z,c0.w, c1.x,c1.y,c1.z,c1.w};
      float ssn[8] = {s0.x,s0.y,s0.z,s0.w, s1.x,s1.y,s1.z,s1.w};
#pragma unroll
      for (int i = 0; i < 8; ++i) {
        float lo = b2f(qr[t][i]), hif = b2f(qr[t + 2][i]);
        qo[t].u[i]     = f2b(lo * cc[i] - hif * ssn[i]);
        qo[t + 2].u[i] = f2b(hif * cc[i] + lo * ssn[i]);
      }
    }
#pragma unroll
    for (int t = 0; t < 4; ++t) qf[t] = qo[t].v;
  }

  f32x16 o0 = {}, o1 = {};
  float m = -1e30f, l = 0.f;

  __shared__ float xch[4][32];

  const int nt = qb * 4 + wid + 1;

#define ATT_LOADK(KF, T) { _Pragma("unroll") for (int q_ = 0; q_ < 4; ++q_) \
    KF[q_] = *(const bf16x8*)(Kp + (T) * 2048 + q_ * 16); }
#define ATT_LOADV(VF, T) { _Pragma("unroll") for (int v_ = 0; v_ < 4; ++v_) \
    VF[v_] = *(const bf16x8*)(Vp[v_] + (T) * 32); }

#define ATT_COMPUTE(KF, VF, T) do {                                          \
    f32x16 sA = {}, sB = {};                                                 \
    sA = __builtin_amdgcn_mfma_f32_32x32x16_bf16(KF[0], qf[0], sA, 0, 0, 0); \
    sB = __builtin_amdgcn_mfma_f32_32x32x16_bf16(KF[1], qf[1], sB, 0, 0, 0); \
    sA = __builtin_amdgcn_mfma_f32_32x32x16_bf16(KF[2], qf[2], sA, 0, 0, 0); \
    sB = __builtin_amdgcn_mfma_f32_32x32x16_bf16(KF[3], qf[3], sB, 0, 0, 0); \
    float p[16];                                                             \
    _Pragma("unroll") for (int r = 0; r < 16; ++r) p[r] = (sA[r] + sB[r]) * ASCALE; \
    if ((T) == nt - 1) {                                                     \
      _Pragma("unroll") for (int r = 0; r < 16; ++r) {                       \
        int kk = (r & 3) + 8 * (r >> 2) + 4 * hi;                            \
        if (kk > cq) p[r] = -1e30f;                                          \
      }                                                                      \
    }                                                                        \
    float m0_ = fmaxf(fmaxf(p[0], p[1]), p[2]);                              \
    float m1_ = fmaxf(fmaxf(p[3], p[4]), p[5]);                              \
    float m2_ = fmaxf(fmaxf(p[6], p[7]), p[8]);                              \
    float m3_ = fmaxf(fmaxf(p[9], p[10]), p[11]);                            \
    float m4_ = fmaxf(fmaxf(p[12], p[13]), p[14]);                           \
    float tmax = fmaxf(fmaxf(fmaxf(m0_, m1_), m2_), fmaxf(fmaxf(m3_, m4_), p[15])); \
    tmax = fmaxf(tmax, __shfl_xor(tmax, 32));                                \
    if (!__all(tmax <= m + 8.0f)) {                                          \
      float mn = fmaxf(m, tmax);                                             \
      float corr = exp2f(m - mn);                                            \
      m = mn;                                                                \
      l *= corr;                                                             \
      if (hi == 0) xch[wid][cq] = corr;                                      \
      asm volatile("s_waitcnt lgkmcnt(0)" ::: "memory");                     \
      __builtin_amdgcn_sched_barrier(0);                                     \
      float4 c0 = *reinterpret_cast<const float4*>(&xch[wid][4 * hi + 0]);   \
      float4 c1 = *reinterpret_cast<const float4*>(&xch[wid][4 * hi + 8]);   \
      float4 c2 = *reinterpret_cast<const float4*>(&xch[wid][4 * hi + 16]);  \
      float4 c3 = *reinterpret_cast<const float4*>(&xch[wid][4 * hi + 24]);  \
      float ca[16] = {c0.x,c0.y,c0.z,c0.w, c1.x,c1.y,c1.z,c1.w,              \
                      c2.x,c2.y,c2.z,c2.w, c3.x,c3.y,c3.z,c3.w};             \
      _Pragma("unroll") for (int r = 0; r < 16; ++r) { o0[r] *= ca[r]; o1[r] *= ca[r]; } \
    }                                                                        \
    float tsum = 0.f;                                                        \
    _Pragma("unroll") for (int r = 0; r < 16; ++r) { p[r] = exp2f(p[r] - m); tsum += p[r]; } \
    l += tsum;                                                               \
    uint32_t wds[8], pw[8];                                                  \
    _Pragma("unroll") for (int j = 0; j < 8; ++j) {                          \
      uint32_t wv;                                                           \
      asm("v_cvt_pk_bf16_f32 %0, %1, %2" : "=v"(wv) : "v"(p[2*j]), "v"(p[2*j+1])); \
      wds[j] = wv;                                                           \
    }                                                                        \
    _Pragma("unroll") for (int j = 0; j < 8; ++j) pw[j] = __shfl_xor(wds[j], 32); \
    union { uint32_t u[4]; bf16x8 v; } pa0, pa1;                             \
    pa0.u[0] = hi ? pw[2]  : wds[0];                                         \
    pa0.u[1] = hi ? pw[3]  : wds[1];                                         \
    pa0.u[2] = hi ? wds[2] : pw[0];                                          \
    pa0.u[3] = hi ? wds[3] : pw[1];                                          \
    pa1.u[0] = hi ? pw[6]  : wds[4];                                         \
    pa1.u[1] = hi ? pw[7]  : wds[5];                                         \
    pa1.u[2] = hi ? wds[6] : pw[4];                                          \
    pa1.u[3] = hi ? wds[7] : pw[5];                                          \
    o0 = __builtin_amdgcn_mfma_f32_32x32x16_bf16(pa0.v, VF[0], o0, 0, 0, 0); \
    o0 = __builtin_amdgcn_mfma_f32_32x32x16_bf16(pa1.v, VF[2], o0, 0, 0, 0); \
    o1 = __builtin_amdgcn_mfma_f32_32x32x16_bf16(pa0.v, VF[1], o1, 0, 0, 0); \
    o1 = __builtin_amdgcn_mfma_f32_32x32x16_bf16(pa1.v, VF[3], o1, 0, 0, 0); \
  } while (0)

  bf16x8 kf0[4], kf1[4], vf[4];
  ATT_LOADK(kf0, 0);
  for (int t = 0; t < nt; ) {
    if (t + 1 < nt) ATT_LOADK(kf1, t + 1);
    ATT_LOADV(vf, t);
    ATT_COMPUTE(kf0, vf, t);
    ++t; if (t >= nt) break;
    if (t + 1 < nt) ATT_LOADK(kf0, t + 1);
    ATT_LOADV(vf, t);
    ATT_COMPUTE(kf1, vf, t);
    ++t;
  }
#undef ATT_LOADK
#undef ATT_LOADV
#undef ATT_COMPUTE

  l += __shfl_xor(l, 32);
  float linv = 1.0f / l;
  if (hi == 0) xch[wid][cq] = linv;
  asm volatile("s_waitcnt lgkmcnt(0)" ::: "memory");
  __builtin_amdgcn_sched_barrier(0);
  float4 n0 = *reinterpret_cast<const float4*>(&xch[wid][4 * hi + 0]);
  float4 n1 = *reinterpret_cast<const float4*>(&xch[wid][4 * hi + 8]);
  float4 n2 = *reinterpret_cast<const float4*>(&xch[wid][4 * hi + 16]);
  float4 n3 = *reinterpret_cast<const float4*>(&xch[wid][4 * hi + 24]);
  float na[16] = {n0.x,n0.y,n0.z,n0.w, n1.x,n1.y,n1.z,n1.w,
                  n2.x,n2.y,n2.z,n2.w, n3.x,n3.y,n3.z,n3.w};
#pragma unroll
  for (int r = 0; r < 16; ++r) {
    int row = (r & 3) + 8 * (r >> 2) + 4 * hi;
    size_t base = (size_t)(b * S_LEN + q0 + row) * D_MODEL + h * 64;
    ctx[base + cq]      = f2b(o0[r] * na[r]);
    ctx[base + 32 + cq] = f2b(o1[r] * na[r]);
  }
  conv_tiles(cvW, cvWT, cvNfull, cvKt, cvNt, cvK0g, cvN0g, tfbuf);
}

// ---------------------------------- host ---------------------------------------------
#define NOCV nullptr, nullptr, 0, 0, 0, 0, 0
extern "C" void kernel_launch(void* const* d_in, const int* in_sizes, int n_in,
                              void* d_out, int out_size, void* d_ws, size_t ws_size,
                              hipStream_t stream)
{
  const float* x     = (const float*)d_in[0];
  const float* wn1   = (const float*)d_in[1];
  const float* wqkv  = (const float*)d_in[2];
  const float* wout  = (const float*)d_in[3];
  const float* wn2   = (const float*)d_in[4];
  const float* wgate = (const float*)d_in[5];
  const float* wup   = (const float*)d_in[6];
  const float* wdown = (const float*)d_in[7];
  float* out = (float*)d_out;
  char* ws = (char*)d_ws;

  // arena: 101.2 MB total
  float* cosT  = (float*)(ws + 0);
  float* sinT  = (float*)(ws + 262144);
  u16*   slotA = (u16*)  (ws + 524288);       // 16.8 MB
  u16*   slotB = (u16*)  (ws + 17301504);     // 16.8 MB
  u16*   x1b   = (u16*)  (ws + 34078720);     // 16.8 MB
  char*  S     = ws + 50855936;               // 50.3 MB time-shared
  u16*   hB    = (u16*)(S + 0);               // h (phase 1); later ctx; later h2
  u16*   qkvB  = (u16*)(S + 16777216);        // 25.2 MB; later slab (33.6)
  u16*   kB    = (u16*)(S + 41943040);        // 4.2 MB
  u16*   vtB   = (u16*)(S + 46137344);        // 4.2 MB
  u16*   ctxB  = (u16*)(S + 0);
  u16*   h2B   = (u16*)(S + 0);
  u16*   slab  = (u16*)(S + 16777216);        // [4096][4096] bf16

  sincos_kernel<<<dim3(256), 256, 0, stream>>>(cosT, sinT);
  rmsnorm_kernel<false><<<dim3(NTOK), 256, 0, stream>>>(x, wn1, hB, NOCV);
  wconv_kernel<<<dim3(1536), 256, 0, stream>>>(wqkv, slotA, 3072, 2048, 3072, 0, 0);

  // qkv = h @ w_qkv; tail: convert wout -> slotB
  gemm128_kernel<4><<<dim3(12, 32), 512, 0, stream>>>(hB, slotA, 2048, 2048, 2048, 3072, 0,
      nullptr, qkvB, nullptr, nullptr, nullptr, wout, slotB, 2048, 2048, 2048, 0, 0);
  rope_kernel<<<dim3(NTOK), 256, 0, stream>>>(qkvB, cosT, sinT, kB, vtB);
  // attn (Q direct from qkvB, rope in-kernel); tail: convert gate c0 -> slotA
  attn_kernel<<<dim3(64, 16), 256, 0, stream>>>(qkvB, kB, vtB, ctxB, cosT, sinT,
      wgate, slotA, 8192, 2048, 4096, 0, 0);

  // x1 = x + ctx @ w_out (bf16 out)
  gemm128_kernel<6><<<dim3(8, 32), 512, 0, stream>>>(ctxB, slotB, 2048, 2048, 2048, 2048, 0,
      nullptr, x1b, x, nullptr, nullptr, NOCV);

  // h2 = rmsnorm(x1); tail: convert up c0 -> slotB
  rmsnorm_kernel<true><<<dim3(NTOK), 256, 0, stream>>>(x1b, wn2, h2B,
      wup, slotB, 8192, 2048, 4096, 0, 0);

  // slab = silu(h2 @ gate_c0)
  gemm8p_kernel<2><<<dim3(16, 16), 512, 0, stream>>>(h2B, slotA, 2048, 2048, 2048, 4096, 0,
      nullptr, slab, nullptr, nullptr, nullptr, NOCV);
  // slab *= h2 @ up_c0; tail: convert down c0 -> slotA
  gemm8p_kernel<3><<<dim3(16, 16), 512, 0, stream>>>(h2B, slotB, 2048, 2048, 2048, 4096, 0,
      nullptr, slab, nullptr, nullptr, slab, wdown, slotA, 2048, 4096, 2048, 0, 0);
  // out = x1 + slab @ down_c0; tail: convert gate c1 -> slotB
  gemm128_kernel<7><<<dim3(8, 32), 512, 0, stream>>>(slab, slotA, 4096, 4096, 4096, 2048, 0,
      out, nullptr, nullptr, x1b, nullptr, wgate, slotB, 8192, 2048, 4096, 0, 4096);
  // slab = silu(h2 @ gate_c1); tail: convert up c1 -> slotA
  gemm8p_kernel<2><<<dim3(16, 16), 512, 0, stream>>>(h2B, slotB, 2048, 2048, 2048, 4096, 0,
      nullptr, slab, nullptr, nullptr, nullptr, wup, slotA, 8192, 2048, 4096, 0, 4096);
  // slab *= h2 @ up_c1; tail: convert down c1 -> slotB
  gemm8p_kernel<3><<<dim3(16, 16), 512, 0, stream>>>(h2B, slotA, 2048, 2048, 2048, 4096, 0,
      nullptr, slab, nullptr, nullptr, slab, wdown, slotB, 2048, 4096, 2048, 4096, 0);
  // out += slab @ down_c1
  gemm128_kernel<5><<<dim3(8, 32), 512, 0, stream>>>(slab, slotB, 4096, 4096, 4096, 2048, 0,
      out, nullptr, nullptr, nullptr, nullptr, NOCV);
}